// Round 11
// baseline (624.853 us; speedup 1.0000x reference)
//
#include <hip/hip_runtime.h>
#include <math.h>

#define HID 128
#define HEADS 8

typedef __attribute__((ext_vector_type(8))) short s16x8;
typedef __attribute__((ext_vector_type(4))) float f32x4;

__device__ __forceinline__ unsigned short bf16_rne(float x) {
  unsigned u = __float_as_uint(x);
  unsigned r = u + 0x7FFFu + ((u >> 16) & 1u);
  return (unsigned short)(r >> 16);
}
__device__ __forceinline__ float bf16f(unsigned short h) {
  return __uint_as_float(((unsigned)h) << 16);
}
__device__ __forceinline__ unsigned pack_hi(float a, float b) {
  return (unsigned)bf16_rne(a) | ((unsigned)bf16_rne(b) << 16);
}

// ====== fused prep: TILED transposes (layer W + input W) + make_v + histogram ==============
// R10 postmortem: old transpose read one 4B elem per 4KB-distant line (stride-1024 floats).
// Now: 64x64 LDS tile ([64][65] pad), coalesced float4 reads AND uint4 split-writes.
struct PrepArgs {
  const float* W[8];
  const float* a[8];
  unsigned short* WThi[4];
  unsigned short* WTlo[4];
  float* v[8];
};
struct PrepX {
  const float* lwa; const float* lwb;
  unsigned short *wa_hi, *wa_lo, *wb_hi, *wb_lo;
  int KA, KB, nta, ntb;   // nta = (KA/64)*2 tiles, ntb = (KB/64)*2
};

__global__ __launch_bounds__(256) void prep_hist(
    PrepArgs p, PrepX px,
    const int* __restrict__ dst_ab, const int* __restrict__ dst_ba,
    int* __restrict__ cnt_ab, int* __restrict__ cnt_ba, int E)
{
  __shared__ float tile[64][65];
  const int bid = blockIdx.x;
  const int tid = threadIdx.x;
  const int a = tid >> 2;          // tile row 0..63
  const int cg = (tid & 3) << 4;   // tile col group: 16 cols

  if (bid < 128) {  // layer W: per (mat g, head h, 64x64 tile) transpose (k,c)->(c,k) + split
    const int g = bid >> 5;
    const int rem = bid & 31;
    const int h = rem >> 2;
    const int t = rem & 3;
    const int k0 = (t >> 1) << 6, c0 = (t & 1) << 6;
    const float* src = p.W[2 * g] + (size_t)(k0 + a) * 1024 + h * 128 + c0 + cg;
#pragma unroll
    for (int i = 0; i < 16; i += 4) {
      const float4 v4 = *(const float4*)(src + i);
      tile[a][cg + i + 0] = v4.x; tile[a][cg + i + 1] = v4.y;
      tile[a][cg + i + 2] = v4.z; tile[a][cg + i + 3] = v4.w;
    }
    __syncthreads();
    const size_t ob = (size_t)(c0 + a) * 1024 + h * 128 + k0 + cg;
    unsigned hibuf[4], lobuf[4];
#pragma unroll
    for (int i = 0; i < 8; i++) {
      float x0 = tile[cg + 2 * i][a];
      float x1 = tile[cg + 2 * i + 1][a];
      unsigned short h0 = bf16_rne(x0), h1 = bf16_rne(x1);
      hibuf[i >> 1] = (i & 1) ? (hibuf[i >> 1] | (((unsigned)h0 | ((unsigned)h1 << 16)) == 0 ? 0u : 0u)) : 0u;  // placeholder
    }
    // assemble cleanly (two uint4 = 16 ushorts per array)
    unsigned hw[8], lw_[8];
#pragma unroll
    for (int i = 0; i < 8; i++) {
      float x0 = tile[cg + 2 * i][a];
      float x1 = tile[cg + 2 * i + 1][a];
      unsigned short h0 = bf16_rne(x0), h1 = bf16_rne(x1);
      unsigned short l0 = bf16_rne(x0 - bf16f(h0)), l1 = bf16_rne(x1 - bf16f(h1));
      hw[i]  = (unsigned)h0 | ((unsigned)h1 << 16);
      lw_[i] = (unsigned)l0 | ((unsigned)l1 << 16);
    }
    *(uint4*)(p.WThi[g] + ob)     = make_uint4(hw[0], hw[1], hw[2], hw[3]);
    *(uint4*)(p.WThi[g] + ob + 8) = make_uint4(hw[4], hw[5], hw[6], hw[7]);
    *(uint4*)(p.WTlo[g] + ob)     = make_uint4(lw_[0], lw_[1], lw_[2], lw_[3]);
    *(uint4*)(p.WTlo[g] + ob + 8) = make_uint4(lw_[4], lw_[5], lw_[6], lw_[7]);
  } else if (bid < 160) {  // make_v: v[wi][k*8+h] = sum_c W[wi][k, h*128+c] * a[wi][h,c]
    const int u = bid - 128;
    const int wi = u >> 2;
    const int gid = ((u & 3) << 8) + tid;
    const int k = gid >> 3, h = gid & 7;
    const float* wr = p.W[wi] + (size_t)k * (HEADS * HID) + h * HID;
    const float* ar = p.a[wi] + (size_t)h * HID;
    float s = 0.f;
    for (int c = 0; c < HID; c++) s = fmaf(wr[c], ar[c], s);
    p.v[wi][gid] = s;
  } else if (bid < 160 + px.nta + px.ntb) {  // input W transpose+split: [K][128] -> [128][K]
    const bool isa = (bid - 160) < px.nta;
    const int b = isa ? (bid - 160) : (bid - 160 - px.nta);
    const int K = isa ? px.KA : px.KB;
    const float* lw = isa ? px.lwa : px.lwb;
    unsigned short* ohi = isa ? px.wa_hi : px.wb_hi;
    unsigned short* olo = isa ? px.wa_lo : px.wb_lo;
    const int k0 = (b >> 1) << 6, c0 = (b & 1) << 6;
    const float* src = lw + (size_t)(k0 + a) * 128 + c0 + cg;
#pragma unroll
    for (int i = 0; i < 16; i += 4) {
      const float4 v4 = *(const float4*)(src + i);
      tile[a][cg + i + 0] = v4.x; tile[a][cg + i + 1] = v4.y;
      tile[a][cg + i + 2] = v4.z; tile[a][cg + i + 3] = v4.w;
    }
    __syncthreads();
    const size_t ob = (size_t)(c0 + a) * K + k0 + cg;
    unsigned hw[8], lw_[8];
#pragma unroll
    for (int i = 0; i < 8; i++) {
      float x0 = tile[cg + 2 * i][a];
      float x1 = tile[cg + 2 * i + 1][a];
      unsigned short h0 = bf16_rne(x0), h1 = bf16_rne(x1);
      unsigned short l0 = bf16_rne(x0 - bf16f(h0)), l1 = bf16_rne(x1 - bf16f(h1));
      hw[i]  = (unsigned)h0 | ((unsigned)h1 << 16);
      lw_[i] = (unsigned)l0 | ((unsigned)l1 << 16);
    }
    *(uint4*)(ohi + ob)     = make_uint4(hw[0], hw[1], hw[2], hw[3]);
    *(uint4*)(ohi + ob + 8) = make_uint4(hw[4], hw[5], hw[6], hw[7]);
    *(uint4*)(olo + ob)     = make_uint4(lw_[0], lw_[1], lw_[2], lw_[3]);
    *(uint4*)(olo + ob + 8) = make_uint4(lw_[4], lw_[5], lw_[6], lw_[7]);
  } else {  // degree histogram, both directions
    int gid = (bid - 160 - px.nta - px.ntb) * 256 + tid;
    if (gid < E) atomicAdd(&cnt_ab[dst_ab[gid]], 1);
    else if (gid < 2 * E) atomicAdd(&cnt_ba[dst_ba[gid - E]], 1);
  }
}

__global__ __launch_bounds__(1024) void scan2(
    const int* __restrict__ cnt_ab, const int* __restrict__ cnt_ba,
    int* __restrict__ ip_ab, int* __restrict__ ip_ba, int n_ab, int n_ba)
{
  const int* cnt = (blockIdx.x == 0) ? cnt_ab : cnt_ba;
  int* indptr = (blockIdx.x == 0) ? ip_ab : ip_ba;
  int n = (blockIdx.x == 0) ? n_ab : n_ba;
  __shared__ int parts[1024];
  const int tid = threadIdx.x;
  const int base = tid * 10;
  int local[10];
  int s = 0;
#pragma unroll
  for (int j = 0; j < 10; j++) {
    int v = (base + j < n) ? cnt[base + j] : 0;
    local[j] = v; s += v;
  }
  parts[tid] = s;
  __syncthreads();
  for (int off = 1; off < 1024; off <<= 1) {
    int v = (tid >= off) ? parts[tid - off] : 0;
    __syncthreads();
    parts[tid] += v;
    __syncthreads();
  }
  int ex = parts[tid] - s;
#pragma unroll
  for (int j = 0; j < 10; j++) {
    if (base + j < n) indptr[base + j] = ex;
    ex += local[j];
  }
  if (tid == 1023) indptr[n] = parts[1023];
}

__global__ __launch_bounds__(256) void scatter2(
    const int* __restrict__ edge_ab, const int* __restrict__ edge_ba,
    const int* __restrict__ ip_ab, const int* __restrict__ ip_ba,
    int* __restrict__ cur_ab, int* __restrict__ cur_ba,
    int* __restrict__ srcs_ab, int* __restrict__ srcs_ba, int E)
{
  int gid = blockIdx.x * 256 + threadIdx.x;
  if (gid < E) {
    int d = edge_ab[E + gid];
    int pos = ip_ab[d] + atomicAdd(&cur_ab[d], 1);
    srcs_ab[pos] = edge_ab[gid];
  } else if (gid < 2 * E) {
    int g = gid - E;
    int d = edge_ba[E + g];
    int pos = ip_ba[d] + atomicAdd(&cur_ba[d], 1);
    srcs_ba[pos] = edge_ba[g];
  }
}

// ===== input linears: MFMA bf16-split GEMM, fp32 A split on the fly, fused bias+relu =======
struct ISeg {
  const float* A;
  const unsigned short* Bhi; const unsigned short* Blo;
  float* out; const float* bias; int M; int K; int yb;
};

__global__ __launch_bounds__(256) void gemm_mfma_in(ISeg s0, ISeg s1)
{
  __shared__ __align__(16) unsigned short smem[12288];
  const int tid = threadIdx.x;
  const float* A; const unsigned short *Bhi, *Blo; const float* bias; float* out;
  int M, K, ytile;
  if ((int)blockIdx.x < s0.yb) {
    A = s0.A; Bhi = s0.Bhi; Blo = s0.Blo; out = s0.out; bias = s0.bias;
    M = s0.M; K = s0.K; ytile = blockIdx.x;
  } else {
    A = s1.A; Bhi = s1.Bhi; Blo = s1.Blo; out = s1.out; bias = s1.bias;
    M = s1.M; K = s1.K; ytile = blockIdx.x - s0.yb;
  }
  const int bm = ytile * 64;
  const int nks = K >> 5;

  const int sr = tid >> 2;
  const int sg = tid & 3;
  const int g1 = sg ^ ((sr >> 1) & 3);
  const int sr2 = sr + 64;
  const int g2 = sg ^ ((sr2 >> 1) & 3);
  const int aslot  = sr * 32 + g1 * 8;
  const int bslotA = sr * 32 + g1 * 8;
  const int bslotB = sr2 * 32 + g2 * 8;
  const int gr = bm + sr;
  const bool arow_ok = (gr < M);
  const float* gA = A + (size_t)gr * K + sg * 8;
  const unsigned short* gB0 = Bhi + (size_t)sr  * K + sg * 8;
  const unsigned short* gB1 = Bhi + (size_t)sr2 * K + sg * 8;
  const unsigned short* gC0 = Blo + (size_t)sr  * K + sg * 8;
  const unsigned short* gC1 = Blo + (size_t)sr2 * K + sg * 8;

  const int l = tid & 63;
  const int w = tid >> 6;
  const int kg = l >> 4;
  int aoff[4], boff[2];
#pragma unroll
  for (int mi = 0; mi < 4; mi++) {
    int r = mi * 16 + (l & 15);
    aoff[mi] = r * 32 + (kg ^ ((r >> 1) & 3)) * 8;
  }
#pragma unroll
  for (int ni = 0; ni < 2; ni++) {
    int r = w * 32 + ni * 16 + (l & 15);
    boff[ni] = r * 32 + (kg ^ ((r >> 1) & 3)) * 8;
  }

  f32x4 acc[4][2];
  const f32x4 z4 = {0.f, 0.f, 0.f, 0.f};
#pragma unroll
  for (int mi = 0; mi < 4; mi++)
#pragma unroll
    for (int ni = 0; ni < 2; ni++) acc[mi][ni] = z4;

  float4 fa0 = make_float4(0.f, 0.f, 0.f, 0.f), fa1 = fa0;
  if (arow_ok) { fa0 = *(const float4*)gA; fa1 = *(const float4*)(gA + 4); }
  uint4 rB0 = *(const uint4*)gB0;
  uint4 rB1 = *(const uint4*)gB1;
  uint4 rC0 = *(const uint4*)gC0;
  uint4 rC1 = *(const uint4*)gC1;

  for (int ks = 0; ks < nks; ks++) {
    {
      const float f[8] = {fa0.x, fa0.y, fa0.z, fa0.w, fa1.x, fa1.y, fa1.z, fa1.w};
      unsigned au[4], lu[4];
#pragma unroll
      for (int i = 0; i < 4; i++) {
        unsigned short h0 = bf16_rne(f[2 * i]);
        unsigned short l0 = bf16_rne(f[2 * i] - bf16f(h0));
        unsigned short h1 = bf16_rne(f[2 * i + 1]);
        unsigned short l1 = bf16_rne(f[2 * i + 1] - bf16f(h1));
        au[i] = (unsigned)h0 | ((unsigned)h1 << 16);
        lu[i] = (unsigned)l0 | ((unsigned)l1 << 16);
      }
      *(uint4*)&smem[aslot]        = make_uint4(au[0], au[1], au[2], au[3]);
      *(uint4*)&smem[2048 + aslot] = make_uint4(lu[0], lu[1], lu[2], lu[3]);
    }
    *(uint4*)&smem[4096 + bslotA] = rB0;
    *(uint4*)&smem[4096 + bslotB] = rB1;
    *(uint4*)&smem[8192 + bslotA] = rC0;
    *(uint4*)&smem[8192 + bslotB] = rC1;
    __syncthreads();
    if (ks < nks - 1) {
      const int k0 = (ks + 1) * 32;
      if (arow_ok) {
        fa0 = *(const float4*)(gA + k0);
        fa1 = *(const float4*)(gA + k0 + 4);
      }
      rB0 = *(const uint4*)(gB0 + k0);
      rB1 = *(const uint4*)(gB1 + k0);
      rC0 = *(const uint4*)(gC0 + k0);
      rC1 = *(const uint4*)(gC1 + k0);
    }
    s16x8 bh0 = *(const s16x8*)&smem[4096 + boff[0]];
    s16x8 bh1 = *(const s16x8*)&smem[4096 + boff[1]];
    s16x8 bl0 = *(const s16x8*)&smem[8192 + boff[0]];
    s16x8 bl1 = *(const s16x8*)&smem[8192 + boff[1]];
#pragma unroll
    for (int mi = 0; mi < 4; mi++) {
      s16x8 ah = *(const s16x8*)&smem[aoff[mi]];
      s16x8 al = *(const s16x8*)&smem[2048 + aoff[mi]];
      acc[mi][0] = __builtin_amdgcn_mfma_f32_16x16x32_bf16(ah, bh0, acc[mi][0], 0, 0, 0);
      acc[mi][1] = __builtin_amdgcn_mfma_f32_16x16x32_bf16(ah, bh1, acc[mi][1], 0, 0, 0);
      acc[mi][0] = __builtin_amdgcn_mfma_f32_16x16x32_bf16(ah, bl0, acc[mi][0], 0, 0, 0);
      acc[mi][1] = __builtin_amdgcn_mfma_f32_16x16x32_bf16(ah, bl1, acc[mi][1], 0, 0, 0);
      acc[mi][0] = __builtin_amdgcn_mfma_f32_16x16x32_bf16(al, bh0, acc[mi][0], 0, 0, 0);
      acc[mi][1] = __builtin_amdgcn_mfma_f32_16x16x32_bf16(al, bh1, acc[mi][1], 0, 0, 0);
      acc[mi][0] = __builtin_amdgcn_mfma_f32_16x16x32_bf16(al, bl0, acc[mi][0], 0, 0, 0);
      acc[mi][1] = __builtin_amdgcn_mfma_f32_16x16x32_bf16(al, bl1, acc[mi][1], 0, 0, 0);
    }
    __syncthreads();
  }

  const int q = l >> 4, cl = l & 15;
#pragma unroll
  for (int ni = 0; ni < 2; ni++) {
    const int col = w * 32 + ni * 16 + cl;
    const float bv = bias[col];
#pragma unroll
    for (int mi = 0; mi < 4; mi++) {
      const int r0 = bm + mi * 16 + q * 4;
      const f32x4 v = acc[mi][ni];
#pragma unroll
      for (int j = 0; j < 4; j++) {
        const int r = r0 + j;
        if (r < M) {
          float x = v[j] + bv;
          x = fmaxf(x, 0.f);
          out[(size_t)r * HID + col] = x;
        }
      }
    }
  }
}

// ================= 4 attention-logit arrays (layer 0 only now) =================
__global__ __launch_bounds__(256) void compute_al4(
    const float* __restrict__ ha, const float* __restrict__ hb,
    const float* __restrict__ v4,
    float* __restrict__ o0, float* __restrict__ o1,
    float* __restrict__ o2, float* __restrict__ o3, int na, int nb)
{
  __shared__ float vsh[4 * HID * HEADS];
  for (int i = threadIdx.x; i < 4 * HID * HEADS; i += 256) vsh[i] = v4[i];
  __syncthreads();
  int gid = blockIdx.x * 256 + threadIdx.x;
  int row = gid >> 3, h = gid & 7;
  const float* hr; float* o; int q, rl;
  if (row < na)                    { q = 0; rl = row;               hr = ha; o = o0; }
  else if (row < na + nb)          { q = 1; rl = row - na;          hr = hb; o = o1; }
  else if (row < na + 2 * nb)      { q = 2; rl = row - na - nb;     hr = hb; o = o2; }
  else if (row < 2 * na + 2 * nb)  { q = 3; rl = row - na - 2 * nb; hr = ha; o = o3; }
  else return;
  hr += (size_t)rl * HID;
  const float* vq = vsh + q * HID * HEADS;
  float s = 0.f;
  for (int k = 0; k < HID; k++) s = fmaf(hr[k], vq[k * HEADS + h], s);
  o[(size_t)rl * HEADS + h] = s;
}

// ================= wave-per-node segment softmax + aggregation; writes bf16-split z =========
// ROUND-5 PROVEN CONFIG (60 VGPR, batch-4 gathers, merged logit+exp pass, no launch bound).
struct GDir {
  const int* indptr; const int* srcs;
  const float* als; const float* ald;
  const float* h;
  unsigned short* zhi; unsigned short* zlo;
};

__global__ __launch_bounds__(256) void gat_edge2(GDir d0, GDir d1, int n0, int ntot)
{
  const int w = threadIdx.x >> 6;
  const int lane = threadIdx.x & 63;
  const int g = blockIdx.x * 4 + w;
  if (g >= ntot) return;
  const bool first = (g < n0);
  const int n = first ? g : g - n0;
  const int* indptr = first ? d0.indptr : d1.indptr;
  const int* srcs   = first ? d0.srcs   : d1.srcs;
  const float* als  = first ? d0.als    : d1.als;
  const float* ald  = first ? d0.ald    : d1.ald;
  const float* hsrc = first ? d0.h      : d1.h;
  unsigned short* zh = (first ? d0.zhi : d1.zhi) + (size_t)n * (HEADS * HID);
  unsigned short* zl = (first ? d0.zlo : d1.zlo) + (size_t)n * (HEADS * HID);

  const int base = indptr[n];
  const int deg = indptr[n + 1] - base;
  if (deg == 0) {
#pragma unroll
    for (int hh = 0; hh < HEADS; hh++) {
      *(unsigned*)(zh + hh * HID + 2 * lane) = 0u;
      *(unsigned*)(zl + hh * HID + 2 * lane) = 0u;
    }
    return;
  }
  const int eh = lane >> 3, h = lane & 7;
  const float aldn = ald[(size_t)n * HEADS + h];
  const int nch = (deg + 7) >> 3;
  const int ncc = nch < 4 ? nch : 4;

  int sc[4];
  float vc[4];
#pragma unroll
  for (int c = 0; c < 4; c++) {
    int e = c * 8 + eh;
    sc[c] = (c < ncc && e < deg) ? srcs[base + e] : -1;
  }
#pragma unroll
  for (int c = 0; c < 4; c++)
    vc[c] = (sc[c] >= 0) ? als[(size_t)sc[c] * HEADS + h] : 0.f;
  float den = 0.f;
#pragma unroll
  for (int c = 0; c < 4; c++) {
    float v = vc[c] + aldn;
    v = v > 0.f ? v : 0.2f * v;
    float ex = (sc[c] >= 0) ? expf(v) : 0.f;
    vc[c] = ex;
    den += ex;
  }
  for (int e0 = 32; e0 < deg; e0 += 8) {
    int e = e0 + eh;
    if (e < deg) {
      int s = srcs[base + e];
      float v = als[(size_t)s * HEADS + h] + aldn;
      v = v > 0.f ? v : 0.2f * v;
      den += expf(v);
    }
  }
  den += __shfl_xor(den, 8);
  den += __shfl_xor(den, 16);
  den += __shfl_xor(den, 32);

  float acc[16];
#pragma unroll
  for (int i = 0; i < 16; i++) acc[i] = 0.f;
#pragma unroll
  for (int c = 0; c < 4; c++) {
    if (c >= ncc) break;
    const int rem = deg - c * 8;
    const int elim = rem < 8 ? rem : 8;
#pragma unroll
    for (int half = 0; half < 2; half++) {
      if (half * 4 >= elim) break;
      int sj[4];
#pragma unroll
      for (int j = 0; j < 4; j++) {
        int s = __shfl(sc[c], (half * 4 + j) * 8);
        sj[j] = s < 0 ? 0 : s;
      }
      float2 hv[4];
#pragma unroll
      for (int j = 0; j < 4; j++)
        hv[j] = *(const float2*)(hsrc + (size_t)sj[j] * HID + 2 * lane);
#pragma unroll
      for (int j = 0; j < 4; j++) {
#pragma unroll
        for (int hh = 0; hh < 8; hh++) {
          float a = __shfl(vc[c], (half * 4 + j) * 8 + hh);
          acc[2 * hh]     = fmaf(a, hv[j].x, acc[2 * hh]);
          acc[2 * hh + 1] = fmaf(a, hv[j].y, acc[2 * hh + 1]);
        }
      }
    }
  }
  for (int e0 = 32; e0 < deg; e0 += 8) {
    int e = e0 + eh;
    int s = (e < deg) ? srcs[base + e] : -1;
    float ex = 0.f;
    if (s >= 0) {
      float v = als[(size_t)s * HEADS + h] + aldn;
      v = v > 0.f ? v : 0.2f * v;
      ex = expf(v);
    }
    int elim = deg - e0; if (elim > 8) elim = 8;
    for (int e8 = 0; e8 < elim; e8++) {
      int ss = __shfl(s, e8 * 8);
      const float2 hvt = *(const float2*)(hsrc + (size_t)ss * HID + 2 * lane);
#pragma unroll
      for (int hh = 0; hh < 8; hh++) {
        float a = __shfl(ex, e8 * 8 + hh);
        acc[2 * hh]     = fmaf(a, hvt.x, acc[2 * hh]);
        acc[2 * hh + 1] = fmaf(a, hvt.y, acc[2 * hh + 1]);
      }
    }
  }
#pragma unroll
  for (int hh = 0; hh < 8; hh++) {
    float dh = __shfl(den, hh);
    float inv = 1.f / (dh + 1e-16f);
    float x0 = acc[2 * hh] * inv;
    float x1 = acc[2 * hh + 1] * inv;
    unsigned short h0 = bf16_rne(x0), h1 = bf16_rne(x1);
    unsigned short l0 = bf16_rne(x0 - bf16f(h0)), l1 = bf16_rne(x1 - bf16f(h1));
    *(unsigned*)(zh + hh * HID + 2 * lane) = (unsigned)h0 | ((unsigned)h1 << 16);
    *(unsigned*)(zl + hh * HID + 2 * lane) = (unsigned)l0 | ((unsigned)l1 << 16);
  }
}

// ================= MFMA bf16x4-split GEMM, GRID SPLIT-K -> P (proven R10) =================
struct MSeg {
  const unsigned short* Ahi; const unsigned short* Alo;
  const unsigned short* Bhi; const unsigned short* Blo;
  int M; int yb;
};

__global__ __launch_bounds__(256, 2) void gemm_mfma_splitk(
    MSeg s0, MSeg s1, float* __restrict__ P, int Mtot, int KS)
{
  __shared__ __align__(16) unsigned short smem[12288];
  const int tid = threadIdx.x;
  const unsigned short *Ahi, *Alo, *Bhi, *Blo; int M, ytile, rowbase;
  if ((int)blockIdx.x < s0.yb) {
    Ahi = s0.Ahi; Alo = s0.Alo; Bhi = s0.Bhi; Blo = s0.Blo;
    M = s0.M; ytile = blockIdx.x; rowbase = 0;
  } else {
    Ahi = s1.Ahi; Alo = s1.Alo; Bhi = s1.Bhi; Blo = s1.Blo;
    M = s1.M; ytile = blockIdx.x - s0.yb; rowbase = s0.yb * 64;
  }
  const int bm = ytile * 64;
  const int kchunk = 1024 / KS;
  const int kbeg = blockIdx.y * kchunk;
  const int nks = kchunk / 32;

  const int sr = tid >> 2;
  const int sg = tid & 3;
  const int g1 = sg ^ ((sr >> 1) & 3);
  const int sr2 = sr + 64;
  const int g2 = sg ^ ((sr2 >> 1) & 3);
  const int aslot  = sr * 32 + g1 * 8;
  const int bslotA = sr * 32 + g1 * 8;
  const int bslotB = sr2 * 32 + g2 * 8;
  const unsigned short* gA  = Ahi + (size_t)(bm + sr) * 1024 + kbeg + sg * 8;
  const unsigned short* gAl = Alo + (size_t)(bm + sr) * 1024 + kbeg + sg * 8;
  const unsigned short* gB0 = Bhi + (size_t)sr  * 1024 + kbeg + sg * 8;
  const unsigned short* gB1 = Bhi + (size_t)sr2 * 1024 + kbeg + sg * 8;
  const unsigned short* gC0 = Blo + (size_t)sr  * 1024 + kbeg + sg * 8;
  const unsigned short* gC1 = Blo + (size_t)sr2 * 1024 + kbeg + sg * 8;

  const int l = tid & 63;
  const int w = tid >> 6;
  const int kg = l >> 4;
  int aoff[4], boff[2];
#pragma unroll
  for (int mi = 0; mi < 4; mi++) {
    int r = mi * 16 + (l & 15);
    aoff[mi] = r * 32 + (kg ^ ((r >> 1) & 3)) * 8;
  }
#pragma unroll
  for (int ni = 0; ni < 2; ni++) {
    int r = w * 32 + ni * 16 + (l & 15);
    boff[ni] = r * 32 + (kg ^ ((r >> 1) & 3)) * 8;
  }

  f32x4 acc[4][2];
  const f32x4 z4 = {0.f, 0.f, 0.f, 0.f};
#pragma unroll
  for (int mi = 0; mi < 4; mi++)
#pragma unroll
    for (int ni = 0; ni < 2; ni++) acc[mi][ni] = z4;

  uint4 rA  = *(const uint4*)gA;
  uint4 rAl = *(const uint4*)gAl;
  uint4 rB0 = *(const uint4*)gB0;
  uint4 rB1 = *(const uint4*)gB1;
  uint4 rC0 = *(const uint4*)gC0;
  uint4 rC1 = *(const uint4*)gC1;

  for (int ks = 0; ks < nks; ks++) {
    *(uint4*)&smem[aslot]         = rA;
    *(uint4*)&smem[2048 + aslot]  = rAl;
    *(uint4*)&smem[4096 + bslotA] = rB0;
    *(uint4*)&smem[4096 + bslotB] = rB1;
    *(uint4*)&smem[8192 + bslotA] = rC0;
    *(uint4*)&smem[8192 + bslotB] = rC1;
    __syncthreads();
    if (ks < nks - 1) {
      const int k0 = (ks + 1) * 32;
      rA  = *(const uint4*)(gA  + k0);
      rAl = *(const uint4*)(gAl + k0);
      rB0 = *(const uint4*)(gB0 + k0);
      rB1 = *(const uint4*)(gB1 + k0);
      rC0 = *(const uint4*)(gC0 + k0);
      rC1 = *(const uint4*)(gC1 + k0);
    }
    s16x8 bh0 = *(const s16x8*)&smem[4096 + boff[0]];
    s16x8 bh1 = *(const s16x8*)&smem[4096 + boff[1]];
    s16x8 bl0 = *(const s16x8*)&smem[8192 + boff[0]];
    s16x8 bl1 = *(const s16x8*)&smem[8192 + boff[1]];
#pragma unroll
    for (int mi = 0; mi < 4; mi++) {
      s16x8 ah = *(const s16x8*)&smem[aoff[mi]];
      s16x8 al = *(const s16x8*)&smem[2048 + aoff[mi]];
      acc[mi][0] = __builtin_amdgcn_mfma_f32_16x16x32_bf16(ah, bh0, acc[mi][0], 0, 0, 0);
      acc[mi][1] = __builtin_amdgcn_mfma_f32_16x16x32_bf16(ah, bh1, acc[mi][1], 0, 0, 0);
      acc[mi][0] = __builtin_amdgcn_mfma_f32_16x16x32_bf16(ah, bl0, acc[mi][0], 0, 0, 0);
      acc[mi][1] = __builtin_amdgcn_mfma_f32_16x16x32_bf16(ah, bl1, acc[mi][1], 0, 0, 0);
      acc[mi][0] = __builtin_amdgcn_mfma_f32_16x16x32_bf16(al, bh0, acc[mi][0], 0, 0, 0);
      acc[mi][1] = __builtin_amdgcn_mfma_f32_16x16x32_bf16(al, bh1, acc[mi][1], 0, 0, 0);
      acc[mi][0] = __builtin_amdgcn_mfma_f32_16x16x32_bf16(al, bl0, acc[mi][0], 0, 0, 0);
      acc[mi][1] = __builtin_amdgcn_mfma_f32_16x16x32_bf16(al, bl1, acc[mi][1], 0, 0, 0);
    }
    __syncthreads();
  }

  const int q = l >> 4, cl = l & 15;
  const size_t prow0 = (size_t)blockIdx.y * Mtot + rowbase + bm;
#pragma unroll
  for (int ni = 0; ni < 2; ni++) {
    const int col = w * 32 + ni * 16 + cl;
#pragma unroll
    for (int mi = 0; mi < 4; mi++) {
      const int r0 = mi * 16 + q * 4;
      const f32x4 v = acc[mi][ni];
#pragma unroll
      for (int j = 0; j < 4; j++) {
        const int r = r0 + j;
        if (bm + r < M) P[(prow0 + r) * HID + col] = v[j];
      }
    }
  }
}

// ======= reduce KS partials + scale/bias/relu + NEXT-LAYER attention logits (fused) ========
// 32 threads own a full 128-col row -> after epilogue, compute al[row,h] = h_row . v[:,h]
// for two v-matrices via per-thread partials + 5-step shfl_xor butterfly (width 32).
struct RSegA {
  float* out; const float* bias; int M; int rowbase;
  const float* va; const float* vb;   // v arrays [128][8]
  float* ala; float* alb;             // outputs [M][8]
};

__global__ __launch_bounds__(256) void reduce_epi_al(
    const float* __restrict__ P, int Mtot, int KS, float scale, int do_relu,
    RSegA s0, RSegA s1)
{
  int idx = blockIdx.x * 256 + threadIdx.x;
  if (idx >= Mtot * 32) return;
  int r = idx >> 5;
  int c = (idx & 31) << 2;
  float* outp; const float* bias; int rl;
  const float* va; const float* vb; float* ala; float* alb;
  if (s1.M > 0 && r >= s1.rowbase) {
    rl = r - s1.rowbase; if (rl >= s1.M) return;
    outp = s1.out; bias = s1.bias; va = s1.va; vb = s1.vb; ala = s1.ala; alb = s1.alb;
  } else {
    rl = r; if (rl >= s0.M) return;
    outp = s0.out; bias = s0.bias; va = s0.va; vb = s0.vb; ala = s0.ala; alb = s0.alb;
  }
  float4 acc = make_float4(0.f, 0.f, 0.f, 0.f);
  for (int z = 0; z < KS; z++) {
    const float4 v = *(const float4*)(P + ((size_t)z * Mtot + r) * HID + c);
    acc.x += v.x; acc.y += v.y; acc.z += v.z; acc.w += v.w;
  }
  const float4 b = *(const float4*)(bias + c);
  acc.x = acc.x * scale + b.x;
  acc.y = acc.y * scale + b.y;
  acc.z = acc.z * scale + b.z;
  acc.w = acc.w * scale + b.w;
  if (do_relu) {
    acc.x = fmaxf(acc.x, 0.f); acc.y = fmaxf(acc.y, 0.f);
    acc.z = fmaxf(acc.z, 0.f); acc.w = fmaxf(acc.w, 0.f);
  }
  *(float4*)(outp + (size_t)rl * HID + c) = acc;

  // next-layer logits
  const float av[4] = {acc.x, acc.y, acc.z, acc.w};
  float pA[8], pB[8];
#pragma unroll
  for (int i = 0; i < 8; i++) { pA[i] = 0.f; pB[i] = 0.f; }
#pragma unroll
  for (int j = 0; j < 4; j++) {
    const float4 a0 = *(const float4*)(va + (c + j) * 8);
    const float4 a1 = *(const float4*)(va + (c + j) * 8 + 4);
    const float4 b0 = *(const float4*)(vb + (c + j) * 8);
    const float4 b1 = *(const float4*)(vb + (c + j) * 8 + 4);
    pA[0] = fmaf(av[j], a0.x, pA[0]); pA[1] = fmaf(av[j], a0.y, pA[1]);
    pA[2] = fmaf(av[j], a0.z, pA[2]); pA[3] = fmaf(av[j], a0.w, pA[3]);
    pA[4] = fmaf(av[j], a1.x, pA[4]); pA[5] = fmaf(av[j], a1.y, pA[5]);
    pA[6] = fmaf(av[j], a1.z, pA[6]); pA[7] = fmaf(av[j], a1.w, pA[7]);
    pB[0] = fmaf(av[j], b0.x, pB[0]); pB[1] = fmaf(av[j], b0.y, pB[1]);
    pB[2] = fmaf(av[j], b0.z, pB[2]); pB[3] = fmaf(av[j], b0.w, pB[3]);
    pB[4] = fmaf(av[j], b1.x, pB[4]); pB[5] = fmaf(av[j], b1.y, pB[5]);
    pB[6] = fmaf(av[j], b1.z, pB[6]); pB[7] = fmaf(av[j], b1.w, pB[7]);
  }
#pragma unroll
  for (int off = 16; off >= 1; off >>= 1) {
#pragma unroll
    for (int i = 0; i < 8; i++) {
      pA[i] += __shfl_xor(pA[i], off);
      pB[i] += __shfl_xor(pB[i], off);
    }
  }
  if ((threadIdx.x & 31) == 0) {
    *(float4*)(ala + (size_t)rl * 8)     = make_float4(pA[0], pA[1], pA[2], pA[3]);
    *(float4*)(ala + (size_t)rl * 8 + 4) = make_float4(pA[4], pA[5], pA[6], pA[7]);
    *(float4*)(alb + (size_t)rl * 8)     = make_float4(pB[0], pB[1], pB[2], pB[3]);
    *(float4*)(alb + (size_t)rl * 8 + 4) = make_float4(pB[4], pB[5], pB[6], pB[7]);
  }
}

// ======= reduce KS partials + scale/bias + POOL dot + atomic-ticket finalize (last layer) ===
// h2 is never materialized: each row's dot with fc_w goes straight to gsum atomics.
struct RSegP { const float* bias; int M; int rowbase; int isA; };

__global__ __launch_bounds__(256) void reduce_epi_pool(
    const float* __restrict__ P, int Mtot, int KS, float scale,
    RSegP s0, RSegP s1,
    const float* __restrict__ fc_w, const float* __restrict__ fc_b,
    const int* __restrict__ batch_a, const int* __restrict__ batch_b,
    float* __restrict__ gsum, int* __restrict__ ticket,
    float* __restrict__ out, int na, int nb, int ng, int tot_blocks)
{
  __shared__ int lastf;
  const int idx = blockIdx.x * 256 + threadIdx.x;
  bool ok = idx < Mtot * 32;
  int r = 0, c = 0, rl = 0, isA = 0;
  const float* bias = s0.bias;
  if (ok) {
    r = idx >> 5;
    c = (idx & 31) << 2;
    if (s1.M > 0 && r >= s1.rowbase) {
      rl = r - s1.rowbase; isA = s1.isA; bias = s1.bias;
      if (rl >= s1.M) ok = false;
    } else {
      rl = r; isA = s0.isA; bias = s0.bias;
      if (rl >= s0.M) ok = false;
    }
  }
  float part = 0.f;
  if (ok) {
    float4 acc = make_float4(0.f, 0.f, 0.f, 0.f);
    for (int z = 0; z < KS; z++) {
      const float4 v = *(const float4*)(P + ((size_t)z * Mtot + r) * HID + c);
      acc.x += v.x; acc.y += v.y; acc.z += v.z; acc.w += v.w;
    }
    const float4 b = *(const float4*)(bias + c);
    acc.x = acc.x * scale + b.x;
    acc.y = acc.y * scale + b.y;
    acc.z = acc.z * scale + b.z;
    acc.w = acc.w * scale + b.w;
    const float* wseg = fc_w + (isA ? 0 : HID) + c;
    part = acc.x * wseg[0] + acc.y * wseg[1] + acc.z * wseg[2] + acc.w * wseg[3];
  }
#pragma unroll
  for (int off = 16; off >= 1; off >>= 1) part += __shfl_xor(part, off);
  if (ok && (threadIdx.x & 31) == 0) {
    const int bt = isA ? batch_a[rl] : batch_b[rl];
    atomicAdd(&gsum[(isA ? 0 : 8) + bt], part);
  }
  __syncthreads();
  if (threadIdx.x == 0) {
    __threadfence();
    int tk = atomicAdd(ticket, 1);
    lastf = (tk == tot_blocks - 1);
  }
  __syncthreads();
  if (lastf) {
    int g = threadIdx.x;
    if (g < ng) {
      int l, rr, lo;
      l = 0; rr = na; while (l < rr) { int m = (l + rr) >> 1; if (batch_a[m] < g) l = m + 1; else rr = m; } lo = l;
      rr = na; while (l < rr) { int m = (l + rr) >> 1; if (batch_a[m] < g + 1) l = m + 1; else rr = m; }
      int ca = l - lo; if (ca < 1) ca = 1;
      l = 0; rr = nb; while (l < rr) { int m = (l + rr) >> 1; if (batch_b[m] < g) l = m + 1; else rr = m; } lo = l;
      rr = nb; while (l < rr) { int m = (l + rr) >> 1; if (batch_b[m] < g + 1) l = m + 1; else rr = m; }
      int cb = l - lo; if (cb < 1) cb = 1;
      float va = atomicAdd(&gsum[g], 0.f);
      float vb = atomicAdd(&gsum[8 + g], 0.f);
      out[g] = va / (float)ca + vb / (float)cb + fc_b[0];
    }
  }
}

extern "C" void kernel_launch(void* const* d_in, const int* in_sizes, int n_in,
                              void* d_out, int out_size, void* d_ws, size_t ws_size,
                              hipStream_t stream)
{
  const float* x_a = (const float*)d_in[0];
  const float* x_b = (const float*)d_in[1];
  const int* edge_ab = (const int*)d_in[2];
  const int* edge_ba = (const int*)d_in[3];
  const int* batch_a = (const int*)d_in[4];
  const int* batch_b = (const int*)d_in[5];
  const float* lin_a_w = (const float*)d_in[6];
  const float* lin_a_b = (const float*)d_in[7];
  const float* lin_b_w = (const float*)d_in[8];
  const float* lin_b_b = (const float*)d_in[9];
  const float* fc_w = (const float*)d_in[10];
  const float* fc_b = (const float*)d_in[11];

  const int NA = in_sizes[4];
  const int NB = in_sizes[5];
  const int E  = in_sizes[2] / 2;
  const int FA = in_sizes[0] / NA;
  const int FB = in_sizes[1] / NB;
  const int NG = out_size;
  const int NMAX = NA > NB ? NA : NB;
  const int NAp = (NA + 127) & ~127, NBp = (NB + 127) & ~127;
  const int NMAXp = NAp > NBp ? NAp : NBp;
  const int Mtot = NAp + NBp;

  // ---- size model (mirrors carve order) ----
  auto al256 = [](size_t b) { return (b + 255) & ~(size_t)255; };
  size_t fixed = 0;
  fixed += 2 * al256((size_t)NAp * HID * 4) + 2 * al256((size_t)NBp * HID * 4);   // h0,h1 (no h2)
  fixed += 2 * al256((size_t)NMAXp * 1024 * 2);                                   // z_ab hi+lo
  fixed += al256((size_t)8 * 131072 * 2);                                         // WT layer
  fixed += 2 * al256((size_t)FA * HID * 2) + 2 * al256((size_t)FB * HID * 2);     // WTin hi/lo
  fixed += al256((size_t)8 * HID * HEADS * 4);                                    // vv
  fixed += 2 * al256((size_t)NAp * HEADS * 4) + 2 * al256((size_t)NBp * HEADS * 4);
  fixed += al256(((size_t)4 * NMAX + 24) * 4);
  fixed += al256((size_t)(NB + 1) * 4) + al256((size_t)(NA + 1) * 4);
  fixed += 2 * al256((size_t)E * 4);
  fixed += 8192;
  const size_t zba_sz = 2 * al256((size_t)NAp * 1024 * 2);
  const size_t pslice = al256((size_t)Mtot * HID * 4);

  int KS = 4; bool dual = true;
  if (fixed + zba_sz + 4 * pslice <= ws_size)      { dual = true;  KS = 4; }
  else if (fixed + zba_sz + 2 * pslice <= ws_size) { dual = true;  KS = 2; }
  else if (fixed + 4 * pslice <= ws_size)          { dual = false; KS = 4; }
  else if (fixed + 2 * pslice <= ws_size)          { dual = false; KS = 2; }
  else if (fixed + 1 * pslice <= ws_size)          { dual = false; KS = 1; }
  else return;  // loud failure (out stays poisoned)

  char* w = (char*)d_ws;
  auto carve = [&](size_t bytes) -> void* {
    void* p = (void*)w;
    w += (bytes + 255) & ~(size_t)255;
    return p;
  };
  float* ha0 = (float*)carve((size_t)NAp * HID * 4);
  float* hb0 = (float*)carve((size_t)NBp * HID * 4);
  float* ha1 = (float*)carve((size_t)NAp * HID * 4);
  float* hb1 = (float*)carve((size_t)NBp * HID * 4);
  unsigned short* zab_hi = (unsigned short*)carve((size_t)NMAXp * 1024 * 2);
  unsigned short* zab_lo = (unsigned short*)carve((size_t)NMAXp * 1024 * 2);
  unsigned short* zba_hi = dual ? (unsigned short*)carve((size_t)NAp * 1024 * 2) : zab_hi;
  unsigned short* zba_lo = dual ? (unsigned short*)carve((size_t)NAp * 1024 * 2) : zab_lo;
  float* P = (float*)carve((size_t)KS * Mtot * HID * 4);
  unsigned short* WT = (unsigned short*)carve((size_t)8 * 131072 * 2);
  unsigned short* wa_hi = (unsigned short*)carve((size_t)FA * HID * 2);
  unsigned short* wa_lo = (unsigned short*)carve((size_t)FA * HID * 2);
  unsigned short* wb_hi = (unsigned short*)carve((size_t)FB * HID * 2);
  unsigned short* wb_lo = (unsigned short*)carve((size_t)FB * HID * 2);
  float* vv  = (float*)carve((size_t)8 * HID * HEADS * 4);
  float* als_ab = (float*)carve((size_t)NAp * HEADS * 4);
  float* ald_ab = (float*)carve((size_t)NBp * HEADS * 4);
  float* als_ba = (float*)carve((size_t)NBp * HEADS * 4);
  float* ald_ba = (float*)carve((size_t)NAp * HEADS * 4);
  int* csrblk = (int*)carve(((size_t)4 * NMAX + 24) * 4);
  int* indptr_ab = (int*)carve((size_t)(NB + 1) * 4);
  int* indptr_ba = (int*)carve((size_t)(NA + 1) * 4);
  int* srcs_ab   = (int*)carve((size_t)E * 4);
  int* srcs_ba   = (int*)carve((size_t)E * 4);
  if ((size_t)(w - (char*)d_ws) > ws_size) return;

  int* cnt_ab = csrblk;
  int* cnt_ba = csrblk + NMAX;
  int* cur_ab = csrblk + 2 * NMAX;
  int* cur_ba = csrblk + 3 * NMAX;
  float* gsum = (float*)(csrblk + 4 * NMAX);
  int* ticket = csrblk + 4 * NMAX + 16;

  hipMemsetAsync(csrblk, 0, ((size_t)4 * NMAX + 24) * 4, stream);

  // ---- fused weight prep (tiled transposes) + histogram ----
  PrepArgs pa;
  const int wi_idx[8] = {12, 13, 17, 18, 22, 23, 27, 28};
  const int ai_idx[8] = {14, 15, 19, 20, 24, 25, 29, 30};
  for (int i = 0; i < 8; i++) {
    pa.W[i] = (const float*)d_in[wi_idx[i]];
    pa.a[i] = (const float*)d_in[ai_idx[i]];
    pa.v[i] = vv + (size_t)i * HID * HEADS;
  }
  for (int g = 0; g < 4; g++) {
    pa.WThi[g] = WT + (size_t)g * 131072;
    pa.WTlo[g] = WT + (size_t)(4 + g) * 131072;
  }
  PrepX px;
  px.lwa = lin_a_w; px.lwb = lin_b_w;
  px.wa_hi = wa_hi; px.wa_lo = wa_lo; px.wb_hi = wb_hi; px.wb_lo = wb_lo;
  px.KA = FA; px.KB = FB;
  px.nta = (FA / 64) * 2;
  px.ntb = (FB / 64) * 2;
  const int hist_b = (2 * E + 255) / 256;
  prep_hist<<<160 + px.nta + px.ntb + hist_b, 256, 0, stream>>>(
      pa, px, edge_ab + E, edge_ba + E, cnt_ab, cnt_ba, E);
  scan2<<<2, 1024, 0, stream>>>(cnt_ab, cnt_ba, indptr_ab, indptr_ba, NB, NA);
  scatter2<<<(2 * E + 255) / 256, 256, 0, stream>>>(
      edge_ab, edge_ba, indptr_ab, indptr_ba, cur_ab, cur_ba, srcs_ab, srcs_ba, E);

  // ---- input linears: MFMA split GEMM with fused bias+relu ----
  {
    ISeg sa = {x_a, wa_hi, wa_lo, ha0, lin_a_b, NA, FA, NAp / 64};
    ISeg sb = {x_b, wb_hi, wb_lo, hb0, lin_b_b, NB, FB, NBp / 64};
    gemm_mfma_in<<<NAp / 64 + NBp / 64, 256, 0, stream>>>(sa, sb);
  }

  const int red_grid = (Mtot * 32 + 255) / 256;

  // ---- layer-0 attention logits (only standalone al launch) ----
  compute_al4<<<((2 * (NA + NB)) * HEADS + 255) / 256, 256, 0, stream>>>(
      ha0, hb0, vv, als_ab, ald_ab, als_ba, ald_ba, NA, NB);

  GDir dab0 = {indptr_ab, srcs_ab, als_ab, ald_ab, ha0, zab_hi, zab_lo};
  GDir dba0 = {indptr_ba, srcs_ba, als_ba, ald_ba, hb0, zba_hi, zba_lo};
  MSeg mab0 = {zab_hi, zab_lo, WT + (size_t)0 * 131072, WT + (size_t)4 * 131072, NB, NBp / 64};
  MSeg mba0 = {zba_hi, zba_lo, WT + (size_t)1 * 131072, WT + (size_t)5 * 131072, NA, NAp / 64};
  const float* v1 = vv + (size_t)4 * HID * HEADS;  // layer-1 v arrays

  GDir dab1 = {indptr_ab, srcs_ab, als_ab, ald_ab, ha1, zab_hi, zab_lo};
  GDir dba1 = {indptr_ba, srcs_ba, als_ba, ald_ba, hb1, zba_hi, zba_lo};
  MSeg mab1 = {zab_hi, zab_lo, WT + (size_t)2 * 131072, WT + (size_t)6 * 131072, NB, NBp / 64};
  MSeg mba1 = {zba_hi, zba_lo, WT + (size_t)3 * 131072, WT + (size_t)7 * 131072, NA, NAp / 64};

  if (dual) {
    // layer 0
    gat_edge2<<<(NB + NA + 3) / 4, 256, 0, stream>>>(dab0, dba0, NB, NB + NA);
    gemm_mfma_splitk<<<dim3(NBp / 64 + NAp / 64, KS), 256, 0, stream>>>(mab0, mba0, P, Mtot, KS);
    RSegA r0 = {hb1, (const float*)d_in[16], NB, 0,
                v1 + 1024, v1 + 2048, ald_ab, als_ba};          // B rows: ald_ab(v1), als_ba(v2)
    RSegA r1 = {ha1, (const float*)d_in[21], NA, NBp,
                v1, v1 + 3072, als_ab, ald_ba};                 // A rows: als_ab(v0), ald_ba(v3)
    reduce_epi_al<<<red_grid, 256, 0, stream>>>(P, Mtot, KS, 1.f / HEADS, 1, r0, r1);
    // layer 1
    gat_edge2<<<(NB + NA + 3) / 4, 256, 0, stream>>>(dab1, dba1, NB, NB + NA);
    gemm_mfma_splitk<<<dim3(NBp / 64 + NAp / 64, KS), 256, 0, stream>>>(mab1, mba1, P, Mtot, KS);
    RSegP p0 = {(const float*)d_in[26], NB, 0, 0};
    RSegP p1 = {(const float*)d_in[31], NA, NBp, 1};
    reduce_epi_pool<<<red_grid, 256, 0, stream>>>(P, Mtot, KS, 1.f / HEADS, p0, p1,
        fc_w, fc_b, batch_a, batch_b, gsum, ticket, (float*)d_out, NA, NB, NG, red_grid);
  } else {
    const RSegA ranull = {nullptr, nullptr, 0, 0, nullptr, nullptr, nullptr, nullptr};
    // layer 0, direction ab then ba
    gat_edge2<<<(NB + 3) / 4, 256, 0, stream>>>(dab0, dab0, NB, NB);
    {
      MSeg mz = {nullptr, nullptr, nullptr, nullptr, 0, 0};
      gemm_mfma_splitk<<<dim3(NBp / 64, KS), 256, 0, stream>>>(mab0, mz, P, NBp, KS);
      RSegA r0 = {hb1, (const float*)d_in[16], NB, 0, v1 + 1024, v1 + 2048, ald_ab, als_ba};
      reduce_epi_al<<<(NBp * 32 + 255) / 256, 256, 0, stream>>>(P, NBp, KS, 1.f / HEADS, 1, r0, ranull);
    }
    gat_edge2<<<(NA + 3) / 4, 256, 0, stream>>>(dba0, dba0, NA, NA);
    {
      MSeg mz = {nullptr, nullptr, nullptr, nullptr, 0, 0};
      gemm_mfma_splitk<<<dim3(NAp / 64, KS), 256, 0, stream>>>(mba0, mz, P, NAp, KS);
      RSegA r1 = {ha1, (const float*)d_in[21], NA, 0, v1, v1 + 3072, als_ab, ald_ba};
      reduce_epi_al<<<(NAp * 32 + 255) / 256, 256, 0, stream>>>(P, NAp, KS, 1.f / HEADS, 1, r1, ranull);
    }
    // layer 1
    const int gb1 = (NBp * 32 + 255) / 256;
    const int ga1 = (NAp * 32 + 255) / 256;
    const RSegP pnull = {nullptr, 0, 0, 0};
    gat_edge2<<<(NB + 3) / 4, 256, 0, stream>>>(dab1, dab1, NB, NB);
    {
      MSeg mz = {nullptr, nullptr, nullptr, nullptr, 0, 0};
      gemm_mfma_splitk<<<dim3(NBp / 64, KS), 256, 0, stream>>>(mab1, mz, P, NBp, KS);
      RSegP p0 = {(const float*)d_in[26], NB, 0, 0};
      reduce_epi_pool<<<gb1, 256, 0, stream>>>(P, NBp, KS, 1.f / HEADS, p0, pnull,
          fc_w, fc_b, batch_a, batch_b, gsum, ticket, (float*)d_out, NA, NB, NG, gb1 + ga1);
    }
    gat_edge2<<<(NA + 3) / 4, 256, 0, stream>>>(dba1, dba1, NA, NA);
    {
      MSeg mz = {nullptr, nullptr, nullptr, nullptr, 0, 0};
      gemm_mfma_splitk<<<dim3(NAp / 64, KS), 256, 0, stream>>>(mba1, mz, P, NAp, KS);
      RSegP p1 = {(const float*)d_in[31], NA, 0, 1};
      reduce_epi_pool<<<ga1, 256, 0, stream>>>(P, NAp, KS, 1.f / HEADS, p1, pnull,
          fc_w, fc_b, batch_a, batch_b, gsum, ticket, (float*)d_out, NA, NB, NG, gb1 + ga1);
    }
  }
}

// Round 12
// 446.499 us; speedup vs baseline: 1.3995x; 1.3995x over previous
//
#include <hip/hip_runtime.h>
#include <math.h>

#define HID 128
#define HEADS 8
#define GSLOTS 256

typedef __attribute__((ext_vector_type(8))) short s16x8;
typedef __attribute__((ext_vector_type(4))) float f32x4;

__device__ __forceinline__ unsigned short bf16_rne(float x) {
  unsigned u = __float_as_uint(x);
  unsigned r = u + 0x7FFFu + ((u >> 16) & 1u);
  return (unsigned short)(r >> 16);
}
__device__ __forceinline__ float bf16f(unsigned short h) {
  return __uint_as_float(((unsigned)h) << 16);
}

// ====== fused prep: TILED transposes (layer W + input W) + make_v + histogram ==============
struct PrepArgs {
  const float* W[8];
  const float* a[8];
  unsigned short* WThi[4];
  unsigned short* WTlo[4];
  float* v[8];
};
struct PrepX {
  const float* lwa; const float* lwb;
  unsigned short *wa_hi, *wa_lo, *wb_hi, *wb_lo;
  int KA, KB, nta, ntb;
};

__global__ __launch_bounds__(256) void prep_hist(
    PrepArgs p, PrepX px,
    const int* __restrict__ dst_ab, const int* __restrict__ dst_ba,
    int* __restrict__ cnt_ab, int* __restrict__ cnt_ba, int E)
{
  __shared__ float tile[64][65];
  const int bid = blockIdx.x;
  const int tid = threadIdx.x;
  const int a = tid >> 2;          // tile row 0..63
  const int cg = (tid & 3) << 4;   // tile col group: 16 cols

  if (bid < 128) {  // layer W: per (mat g, head h, 64x64 tile) transpose (k,c)->(c,k) + split
    const int g = bid >> 5;
    const int rem = bid & 31;
    const int h = rem >> 2;
    const int t = rem & 3;
    const int k0 = (t >> 1) << 6, c0 = (t & 1) << 6;
    const float* src = p.W[2 * g] + (size_t)(k0 + a) * 1024 + h * 128 + c0 + cg;
#pragma unroll
    for (int i = 0; i < 16; i += 4) {
      const float4 v4 = *(const float4*)(src + i);
      tile[a][cg + i + 0] = v4.x; tile[a][cg + i + 1] = v4.y;
      tile[a][cg + i + 2] = v4.z; tile[a][cg + i + 3] = v4.w;
    }
    __syncthreads();
    const size_t ob = (size_t)(c0 + a) * 1024 + h * 128 + k0 + cg;
    unsigned hw[8], lw_[8];
#pragma unroll
    for (int i = 0; i < 8; i++) {
      float x0 = tile[cg + 2 * i][a];
      float x1 = tile[cg + 2 * i + 1][a];
      unsigned short h0 = bf16_rne(x0), h1 = bf16_rne(x1);
      unsigned short l0 = bf16_rne(x0 - bf16f(h0)), l1 = bf16_rne(x1 - bf16f(h1));
      hw[i]  = (unsigned)h0 | ((unsigned)h1 << 16);
      lw_[i] = (unsigned)l0 | ((unsigned)l1 << 16);
    }
    *(uint4*)(p.WThi[g] + ob)     = make_uint4(hw[0], hw[1], hw[2], hw[3]);
    *(uint4*)(p.WThi[g] + ob + 8) = make_uint4(hw[4], hw[5], hw[6], hw[7]);
    *(uint4*)(p.WTlo[g] + ob)     = make_uint4(lw_[0], lw_[1], lw_[2], lw_[3]);
    *(uint4*)(p.WTlo[g] + ob + 8) = make_uint4(lw_[4], lw_[5], lw_[6], lw_[7]);
  } else if (bid < 160) {  // make_v
    const int u = bid - 128;
    const int wi = u >> 2;
    const int gid = ((u & 3) << 8) + tid;
    const int k = gid >> 3, h = gid & 7;
    const float* wr = p.W[wi] + (size_t)k * (HEADS * HID) + h * HID;
    const float* ar = p.a[wi] + (size_t)h * HID;
    float s = 0.f;
    for (int c = 0; c < HID; c++) s = fmaf(wr[c], ar[c], s);
    p.v[wi][gid] = s;
  } else if (bid < 160 + px.nta + px.ntb) {  // input W transpose+split: [K][128] -> [128][K]
    const bool isa = (bid - 160) < px.nta;
    const int b = isa ? (bid - 160) : (bid - 160 - px.nta);
    const int K = isa ? px.KA : px.KB;
    const float* lw = isa ? px.lwa : px.lwb;
    unsigned short* ohi = isa ? px.wa_hi : px.wb_hi;
    unsigned short* olo = isa ? px.wa_lo : px.wb_lo;
    const int k0 = (b >> 1) << 6, c0 = (b & 1) << 6;
    const float* src = lw + (size_t)(k0 + a) * 128 + c0 + cg;
#pragma unroll
    for (int i = 0; i < 16; i += 4) {
      const float4 v4 = *(const float4*)(src + i);
      tile[a][cg + i + 0] = v4.x; tile[a][cg + i + 1] = v4.y;
      tile[a][cg + i + 2] = v4.z; tile[a][cg + i + 3] = v4.w;
    }
    __syncthreads();
    const size_t ob = (size_t)(c0 + a) * K + k0 + cg;
    unsigned hw[8], lw_[8];
#pragma unroll
    for (int i = 0; i < 8; i++) {
      float x0 = tile[cg + 2 * i][a];
      float x1 = tile[cg + 2 * i + 1][a];
      unsigned short h0 = bf16_rne(x0), h1 = bf16_rne(x1);
      unsigned short l0 = bf16_rne(x0 - bf16f(h0)), l1 = bf16_rne(x1 - bf16f(h1));
      hw[i]  = (unsigned)h0 | ((unsigned)h1 << 16);
      lw_[i] = (unsigned)l0 | ((unsigned)l1 << 16);
    }
    *(uint4*)(ohi + ob)     = make_uint4(hw[0], hw[1], hw[2], hw[3]);
    *(uint4*)(ohi + ob + 8) = make_uint4(hw[4], hw[5], hw[6], hw[7]);
    *(uint4*)(olo + ob)     = make_uint4(lw_[0], lw_[1], lw_[2], lw_[3]);
    *(uint4*)(olo + ob + 8) = make_uint4(lw_[4], lw_[5], lw_[6], lw_[7]);
  } else {  // degree histogram, both directions
    int gid = (bid - 160 - px.nta - px.ntb) * 256 + tid;
    if (gid < E) atomicAdd(&cnt_ab[dst_ab[gid]], 1);
    else if (gid < 2 * E) atomicAdd(&cnt_ba[dst_ba[gid - E]], 1);
  }
}

__global__ __launch_bounds__(1024) void scan2(
    const int* __restrict__ cnt_ab, const int* __restrict__ cnt_ba,
    int* __restrict__ ip_ab, int* __restrict__ ip_ba, int n_ab, int n_ba)
{
  const int* cnt = (blockIdx.x == 0) ? cnt_ab : cnt_ba;
  int* indptr = (blockIdx.x == 0) ? ip_ab : ip_ba;
  int n = (blockIdx.x == 0) ? n_ab : n_ba;
  __shared__ int parts[1024];
  const int tid = threadIdx.x;
  const int base = tid * 10;
  int local[10];
  int s = 0;
#pragma unroll
  for (int j = 0; j < 10; j++) {
    int v = (base + j < n) ? cnt[base + j] : 0;
    local[j] = v; s += v;
  }
  parts[tid] = s;
  __syncthreads();
  for (int off = 1; off < 1024; off <<= 1) {
    int v = (tid >= off) ? parts[tid - off] : 0;
    __syncthreads();
    parts[tid] += v;
    __syncthreads();
  }
  int ex = parts[tid] - s;
#pragma unroll
  for (int j = 0; j < 10; j++) {
    if (base + j < n) indptr[base + j] = ex;
    ex += local[j];
  }
  if (tid == 1023) indptr[n] = parts[1023];
}

__global__ __launch_bounds__(256) void scatter2(
    const int* __restrict__ edge_ab, const int* __restrict__ edge_ba,
    const int* __restrict__ ip_ab, const int* __restrict__ ip_ba,
    int* __restrict__ cur_ab, int* __restrict__ cur_ba,
    int* __restrict__ srcs_ab, int* __restrict__ srcs_ba, int E)
{
  int gid = blockIdx.x * 256 + threadIdx.x;
  if (gid < E) {
    int d = edge_ab[E + gid];
    int pos = ip_ab[d] + atomicAdd(&cur_ab[d], 1);
    srcs_ab[pos] = edge_ab[gid];
  } else if (gid < 2 * E) {
    int g = gid - E;
    int d = edge_ba[E + g];
    int pos = ip_ba[d] + atomicAdd(&cur_ba[d], 1);
    srcs_ba[pos] = edge_ba[g];
  }
}

// ===== input linears: MFMA bf16-split GEMM, fp32 A split on the fly, fused bias+relu =======
struct ISeg {
  const float* A;
  const unsigned short* Bhi; const unsigned short* Blo;
  float* out; const float* bias; int M; int K; int yb;
};

__global__ __launch_bounds__(256) void gemm_mfma_in(ISeg s0, ISeg s1)
{
  __shared__ __align__(16) unsigned short smem[12288];
  const int tid = threadIdx.x;
  const float* A; const unsigned short *Bhi, *Blo; const float* bias; float* out;
  int M, K, ytile;
  if ((int)blockIdx.x < s0.yb) {
    A = s0.A; Bhi = s0.Bhi; Blo = s0.Blo; out = s0.out; bias = s0.bias;
    M = s0.M; K = s0.K; ytile = blockIdx.x;
  } else {
    A = s1.A; Bhi = s1.Bhi; Blo = s1.Blo; out = s1.out; bias = s1.bias;
    M = s1.M; K = s1.K; ytile = blockIdx.x - s0.yb;
  }
  const int bm = ytile * 64;
  const int nks = K >> 5;

  const int sr = tid >> 2;
  const int sg = tid & 3;
  const int g1 = sg ^ ((sr >> 1) & 3);
  const int sr2 = sr + 64;
  const int g2 = sg ^ ((sr2 >> 1) & 3);
  const int aslot  = sr * 32 + g1 * 8;
  const int bslotA = sr * 32 + g1 * 8;
  const int bslotB = sr2 * 32 + g2 * 8;
  const int gr = bm + sr;
  const bool arow_ok = (gr < M);
  const float* gA = A + (size_t)gr * K + sg * 8;
  const unsigned short* gB0 = Bhi + (size_t)sr  * K + sg * 8;
  const unsigned short* gB1 = Bhi + (size_t)sr2 * K + sg * 8;
  const unsigned short* gC0 = Blo + (size_t)sr  * K + sg * 8;
  const unsigned short* gC1 = Blo + (size_t)sr2 * K + sg * 8;

  const int l = tid & 63;
  const int w = tid >> 6;
  const int kg = l >> 4;
  int aoff[4], boff[2];
#pragma unroll
  for (int mi = 0; mi < 4; mi++) {
    int r = mi * 16 + (l & 15);
    aoff[mi] = r * 32 + (kg ^ ((r >> 1) & 3)) * 8;
  }
#pragma unroll
  for (int ni = 0; ni < 2; ni++) {
    int r = w * 32 + ni * 16 + (l & 15);
    boff[ni] = r * 32 + (kg ^ ((r >> 1) & 3)) * 8;
  }

  f32x4 acc[4][2];
  const f32x4 z4 = {0.f, 0.f, 0.f, 0.f};
#pragma unroll
  for (int mi = 0; mi < 4; mi++)
#pragma unroll
    for (int ni = 0; ni < 2; ni++) acc[mi][ni] = z4;

  float4 fa0 = make_float4(0.f, 0.f, 0.f, 0.f), fa1 = fa0;
  if (arow_ok) { fa0 = *(const float4*)gA; fa1 = *(const float4*)(gA + 4); }
  uint4 rB0 = *(const uint4*)gB0;
  uint4 rB1 = *(const uint4*)gB1;
  uint4 rC0 = *(const uint4*)gC0;
  uint4 rC1 = *(const uint4*)gC1;

  for (int ks = 0; ks < nks; ks++) {
    {
      const float f[8] = {fa0.x, fa0.y, fa0.z, fa0.w, fa1.x, fa1.y, fa1.z, fa1.w};
      unsigned au[4], lu[4];
#pragma unroll
      for (int i = 0; i < 4; i++) {
        unsigned short h0 = bf16_rne(f[2 * i]);
        unsigned short l0 = bf16_rne(f[2 * i] - bf16f(h0));
        unsigned short h1 = bf16_rne(f[2 * i + 1]);
        unsigned short l1 = bf16_rne(f[2 * i + 1] - bf16f(h1));
        au[i] = (unsigned)h0 | ((unsigned)h1 << 16);
        lu[i] = (unsigned)l0 | ((unsigned)l1 << 16);
      }
      *(uint4*)&smem[aslot]        = make_uint4(au[0], au[1], au[2], au[3]);
      *(uint4*)&smem[2048 + aslot] = make_uint4(lu[0], lu[1], lu[2], lu[3]);
    }
    *(uint4*)&smem[4096 + bslotA] = rB0;
    *(uint4*)&smem[4096 + bslotB] = rB1;
    *(uint4*)&smem[8192 + bslotA] = rC0;
    *(uint4*)&smem[8192 + bslotB] = rC1;
    __syncthreads();
    if (ks < nks - 1) {
      const int k0 = (ks + 1) * 32;
      if (arow_ok) {
        fa0 = *(const float4*)(gA + k0);
        fa1 = *(const float4*)(gA + k0 + 4);
      }
      rB0 = *(const uint4*)(gB0 + k0);
      rB1 = *(const uint4*)(gB1 + k0);
      rC0 = *(const uint4*)(gC0 + k0);
      rC1 = *(const uint4*)(gC1 + k0);
    }
    s16x8 bh0 = *(const s16x8*)&smem[4096 + boff[0]];
    s16x8 bh1 = *(const s16x8*)&smem[4096 + boff[1]];
    s16x8 bl0 = *(const s16x8*)&smem[8192 + boff[0]];
    s16x8 bl1 = *(const s16x8*)&smem[8192 + boff[1]];
#pragma unroll
    for (int mi = 0; mi < 4; mi++) {
      s16x8 ah = *(const s16x8*)&smem[aoff[mi]];
      s16x8 al = *(const s16x8*)&smem[2048 + aoff[mi]];
      acc[mi][0] = __builtin_amdgcn_mfma_f32_16x16x32_bf16(ah, bh0, acc[mi][0], 0, 0, 0);
      acc[mi][1] = __builtin_amdgcn_mfma_f32_16x16x32_bf16(ah, bh1, acc[mi][1], 0, 0, 0);
      acc[mi][0] = __builtin_amdgcn_mfma_f32_16x16x32_bf16(ah, bl0, acc[mi][0], 0, 0, 0);
      acc[mi][1] = __builtin_amdgcn_mfma_f32_16x16x32_bf16(ah, bl1, acc[mi][1], 0, 0, 0);
      acc[mi][0] = __builtin_amdgcn_mfma_f32_16x16x32_bf16(al, bh0, acc[mi][0], 0, 0, 0);
      acc[mi][1] = __builtin_amdgcn_mfma_f32_16x16x32_bf16(al, bh1, acc[mi][1], 0, 0, 0);
      acc[mi][0] = __builtin_amdgcn_mfma_f32_16x16x32_bf16(al, bl0, acc[mi][0], 0, 0, 0);
      acc[mi][1] = __builtin_amdgcn_mfma_f32_16x16x32_bf16(al, bl1, acc[mi][1], 0, 0, 0);
    }
    __syncthreads();
  }

  const int q = l >> 4, cl = l & 15;
#pragma unroll
  for (int ni = 0; ni < 2; ni++) {
    const int col = w * 32 + ni * 16 + cl;
    const float bv = bias[col];
#pragma unroll
    for (int mi = 0; mi < 4; mi++) {
      const int r0 = bm + mi * 16 + q * 4;
      const f32x4 v = acc[mi][ni];
#pragma unroll
      for (int j = 0; j < 4; j++) {
        const int r = r0 + j;
        if (r < M) {
          float x = v[j] + bv;
          x = fmaxf(x, 0.f);
          out[(size_t)r * HID + col] = x;
        }
      }
    }
  }
}

// ================= 4 attention-logit arrays (layer 0 only) =================
__global__ __launch_bounds__(256) void compute_al4(
    const float* __restrict__ ha, const float* __restrict__ hb,
    const float* __restrict__ v4,
    float* __restrict__ o0, float* __restrict__ o1,
    float* __restrict__ o2, float* __restrict__ o3, int na, int nb)
{
  __shared__ float vsh[4 * HID * HEADS];
  for (int i = threadIdx.x; i < 4 * HID * HEADS; i += 256) vsh[i] = v4[i];
  __syncthreads();
  int gid = blockIdx.x * 256 + threadIdx.x;
  int row = gid >> 3, h = gid & 7;
  const float* hr; float* o; int q, rl;
  if (row < na)                    { q = 0; rl = row;               hr = ha; o = o0; }
  else if (row < na + nb)          { q = 1; rl = row - na;          hr = hb; o = o1; }
  else if (row < na + 2 * nb)      { q = 2; rl = row - na - nb;     hr = hb; o = o2; }
  else if (row < 2 * na + 2 * nb)  { q = 3; rl = row - na - 2 * nb; hr = ha; o = o3; }
  else return;
  hr += (size_t)rl * HID;
  const float* vq = vsh + q * HID * HEADS;
  float s = 0.f;
  for (int k = 0; k < HID; k++) s = fmaf(hr[k], vq[k * HEADS + h], s);
  o[(size_t)rl * HEADS + h] = s;
}

// ================= wave-per-node segment softmax + aggregation; writes bf16-split z =========
struct GDir {
  const int* indptr; const int* srcs;
  const float* als; const float* ald;
  const float* h;
  unsigned short* zhi; unsigned short* zlo;
};

__global__ __launch_bounds__(256) void gat_edge2(GDir d0, GDir d1, int n0, int ntot)
{
  const int w = threadIdx.x >> 6;
  const int lane = threadIdx.x & 63;
  const int g = blockIdx.x * 4 + w;
  if (g >= ntot) return;
  const bool first = (g < n0);
  const int n = first ? g : g - n0;
  const int* indptr = first ? d0.indptr : d1.indptr;
  const int* srcs   = first ? d0.srcs   : d1.srcs;
  const float* als  = first ? d0.als    : d1.als;
  const float* ald  = first ? d0.ald    : d1.ald;
  const float* hsrc = first ? d0.h      : d1.h;
  unsigned short* zh = (first ? d0.zhi : d1.zhi) + (size_t)n * (HEADS * HID);
  unsigned short* zl = (first ? d0.zlo : d1.zlo) + (size_t)n * (HEADS * HID);

  const int base = indptr[n];
  const int deg = indptr[n + 1] - base;
  if (deg == 0) {
#pragma unroll
    for (int hh = 0; hh < HEADS; hh++) {
      *(unsigned*)(zh + hh * HID + 2 * lane) = 0u;
      *(unsigned*)(zl + hh * HID + 2 * lane) = 0u;
    }
    return;
  }
  const int eh = lane >> 3, h = lane & 7;
  const float aldn = ald[(size_t)n * HEADS + h];
  const int nch = (deg + 7) >> 3;
  const int ncc = nch < 4 ? nch : 4;

  int sc[4];
  float vc[4];
#pragma unroll
  for (int c = 0; c < 4; c++) {
    int e = c * 8 + eh;
    sc[c] = (c < ncc && e < deg) ? srcs[base + e] : -1;
  }
#pragma unroll
  for (int c = 0; c < 4; c++)
    vc[c] = (sc[c] >= 0) ? als[(size_t)sc[c] * HEADS + h] : 0.f;
  float den = 0.f;
#pragma unroll
  for (int c = 0; c < 4; c++) {
    float v = vc[c] + aldn;
    v = v > 0.f ? v : 0.2f * v;
    float ex = (sc[c] >= 0) ? expf(v) : 0.f;
    vc[c] = ex;
    den += ex;
  }
  for (int e0 = 32; e0 < deg; e0 += 8) {
    int e = e0 + eh;
    if (e < deg) {
      int s = srcs[base + e];
      float v = als[(size_t)s * HEADS + h] + aldn;
      v = v > 0.f ? v : 0.2f * v;
      den += expf(v);
    }
  }
  den += __shfl_xor(den, 8);
  den += __shfl_xor(den, 16);
  den += __shfl_xor(den, 32);

  float acc[16];
#pragma unroll
  for (int i = 0; i < 16; i++) acc[i] = 0.f;
#pragma unroll
  for (int c = 0; c < 4; c++) {
    if (c >= ncc) break;
    const int rem = deg - c * 8;
    const int elim = rem < 8 ? rem : 8;
#pragma unroll
    for (int half = 0; half < 2; half++) {
      if (half * 4 >= elim) break;
      int sj[4];
#pragma unroll
      for (int j = 0; j < 4; j++) {
        int s = __shfl(sc[c], (half * 4 + j) * 8);
        sj[j] = s < 0 ? 0 : s;
      }
      float2 hv[4];
#pragma unroll
      for (int j = 0; j < 4; j++)
        hv[j] = *(const float2*)(hsrc + (size_t)sj[j] * HID + 2 * lane);
#pragma unroll
      for (int j = 0; j < 4; j++) {
#pragma unroll
        for (int hh = 0; hh < 8; hh++) {
          float a = __shfl(vc[c], (half * 4 + j) * 8 + hh);
          acc[2 * hh]     = fmaf(a, hv[j].x, acc[2 * hh]);
          acc[2 * hh + 1] = fmaf(a, hv[j].y, acc[2 * hh + 1]);
        }
      }
    }
  }
  for (int e0 = 32; e0 < deg; e0 += 8) {
    int e = e0 + eh;
    int s = (e < deg) ? srcs[base + e] : -1;
    float ex = 0.f;
    if (s >= 0) {
      float v = als[(size_t)s * HEADS + h] + aldn;
      v = v > 0.f ? v : 0.2f * v;
      ex = expf(v);
    }
    int elim = deg - e0; if (elim > 8) elim = 8;
    for (int e8 = 0; e8 < elim; e8++) {
      int ss = __shfl(s, e8 * 8);
      const float2 hvt = *(const float2*)(hsrc + (size_t)ss * HID + 2 * lane);
#pragma unroll
      for (int hh = 0; hh < 8; hh++) {
        float a = __shfl(ex, e8 * 8 + hh);
        acc[2 * hh]     = fmaf(a, hvt.x, acc[2 * hh]);
        acc[2 * hh + 1] = fmaf(a, hvt.y, acc[2 * hh + 1]);
      }
    }
  }
#pragma unroll
  for (int hh = 0; hh < 8; hh++) {
    float dh = __shfl(den, hh);
    float inv = 1.f / (dh + 1e-16f);
    float x0 = acc[2 * hh] * inv;
    float x1 = acc[2 * hh + 1] * inv;
    unsigned short h0 = bf16_rne(x0), h1 = bf16_rne(x1);
    unsigned short l0 = bf16_rne(x0 - bf16f(h0)), l1 = bf16_rne(x1 - bf16f(h1));
    *(unsigned*)(zh + hh * HID + 2 * lane) = (unsigned)h0 | ((unsigned)h1 << 16);
    *(unsigned*)(zl + hh * HID + 2 * lane) = (unsigned)l0 | ((unsigned)l1 << 16);
  }
}

// ================= MFMA bf16x4-split GEMM, GRID SPLIT-K -> P (proven R10) =================
struct MSeg {
  const unsigned short* Ahi; const unsigned short* Alo;
  const unsigned short* Bhi; const unsigned short* Blo;
  int M; int yb;
};

__global__ __launch_bounds__(256, 2) void gemm_mfma_splitk(
    MSeg s0, MSeg s1, float* __restrict__ P, int Mtot, int KS)
{
  __shared__ __align__(16) unsigned short smem[12288];
  const int tid = threadIdx.x;
  const unsigned short *Ahi, *Alo, *Bhi, *Blo; int M, ytile, rowbase;
  if ((int)blockIdx.x < s0.yb) {
    Ahi = s0.Ahi; Alo = s0.Alo; Bhi = s0.Bhi; Blo = s0.Blo;
    M = s0.M; ytile = blockIdx.x; rowbase = 0;
  } else {
    Ahi = s1.Ahi; Alo = s1.Alo; Bhi = s1.Bhi; Blo = s1.Blo;
    M = s1.M; ytile = blockIdx.x - s0.yb; rowbase = s0.yb * 64;
  }
  const int bm = ytile * 64;
  const int kchunk = 1024 / KS;
  const int kbeg = blockIdx.y * kchunk;
  const int nks = kchunk / 32;

  const int sr = tid >> 2;
  const int sg = tid & 3;
  const int g1 = sg ^ ((sr >> 1) & 3);
  const int sr2 = sr + 64;
  const int g2 = sg ^ ((sr2 >> 1) & 3);
  const int aslot  = sr * 32 + g1 * 8;
  const int bslotA = sr * 32 + g1 * 8;
  const int bslotB = sr2 * 32 + g2 * 8;
  const unsigned short* gA  = Ahi + (size_t)(bm + sr) * 1024 + kbeg + sg * 8;
  const unsigned short* gAl = Alo + (size_t)(bm + sr) * 1024 + kbeg + sg * 8;
  const unsigned short* gB0 = Bhi + (size_t)sr  * 1024 + kbeg + sg * 8;
  const unsigned short* gB1 = Bhi + (size_t)sr2 * 1024 + kbeg + sg * 8;
  const unsigned short* gC0 = Blo + (size_t)sr  * 1024 + kbeg + sg * 8;
  const unsigned short* gC1 = Blo + (size_t)sr2 * 1024 + kbeg + sg * 8;

  const int l = tid & 63;
  const int w = tid >> 6;
  const int kg = l >> 4;
  int aoff[4], boff[2];
#pragma unroll
  for (int mi = 0; mi < 4; mi++) {
    int r = mi * 16 + (l & 15);
    aoff[mi] = r * 32 + (kg ^ ((r >> 1) & 3)) * 8;
  }
#pragma unroll
  for (int ni = 0; ni < 2; ni++) {
    int r = w * 32 + ni * 16 + (l & 15);
    boff[ni] = r * 32 + (kg ^ ((r >> 1) & 3)) * 8;
  }

  f32x4 acc[4][2];
  const f32x4 z4 = {0.f, 0.f, 0.f, 0.f};
#pragma unroll
  for (int mi = 0; mi < 4; mi++)
#pragma unroll
    for (int ni = 0; ni < 2; ni++) acc[mi][ni] = z4;

  uint4 rA  = *(const uint4*)gA;
  uint4 rAl = *(const uint4*)gAl;
  uint4 rB0 = *(const uint4*)gB0;
  uint4 rB1 = *(const uint4*)gB1;
  uint4 rC0 = *(const uint4*)gC0;
  uint4 rC1 = *(const uint4*)gC1;

  for (int ks = 0; ks < nks; ks++) {
    *(uint4*)&smem[aslot]         = rA;
    *(uint4*)&smem[2048 + aslot]  = rAl;
    *(uint4*)&smem[4096 + bslotA] = rB0;
    *(uint4*)&smem[4096 + bslotB] = rB1;
    *(uint4*)&smem[8192 + bslotA] = rC0;
    *(uint4*)&smem[8192 + bslotB] = rC1;
    __syncthreads();
    if (ks < nks - 1) {
      const int k0 = (ks + 1) * 32;
      rA  = *(const uint4*)(gA  + k0);
      rAl = *(const uint4*)(gAl + k0);
      rB0 = *(const uint4*)(gB0 + k0);
      rB1 = *(const uint4*)(gB1 + k0);
      rC0 = *(const uint4*)(gC0 + k0);
      rC1 = *(const uint4*)(gC1 + k0);
    }
    s16x8 bh0 = *(const s16x8*)&smem[4096 + boff[0]];
    s16x8 bh1 = *(const s16x8*)&smem[4096 + boff[1]];
    s16x8 bl0 = *(const s16x8*)&smem[8192 + boff[0]];
    s16x8 bl1 = *(const s16x8*)&smem[8192 + boff[1]];
#pragma unroll
    for (int mi = 0; mi < 4; mi++) {
      s16x8 ah = *(const s16x8*)&smem[aoff[mi]];
      s16x8 al = *(const s16x8*)&smem[2048 + aoff[mi]];
      acc[mi][0] = __builtin_amdgcn_mfma_f32_16x16x32_bf16(ah, bh0, acc[mi][0], 0, 0, 0);
      acc[mi][1] = __builtin_amdgcn_mfma_f32_16x16x32_bf16(ah, bh1, acc[mi][1], 0, 0, 0);
      acc[mi][0] = __builtin_amdgcn_mfma_f32_16x16x32_bf16(ah, bl0, acc[mi][0], 0, 0, 0);
      acc[mi][1] = __builtin_amdgcn_mfma_f32_16x16x32_bf16(ah, bl1, acc[mi][1], 0, 0, 0);
      acc[mi][0] = __builtin_amdgcn_mfma_f32_16x16x32_bf16(al, bh0, acc[mi][0], 0, 0, 0);
      acc[mi][1] = __builtin_amdgcn_mfma_f32_16x16x32_bf16(al, bh1, acc[mi][1], 0, 0, 0);
      acc[mi][0] = __builtin_amdgcn_mfma_f32_16x16x32_bf16(al, bl0, acc[mi][0], 0, 0, 0);
      acc[mi][1] = __builtin_amdgcn_mfma_f32_16x16x32_bf16(al, bl1, acc[mi][1], 0, 0, 0);
    }
    __syncthreads();
  }

  const int q = l >> 4, cl = l & 15;
  const size_t prow0 = (size_t)blockIdx.y * Mtot + rowbase + bm;
#pragma unroll
  for (int ni = 0; ni < 2; ni++) {
    const int col = w * 32 + ni * 16 + cl;
#pragma unroll
    for (int mi = 0; mi < 4; mi++) {
      const int r0 = mi * 16 + q * 4;
      const f32x4 v = acc[mi][ni];
#pragma unroll
      for (int j = 0; j < 4; j++) {
        const int r = r0 + j;
        if (bm + r < M) P[(prow0 + r) * HID + col] = v[j];
      }
    }
  }
}

// ======= reduce KS partials + scale/bias/relu + NEXT-LAYER attention logits (fused) ========
struct RSegA {
  float* out; const float* bias; int M; int rowbase;
  const float* va; const float* vb;
  float* ala; float* alb;
};

__global__ __launch_bounds__(256) void reduce_epi_al(
    const float* __restrict__ P, int Mtot, int KS, float scale, int do_relu,
    RSegA s0, RSegA s1)
{
  int idx = blockIdx.x * 256 + threadIdx.x;
  if (idx >= Mtot * 32) return;
  int r = idx >> 5;
  int c = (idx & 31) << 2;
  float* outp; const float* bias; int rl;
  const float* va; const float* vb; float* ala; float* alb;
  if (s1.M > 0 && r >= s1.rowbase) {
    rl = r - s1.rowbase; if (rl >= s1.M) return;
    outp = s1.out; bias = s1.bias; va = s1.va; vb = s1.vb; ala = s1.ala; alb = s1.alb;
  } else {
    rl = r; if (rl >= s0.M) return;
    outp = s0.out; bias = s0.bias; va = s0.va; vb = s0.vb; ala = s0.ala; alb = s0.alb;
  }
  float4 acc = make_float4(0.f, 0.f, 0.f, 0.f);
  for (int z = 0; z < KS; z++) {
    const float4 v = *(const float4*)(P + ((size_t)z * Mtot + r) * HID + c);
    acc.x += v.x; acc.y += v.y; acc.z += v.z; acc.w += v.w;
  }
  const float4 b = *(const float4*)(bias + c);
  acc.x = acc.x * scale + b.x;
  acc.y = acc.y * scale + b.y;
  acc.z = acc.z * scale + b.z;
  acc.w = acc.w * scale + b.w;
  if (do_relu) {
    acc.x = fmaxf(acc.x, 0.f); acc.y = fmaxf(acc.y, 0.f);
    acc.z = fmaxf(acc.z, 0.f); acc.w = fmaxf(acc.w, 0.f);
  }
  *(float4*)(outp + (size_t)rl * HID + c) = acc;

  const float av[4] = {acc.x, acc.y, acc.z, acc.w};
  float pA[8], pB[8];
#pragma unroll
  for (int i = 0; i < 8; i++) { pA[i] = 0.f; pB[i] = 0.f; }
#pragma unroll
  for (int j = 0; j < 4; j++) {
    const float4 a0 = *(const float4*)(va + (c + j) * 8);
    const float4 a1 = *(const float4*)(va + (c + j) * 8 + 4);
    const float4 b0 = *(const float4*)(vb + (c + j) * 8);
    const float4 b1 = *(const float4*)(vb + (c + j) * 8 + 4);
    pA[0] = fmaf(av[j], a0.x, pA[0]); pA[1] = fmaf(av[j], a0.y, pA[1]);
    pA[2] = fmaf(av[j], a0.z, pA[2]); pA[3] = fmaf(av[j], a0.w, pA[3]);
    pA[4] = fmaf(av[j], a1.x, pA[4]); pA[5] = fmaf(av[j], a1.y, pA[5]);
    pA[6] = fmaf(av[j], a1.z, pA[6]); pA[7] = fmaf(av[j], a1.w, pA[7]);
    pB[0] = fmaf(av[j], b0.x, pB[0]); pB[1] = fmaf(av[j], b0.y, pB[1]);
    pB[2] = fmaf(av[j], b0.z, pB[2]); pB[3] = fmaf(av[j], b0.w, pB[3]);
    pB[4] = fmaf(av[j], b1.x, pB[4]); pB[5] = fmaf(av[j], b1.y, pB[5]);
    pB[6] = fmaf(av[j], b1.z, pB[6]); pB[7] = fmaf(av[j], b1.w, pB[7]);
  }
#pragma unroll
  for (int off = 16; off >= 1; off >>= 1) {
#pragma unroll
    for (int i = 0; i < 8; i++) {
      pA[i] += __shfl_xor(pA[i], off);
      pB[i] += __shfl_xor(pB[i], off);
    }
  }
  if ((threadIdx.x & 31) == 0) {
    *(float4*)(ala + (size_t)rl * 8)     = make_float4(pA[0], pA[1], pA[2], pA[3]);
    *(float4*)(ala + (size_t)rl * 8 + 4) = make_float4(pA[4], pA[5], pA[6], pA[7]);
    *(float4*)(alb + (size_t)rl * 8)     = make_float4(pB[0], pB[1], pB[2], pB[3]);
    *(float4*)(alb + (size_t)rl * 8 + 4) = make_float4(pB[4], pB[5], pB[6], pB[7]);
  }
}

// ======= reduce KS partials + scale/bias + POOL dot + finalize (SLOTTED gsum) ==============
// R11 postmortem: single gsum[16] cacheline took 20K atomics -> 283us serialization.
// Now gsum[GSLOTS][16]; block accumulates into slot (blockIdx.x & (GSLOTS-1)); last-ticket
// block's 256 threads each fold one slot into LDS tot[16] via LDS atomics.
struct RSegP { const float* bias; int M; int rowbase; int isA; };

__global__ __launch_bounds__(256) void reduce_epi_pool(
    const float* __restrict__ P, int Mtot, int KS, float scale,
    RSegP s0, RSegP s1,
    const float* __restrict__ fc_w, const float* __restrict__ fc_b,
    const int* __restrict__ batch_a, const int* __restrict__ batch_b,
    float* __restrict__ gsum, int* __restrict__ ticket,
    float* __restrict__ out, int na, int nb, int ng, int tot_blocks)
{
  __shared__ int lastf;
  __shared__ float tot[16];
  const int idx = blockIdx.x * 256 + threadIdx.x;
  bool ok = idx < Mtot * 32;
  int r = 0, c = 0, rl = 0, isA = 0;
  const float* bias = s0.bias;
  if (ok) {
    r = idx >> 5;
    c = (idx & 31) << 2;
    if (s1.M > 0 && r >= s1.rowbase) {
      rl = r - s1.rowbase; isA = s1.isA; bias = s1.bias;
      if (rl >= s1.M) ok = false;
    } else {
      rl = r; isA = s0.isA; bias = s0.bias;
      if (rl >= s0.M) ok = false;
    }
  }
  float part = 0.f;
  if (ok) {
    float4 acc = make_float4(0.f, 0.f, 0.f, 0.f);
    for (int z = 0; z < KS; z++) {
      const float4 v = *(const float4*)(P + ((size_t)z * Mtot + r) * HID + c);
      acc.x += v.x; acc.y += v.y; acc.z += v.z; acc.w += v.w;
    }
    const float4 b = *(const float4*)(bias + c);
    acc.x = acc.x * scale + b.x;
    acc.y = acc.y * scale + b.y;
    acc.z = acc.z * scale + b.z;
    acc.w = acc.w * scale + b.w;
    const float* wseg = fc_w + (isA ? 0 : HID) + c;
    part = acc.x * wseg[0] + acc.y * wseg[1] + acc.z * wseg[2] + acc.w * wseg[3];
  }
#pragma unroll
  for (int off = 16; off >= 1; off >>= 1) part += __shfl_xor(part, off);
  if (ok && (threadIdx.x & 31) == 0) {
    const int bt = isA ? batch_a[rl] : batch_b[rl];
    const int slot = blockIdx.x & (GSLOTS - 1);
    atomicAdd(&gsum[slot * 16 + (isA ? 0 : 8) + bt], part);
  }
  __syncthreads();
  if (threadIdx.x == 0) {
    __threadfence();
    int tk = atomicAdd(ticket, 1);
    lastf = (tk == tot_blocks - 1);
  }
  __syncthreads();
  if (lastf) {
    if (threadIdx.x < 16) tot[threadIdx.x] = 0.f;
    __syncthreads();
    // each thread folds one slot (coherent atomic reads, parallel across threads)
    {
      const int slot = threadIdx.x;
      float loc[16];
#pragma unroll
      for (int j = 0; j < 16; j++) loc[j] = atomicAdd(&gsum[slot * 16 + j], 0.f);
#pragma unroll
      for (int j = 0; j < 16; j++) atomicAdd(&tot[j], loc[j]);
    }
    __syncthreads();
    int g = threadIdx.x;
    if (g < ng) {
      int l, rr, lo;
      l = 0; rr = na; while (l < rr) { int m = (l + rr) >> 1; if (batch_a[m] < g) l = m + 1; else rr = m; } lo = l;
      rr = na; while (l < rr) { int m = (l + rr) >> 1; if (batch_a[m] < g + 1) l = m + 1; else rr = m; }
      int ca = l - lo; if (ca < 1) ca = 1;
      l = 0; rr = nb; while (l < rr) { int m = (l + rr) >> 1; if (batch_b[m] < g) l = m + 1; else rr = m; } lo = l;
      rr = nb; while (l < rr) { int m = (l + rr) >> 1; if (batch_b[m] < g + 1) l = m + 1; else rr = m; }
      int cb = l - lo; if (cb < 1) cb = 1;
      out[g] = tot[g] / (float)ca + tot[8 + g] / (float)cb + fc_b[0];
    }
  }
}

extern "C" void kernel_launch(void* const* d_in, const int* in_sizes, int n_in,
                              void* d_out, int out_size, void* d_ws, size_t ws_size,
                              hipStream_t stream)
{
  const float* x_a = (const float*)d_in[0];
  const float* x_b = (const float*)d_in[1];
  const int* edge_ab = (const int*)d_in[2];
  const int* edge_ba = (const int*)d_in[3];
  const int* batch_a = (const int*)d_in[4];
  const int* batch_b = (const int*)d_in[5];
  const float* lin_a_w = (const float*)d_in[6];
  const float* lin_a_b = (const float*)d_in[7];
  const float* lin_b_w = (const float*)d_in[8];
  const float* lin_b_b = (const float*)d_in[9];
  const float* fc_w = (const float*)d_in[10];
  const float* fc_b = (const float*)d_in[11];

  const int NA = in_sizes[4];
  const int NB = in_sizes[5];
  const int E  = in_sizes[2] / 2;
  const int FA = in_sizes[0] / NA;
  const int FB = in_sizes[1] / NB;
  const int NG = out_size;
  const int NMAX = NA > NB ? NA : NB;
  const int NAp = (NA + 127) & ~127, NBp = (NB + 127) & ~127;
  const int NMAXp = NAp > NBp ? NAp : NBp;
  const int Mtot = NAp + NBp;

  // ---- size model (mirrors carve order) ----
  auto al256 = [](size_t b) { return (b + 255) & ~(size_t)255; };
  size_t fixed = 0;
  fixed += 2 * al256((size_t)NAp * HID * 4) + 2 * al256((size_t)NBp * HID * 4);
  fixed += 2 * al256((size_t)NMAXp * 1024 * 2);
  fixed += al256((size_t)8 * 131072 * 2);
  fixed += 2 * al256((size_t)FA * HID * 2) + 2 * al256((size_t)FB * HID * 2);
  fixed += al256((size_t)8 * HID * HEADS * 4);
  fixed += 2 * al256((size_t)NAp * HEADS * 4) + 2 * al256((size_t)NBp * HEADS * 4);
  fixed += al256(((size_t)4 * NMAX + GSLOTS * 16 + 8) * 4);
  fixed += al256((size_t)(NB + 1) * 4) + al256((size_t)(NA + 1) * 4);
  fixed += 2 * al256((size_t)E * 4);
  fixed += 8192;
  const size_t zba_sz = 2 * al256((size_t)NAp * 1024 * 2);
  const size_t pslice = al256((size_t)Mtot * HID * 4);

  int KS = 4; bool dual = true;
  if (fixed + zba_sz + 4 * pslice <= ws_size)      { dual = true;  KS = 4; }
  else if (fixed + zba_sz + 2 * pslice <= ws_size) { dual = true;  KS = 2; }
  else if (fixed + 4 * pslice <= ws_size)          { dual = false; KS = 4; }
  else if (fixed + 2 * pslice <= ws_size)          { dual = false; KS = 2; }
  else if (fixed + 1 * pslice <= ws_size)          { dual = false; KS = 1; }
  else return;  // loud failure (out stays poisoned)

  char* w = (char*)d_ws;
  auto carve = [&](size_t bytes) -> void* {
    void* p = (void*)w;
    w += (bytes + 255) & ~(size_t)255;
    return p;
  };
  float* ha0 = (float*)carve((size_t)NAp * HID * 4);
  float* hb0 = (float*)carve((size_t)NBp * HID * 4);
  float* ha1 = (float*)carve((size_t)NAp * HID * 4);
  float* hb1 = (float*)carve((size_t)NBp * HID * 4);
  unsigned short* zab_hi = (unsigned short*)carve((size_t)NMAXp * 1024 * 2);
  unsigned short* zab_lo = (unsigned short*)carve((size_t)NMAXp * 1024 * 2);
  unsigned short* zba_hi = dual ? (unsigned short*)carve((size_t)NAp * 1024 * 2) : zab_hi;
  unsigned short* zba_lo = dual ? (unsigned short*)carve((size_t)NAp * 1024 * 2) : zab_lo;
  float* P = (float*)carve((size_t)KS * Mtot * HID * 4);
  unsigned short* WT = (unsigned short*)carve((size_t)8 * 131072 * 2);
  unsigned short* wa_hi = (unsigned short*)carve((size_t)FA * HID * 2);
  unsigned short* wa_lo = (unsigned short*)carve((size_t)FA * HID * 2);
  unsigned short* wb_hi = (unsigned short*)carve((size_t)FB * HID * 2);
  unsigned short* wb_lo = (unsigned short*)carve((size_t)FB * HID * 2);
  float* vv  = (float*)carve((size_t)8 * HID * HEADS * 4);
  float* als_ab = (float*)carve((size_t)NAp * HEADS * 4);
  float* ald_ab = (float*)carve((size_t)NBp * HEADS * 4);
  float* als_ba = (float*)carve((size_t)NBp * HEADS * 4);
  float* ald_ba = (float*)carve((size_t)NAp * HEADS * 4);
  int* csrblk = (int*)carve(((size_t)4 * NMAX + GSLOTS * 16 + 8) * 4);
  int* indptr_ab = (int*)carve((size_t)(NB + 1) * 4);
  int* indptr_ba = (int*)carve((size_t)(NA + 1) * 4);
  int* srcs_ab   = (int*)carve((size_t)E * 4);
  int* srcs_ba   = (int*)carve((size_t)E * 4);
  if ((size_t)(w - (char*)d_ws) > ws_size) return;

  int* cnt_ab = csrblk;
  int* cnt_ba = csrblk + NMAX;
  int* cur_ab = csrblk + 2 * NMAX;
  int* cur_ba = csrblk + 3 * NMAX;
  float* gsum = (float*)(csrblk + 4 * NMAX);
  int* ticket = csrblk + 4 * NMAX + GSLOTS * 16;

  hipMemsetAsync(csrblk, 0, ((size_t)4 * NMAX + GSLOTS * 16 + 8) * 4, stream);

  // ---- fused weight prep (tiled transposes) + histogram ----
  PrepArgs pa;
  const int wi_idx[8] = {12, 13, 17, 18, 22, 23, 27, 28};
  const int ai_idx[8] = {14, 15, 19, 20, 24, 25, 29, 30};
  for (int i = 0; i < 8; i++) {
    pa.W[i] = (const float*)d_in[wi_idx[i]];
    pa.a[i] = (const float*)d_in[ai_idx[i]];
    pa.v[i] = vv + (size_t)i * HID * HEADS;
  }
  for (int g = 0; g < 4; g++) {
    pa.WThi[g] = WT + (size_t)g * 131072;
    pa.WTlo[g] = WT + (size_t)(4 + g) * 131072;
  }
  PrepX px;
  px.lwa = lin_a_w; px.lwb = lin_b_w;
  px.wa_hi = wa_hi; px.wa_lo = wa_lo; px.wb_hi = wb_hi; px.wb_lo = wb_lo;
  px.KA = FA; px.KB = FB;
  px.nta = (FA / 64) * 2;
  px.ntb = (FB / 64) * 2;
  const int hist_b = (2 * E + 255) / 256;
  prep_hist<<<160 + px.nta + px.ntb + hist_b, 256, 0, stream>>>(
      pa, px, edge_ab + E, edge_ba + E, cnt_ab, cnt_ba, E);
  scan2<<<2, 1024, 0, stream>>>(cnt_ab, cnt_ba, indptr_ab, indptr_ba, NB, NA);
  scatter2<<<(2 * E + 255) / 256, 256, 0, stream>>>(
      edge_ab, edge_ba, indptr_ab, indptr_ba, cur_ab, cur_ba, srcs_ab, srcs_ba, E);

  // ---- input linears: MFMA split GEMM with fused bias+relu ----
  {
    ISeg sa = {x_a, wa_hi, wa_lo, ha0, lin_a_b, NA, FA, NAp / 64};
    ISeg sb = {x_b, wb_hi, wb_lo, hb0, lin_b_b, NB, FB, NBp / 64};
    gemm_mfma_in<<<NAp / 64 + NBp / 64, 256, 0, stream>>>(sa, sb);
  }

  const int red_grid = (Mtot * 32 + 255) / 256;

  // ---- layer-0 attention logits (only standalone al launch) ----
  compute_al4<<<((2 * (NA + NB)) * HEADS + 255) / 256, 256, 0, stream>>>(
      ha0, hb0, vv, als_ab, ald_ab, als_ba, ald_ba, NA, NB);

  GDir dab0 = {indptr_ab, srcs_ab, als_ab, ald_ab, ha0, zab_hi, zab_lo};
  GDir dba0 = {indptr_ba, srcs_ba, als_ba, ald_ba, hb0, zba_hi, zba_lo};
  MSeg mab0 = {zab_hi, zab_lo, WT + (size_t)0 * 131072, WT + (size_t)4 * 131072, NB, NBp / 64};
  MSeg mba0 = {zba_hi, zba_lo, WT + (size_t)1 * 131072, WT + (size_t)5 * 131072, NA, NAp / 64};
  const float* v1 = vv + (size_t)4 * HID * HEADS;

  GDir dab1 = {indptr_ab, srcs_ab, als_ab, ald_ab, ha1, zab_hi, zab_lo};
  GDir dba1 = {indptr_ba, srcs_ba, als_ba, ald_ba, hb1, zba_hi, zba_lo};
  MSeg mab1 = {zab_hi, zab_lo, WT + (size_t)2 * 131072, WT + (size_t)6 * 131072, NB, NBp / 64};
  MSeg mba1 = {zba_hi, zba_lo, WT + (size_t)3 * 131072, WT + (size_t)7 * 131072, NA, NAp / 64};

  if (dual) {
    // layer 0
    gat_edge2<<<(NB + NA + 3) / 4, 256, 0, stream>>>(dab0, dba0, NB, NB + NA);
    gemm_mfma_splitk<<<dim3(NBp / 64 + NAp / 64, KS), 256, 0, stream>>>(mab0, mba0, P, Mtot, KS);
    RSegA r0 = {hb1, (const float*)d_in[16], NB, 0,
                v1 + 1024, v1 + 2048, ald_ab, als_ba};
    RSegA r1 = {ha1, (const float*)d_in[21], NA, NBp,
                v1, v1 + 3072, als_ab, ald_ba};
    reduce_epi_al<<<red_grid, 256, 0, stream>>>(P, Mtot, KS, 1.f / HEADS, 1, r0, r1);
    // layer 1
    gat_edge2<<<(NB + NA + 3) / 4, 256, 0, stream>>>(dab1, dba1, NB, NB + NA);
    gemm_mfma_splitk<<<dim3(NBp / 64 + NAp / 64, KS), 256, 0, stream>>>(mab1, mba1, P, Mtot, KS);
    RSegP p0 = {(const float*)d_in[26], NB, 0, 0};
    RSegP p1 = {(const float*)d_in[31], NA, NBp, 1};
    reduce_epi_pool<<<red_grid, 256, 0, stream>>>(P, Mtot, KS, 1.f / HEADS, p0, p1,
        fc_w, fc_b, batch_a, batch_b, gsum, ticket, (float*)d_out, NA, NB, NG, red_grid);
  } else {
    const RSegA ranull = {nullptr, nullptr, 0, 0, nullptr, nullptr, nullptr, nullptr};
    gat_edge2<<<(NB + 3) / 4, 256, 0, stream>>>(dab0, dab0, NB, NB);
    {
      MSeg mz = {nullptr, nullptr, nullptr, nullptr, 0, 0};
      gemm_mfma_splitk<<<dim3(NBp / 64, KS), 256, 0, stream>>>(mab0, mz, P, NBp, KS);
      RSegA r0 = {hb1, (const float*)d_in[16], NB, 0, v1 + 1024, v1 + 2048, ald_ab, als_ba};
      reduce_epi_al<<<(NBp * 32 + 255) / 256, 256, 0, stream>>>(P, NBp, KS, 1.f / HEADS, 1, r0, ranull);
    }
    gat_edge2<<<(NA + 3) / 4, 256, 0, stream>>>(dba0, dba0, NA, NA);
    {
      MSeg mz = {nullptr, nullptr, nullptr, nullptr, 0, 0};
      gemm_mfma_splitk<<<dim3(NAp / 64, KS), 256, 0, stream>>>(mba0, mz, P, NAp, KS);
      RSegA r1 = {ha1, (const float*)d_in[21], NA, 0, v1, v1 + 3072, als_ab, ald_ba};
      reduce_epi_al<<<(NAp * 32 + 255) / 256, 256, 0, stream>>>(P, NAp, KS, 1.f / HEADS, 1, r1, ranull);
    }
    const int gb1 = (NBp * 32 + 255) / 256;
    const int ga1 = (NAp * 32 + 255) / 256;
    const RSegP pnull = {nullptr, 0, 0, 0};
    gat_edge2<<<(NB + 3) / 4, 256, 0, stream>>>(dab1, dab1, NB, NB);
    {
      MSeg mz = {nullptr, nullptr, nullptr, nullptr, 0, 0};
      gemm_mfma_splitk<<<dim3(NBp / 64, KS), 256, 0, stream>>>(mab1, mz, P, NBp, KS);
      RSegP p0 = {(const float*)d_in[26], NB, 0, 0};
      reduce_epi_pool<<<gb1, 256, 0, stream>>>(P, NBp, KS, 1.f / HEADS, p0, pnull,
          fc_w, fc_b, batch_a, batch_b, gsum, ticket, (float*)d_out, NA, NB, NG, gb1 + ga1);
    }
    gat_edge2<<<(NA + 3) / 4, 256, 0, stream>>>(dba1, dba1, NA, NA);
    {
      MSeg mz = {nullptr, nullptr, nullptr, nullptr, 0, 0};
      gemm_mfma_splitk<<<dim3(NAp / 64, KS), 256, 0, stream>>>(mba1, mz, P, NAp, KS);
      RSegP p1 = {(const float*)d_in[31], NA, 0, 1};
      reduce_epi_pool<<<ga1, 256, 0, stream>>>(P, NAp, KS, 1.f / HEADS, p1, pnull,
          fc_w, fc_b, batch_a, batch_b, gsum, ticket, (float*)d_out, NA, NB, NG, gb1 + ga1);
    }
  }
}

// Round 13
// 382.380 us; speedup vs baseline: 1.6341x; 1.1677x over previous
//
#include <hip/hip_runtime.h>
#include <math.h>

#define HID 128
#define HEADS 8

typedef __attribute__((ext_vector_type(8))) short s16x8;
typedef __attribute__((ext_vector_type(4))) float f32x4;

__device__ __forceinline__ unsigned short bf16_rne(float x) {
  unsigned u = __float_as_uint(x);
  unsigned r = u + 0x7FFFu + ((u >> 16) & 1u);
  return (unsigned short)(r >> 16);
}
__device__ __forceinline__ float bf16f(unsigned short h) {
  return __uint_as_float(((unsigned)h) << 16);
}

// ====== fused prep: TILED transposes (layer W + input W) + make_v + histogram ==============
struct PrepArgs {
  const float* W[8];
  const float* a[8];
  unsigned short* WThi[4];
  unsigned short* WTlo[4];
  float* v[8];
};
struct PrepX {
  const float* lwa; const float* lwb;
  unsigned short *wa_hi, *wa_lo, *wb_hi, *wb_lo;
  int KA, KB, nta, ntb;
};

__global__ __launch_bounds__(256) void prep_hist(
    PrepArgs p, PrepX px,
    const int* __restrict__ dst_ab, const int* __restrict__ dst_ba,
    int* __restrict__ cnt_ab, int* __restrict__ cnt_ba, int E)
{
  __shared__ float tile[64][65];
  const int bid = blockIdx.x;
  const int tid = threadIdx.x;
  const int a = tid >> 2;          // tile row 0..63
  const int cg = (tid & 3) << 4;   // tile col group: 16 cols

  if (bid < 128) {  // layer W: per (mat g, head h, 64x64 tile) transpose (k,c)->(c,k) + split
    const int g = bid >> 5;
    const int rem = bid & 31;
    const int h = rem >> 2;
    const int t = rem & 3;
    const int k0 = (t >> 1) << 6, c0 = (t & 1) << 6;
    const float* src = p.W[2 * g] + (size_t)(k0 + a) * 1024 + h * 128 + c0 + cg;
#pragma unroll
    for (int i = 0; i < 16; i += 4) {
      const float4 v4 = *(const float4*)(src + i);
      tile[a][cg + i + 0] = v4.x; tile[a][cg + i + 1] = v4.y;
      tile[a][cg + i + 2] = v4.z; tile[a][cg + i + 3] = v4.w;
    }
    __syncthreads();
    const size_t ob = (size_t)(c0 + a) * 1024 + h * 128 + k0 + cg;
    unsigned hw[8], lw_[8];
#pragma unroll
    for (int i = 0; i < 8; i++) {
      float x0 = tile[cg + 2 * i][a];
      float x1 = tile[cg + 2 * i + 1][a];
      unsigned short h0 = bf16_rne(x0), h1 = bf16_rne(x1);
      unsigned short l0 = bf16_rne(x0 - bf16f(h0)), l1 = bf16_rne(x1 - bf16f(h1));
      hw[i]  = (unsigned)h0 | ((unsigned)h1 << 16);
      lw_[i] = (unsigned)l0 | ((unsigned)l1 << 16);
    }
    *(uint4*)(p.WThi[g] + ob)     = make_uint4(hw[0], hw[1], hw[2], hw[3]);
    *(uint4*)(p.WThi[g] + ob + 8) = make_uint4(hw[4], hw[5], hw[6], hw[7]);
    *(uint4*)(p.WTlo[g] + ob)     = make_uint4(lw_[0], lw_[1], lw_[2], lw_[3]);
    *(uint4*)(p.WTlo[g] + ob + 8) = make_uint4(lw_[4], lw_[5], lw_[6], lw_[7]);
  } else if (bid < 160) {  // make_v
    const int u = bid - 128;
    const int wi = u >> 2;
    const int gid = ((u & 3) << 8) + tid;
    const int k = gid >> 3, h = gid & 7;
    const float* wr = p.W[wi] + (size_t)k * (HEADS * HID) + h * HID;
    const float* ar = p.a[wi] + (size_t)h * HID;
    float s = 0.f;
    for (int c = 0; c < HID; c++) s = fmaf(wr[c], ar[c], s);
    p.v[wi][gid] = s;
  } else if (bid < 160 + px.nta + px.ntb) {  // input W transpose+split: [K][128] -> [128][K]
    const bool isa = (bid - 160) < px.nta;
    const int b = isa ? (bid - 160) : (bid - 160 - px.nta);
    const int K = isa ? px.KA : px.KB;
    const float* lw = isa ? px.lwa : px.lwb;
    unsigned short* ohi = isa ? px.wa_hi : px.wb_hi;
    unsigned short* olo = isa ? px.wa_lo : px.wb_lo;
    const int k0 = (b >> 1) << 6, c0 = (b & 1) << 6;
    const float* src = lw + (size_t)(k0 + a) * 128 + c0 + cg;
#pragma unroll
    for (int i = 0; i < 16; i += 4) {
      const float4 v4 = *(const float4*)(src + i);
      tile[a][cg + i + 0] = v4.x; tile[a][cg + i + 1] = v4.y;
      tile[a][cg + i + 2] = v4.z; tile[a][cg + i + 3] = v4.w;
    }
    __syncthreads();
    const size_t ob = (size_t)(c0 + a) * K + k0 + cg;
    unsigned hw[8], lw_[8];
#pragma unroll
    for (int i = 0; i < 8; i++) {
      float x0 = tile[cg + 2 * i][a];
      float x1 = tile[cg + 2 * i + 1][a];
      unsigned short h0 = bf16_rne(x0), h1 = bf16_rne(x1);
      unsigned short l0 = bf16_rne(x0 - bf16f(h0)), l1 = bf16_rne(x1 - bf16f(h1));
      hw[i]  = (unsigned)h0 | ((unsigned)h1 << 16);
      lw_[i] = (unsigned)l0 | ((unsigned)l1 << 16);
    }
    *(uint4*)(ohi + ob)     = make_uint4(hw[0], hw[1], hw[2], hw[3]);
    *(uint4*)(ohi + ob + 8) = make_uint4(hw[4], hw[5], hw[6], hw[7]);
    *(uint4*)(olo + ob)     = make_uint4(lw_[0], lw_[1], lw_[2], lw_[3]);
    *(uint4*)(olo + ob + 8) = make_uint4(lw_[4], lw_[5], lw_[6], lw_[7]);
  } else {  // degree histogram, both directions
    int gid = (bid - 160 - px.nta - px.ntb) * 256 + tid;
    if (gid < E) atomicAdd(&cnt_ab[dst_ab[gid]], 1);
    else if (gid < 2 * E) atomicAdd(&cnt_ba[dst_ba[gid - E]], 1);
  }
}

__global__ __launch_bounds__(1024) void scan2(
    const int* __restrict__ cnt_ab, const int* __restrict__ cnt_ba,
    int* __restrict__ ip_ab, int* __restrict__ ip_ba, int n_ab, int n_ba)
{
  const int* cnt = (blockIdx.x == 0) ? cnt_ab : cnt_ba;
  int* indptr = (blockIdx.x == 0) ? ip_ab : ip_ba;
  int n = (blockIdx.x == 0) ? n_ab : n_ba;
  __shared__ int parts[1024];
  const int tid = threadIdx.x;
  const int base = tid * 10;
  int local[10];
  int s = 0;
#pragma unroll
  for (int j = 0; j < 10; j++) {
    int v = (base + j < n) ? cnt[base + j] : 0;
    local[j] = v; s += v;
  }
  parts[tid] = s;
  __syncthreads();
  for (int off = 1; off < 1024; off <<= 1) {
    int v = (tid >= off) ? parts[tid - off] : 0;
    __syncthreads();
    parts[tid] += v;
    __syncthreads();
  }
  int ex = parts[tid] - s;
#pragma unroll
  for (int j = 0; j < 10; j++) {
    if (base + j < n) indptr[base + j] = ex;
    ex += local[j];
  }
  if (tid == 1023) indptr[n] = parts[1023];
}

__global__ __launch_bounds__(256) void scatter2(
    const int* __restrict__ edge_ab, const int* __restrict__ edge_ba,
    const int* __restrict__ ip_ab, const int* __restrict__ ip_ba,
    int* __restrict__ cur_ab, int* __restrict__ cur_ba,
    int* __restrict__ srcs_ab, int* __restrict__ srcs_ba, int E)
{
  int gid = blockIdx.x * 256 + threadIdx.x;
  if (gid < E) {
    int d = edge_ab[E + gid];
    int pos = ip_ab[d] + atomicAdd(&cur_ab[d], 1);
    srcs_ab[pos] = edge_ab[gid];
  } else if (gid < 2 * E) {
    int g = gid - E;
    int d = edge_ba[E + g];
    int pos = ip_ba[d] + atomicAdd(&cur_ba[d], 1);
    srcs_ba[pos] = edge_ba[g];
  }
}

// ===== input linears: MFMA bf16-split GEMM, fp32 A split on the fly, fused bias+relu =======
struct ISeg {
  const float* A;
  const unsigned short* Bhi; const unsigned short* Blo;
  float* out; const float* bias; int M; int K; int yb;
};

__global__ __launch_bounds__(256) void gemm_mfma_in(ISeg s0, ISeg s1)
{
  __shared__ __align__(16) unsigned short smem[12288];
  const int tid = threadIdx.x;
  const float* A; const unsigned short *Bhi, *Blo; const float* bias; float* out;
  int M, K, ytile;
  if ((int)blockIdx.x < s0.yb) {
    A = s0.A; Bhi = s0.Bhi; Blo = s0.Blo; out = s0.out; bias = s0.bias;
    M = s0.M; K = s0.K; ytile = blockIdx.x;
  } else {
    A = s1.A; Bhi = s1.Bhi; Blo = s1.Blo; out = s1.out; bias = s1.bias;
    M = s1.M; K = s1.K; ytile = blockIdx.x - s0.yb;
  }
  const int bm = ytile * 64;
  const int nks = K >> 5;

  const int sr = tid >> 2;
  const int sg = tid & 3;
  const int g1 = sg ^ ((sr >> 1) & 3);
  const int sr2 = sr + 64;
  const int g2 = sg ^ ((sr2 >> 1) & 3);
  const int aslot  = sr * 32 + g1 * 8;
  const int bslotA = sr * 32 + g1 * 8;
  const int bslotB = sr2 * 32 + g2 * 8;
  const int gr = bm + sr;
  const bool arow_ok = (gr < M);
  const float* gA = A + (size_t)gr * K + sg * 8;
  const unsigned short* gB0 = Bhi + (size_t)sr  * K + sg * 8;
  const unsigned short* gB1 = Bhi + (size_t)sr2 * K + sg * 8;
  const unsigned short* gC0 = Blo + (size_t)sr  * K + sg * 8;
  const unsigned short* gC1 = Blo + (size_t)sr2 * K + sg * 8;

  const int l = tid & 63;
  const int w = tid >> 6;
  const int kg = l >> 4;
  int aoff[4], boff[2];
#pragma unroll
  for (int mi = 0; mi < 4; mi++) {
    int r = mi * 16 + (l & 15);
    aoff[mi] = r * 32 + (kg ^ ((r >> 1) & 3)) * 8;
  }
#pragma unroll
  for (int ni = 0; ni < 2; ni++) {
    int r = w * 32 + ni * 16 + (l & 15);
    boff[ni] = r * 32 + (kg ^ ((r >> 1) & 3)) * 8;
  }

  f32x4 acc[4][2];
  const f32x4 z4 = {0.f, 0.f, 0.f, 0.f};
#pragma unroll
  for (int mi = 0; mi < 4; mi++)
#pragma unroll
    for (int ni = 0; ni < 2; ni++) acc[mi][ni] = z4;

  float4 fa0 = make_float4(0.f, 0.f, 0.f, 0.f), fa1 = fa0;
  if (arow_ok) { fa0 = *(const float4*)gA; fa1 = *(const float4*)(gA + 4); }
  uint4 rB0 = *(const uint4*)gB0;
  uint4 rB1 = *(const uint4*)gB1;
  uint4 rC0 = *(const uint4*)gC0;
  uint4 rC1 = *(const uint4*)gC1;

  for (int ks = 0; ks < nks; ks++) {
    {
      const float f[8] = {fa0.x, fa0.y, fa0.z, fa0.w, fa1.x, fa1.y, fa1.z, fa1.w};
      unsigned au[4], lu[4];
#pragma unroll
      for (int i = 0; i < 4; i++) {
        unsigned short h0 = bf16_rne(f[2 * i]);
        unsigned short l0 = bf16_rne(f[2 * i] - bf16f(h0));
        unsigned short h1 = bf16_rne(f[2 * i + 1]);
        unsigned short l1 = bf16_rne(f[2 * i + 1] - bf16f(h1));
        au[i] = (unsigned)h0 | ((unsigned)h1 << 16);
        lu[i] = (unsigned)l0 | ((unsigned)l1 << 16);
      }
      *(uint4*)&smem[aslot]        = make_uint4(au[0], au[1], au[2], au[3]);
      *(uint4*)&smem[2048 + aslot] = make_uint4(lu[0], lu[1], lu[2], lu[3]);
    }
    *(uint4*)&smem[4096 + bslotA] = rB0;
    *(uint4*)&smem[4096 + bslotB] = rB1;
    *(uint4*)&smem[8192 + bslotA] = rC0;
    *(uint4*)&smem[8192 + bslotB] = rC1;
    __syncthreads();
    if (ks < nks - 1) {
      const int k0 = (ks + 1) * 32;
      if (arow_ok) {
        fa0 = *(const float4*)(gA + k0);
        fa1 = *(const float4*)(gA + k0 + 4);
      }
      rB0 = *(const uint4*)(gB0 + k0);
      rB1 = *(const uint4*)(gB1 + k0);
      rC0 = *(const uint4*)(gC0 + k0);
      rC1 = *(const uint4*)(gC1 + k0);
    }
    s16x8 bh0 = *(const s16x8*)&smem[4096 + boff[0]];
    s16x8 bh1 = *(const s16x8*)&smem[4096 + boff[1]];
    s16x8 bl0 = *(const s16x8*)&smem[8192 + boff[0]];
    s16x8 bl1 = *(const s16x8*)&smem[8192 + boff[1]];
#pragma unroll
    for (int mi = 0; mi < 4; mi++) {
      s16x8 ah = *(const s16x8*)&smem[aoff[mi]];
      s16x8 al = *(const s16x8*)&smem[2048 + aoff[mi]];
      acc[mi][0] = __builtin_amdgcn_mfma_f32_16x16x32_bf16(ah, bh0, acc[mi][0], 0, 0, 0);
      acc[mi][1] = __builtin_amdgcn_mfma_f32_16x16x32_bf16(ah, bh1, acc[mi][1], 0, 0, 0);
      acc[mi][0] = __builtin_amdgcn_mfma_f32_16x16x32_bf16(ah, bl0, acc[mi][0], 0, 0, 0);
      acc[mi][1] = __builtin_amdgcn_mfma_f32_16x16x32_bf16(ah, bl1, acc[mi][1], 0, 0, 0);
      acc[mi][0] = __builtin_amdgcn_mfma_f32_16x16x32_bf16(al, bh0, acc[mi][0], 0, 0, 0);
      acc[mi][1] = __builtin_amdgcn_mfma_f32_16x16x32_bf16(al, bh1, acc[mi][1], 0, 0, 0);
      acc[mi][0] = __builtin_amdgcn_mfma_f32_16x16x32_bf16(al, bl0, acc[mi][0], 0, 0, 0);
      acc[mi][1] = __builtin_amdgcn_mfma_f32_16x16x32_bf16(al, bl1, acc[mi][1], 0, 0, 0);
    }
    __syncthreads();
  }

  const int q = l >> 4, cl = l & 15;
#pragma unroll
  for (int ni = 0; ni < 2; ni++) {
    const int col = w * 32 + ni * 16 + cl;
    const float bv = bias[col];
#pragma unroll
    for (int mi = 0; mi < 4; mi++) {
      const int r0 = bm + mi * 16 + q * 4;
      const f32x4 v = acc[mi][ni];
#pragma unroll
      for (int j = 0; j < 4; j++) {
        const int r = r0 + j;
        if (r < M) {
          float x = v[j] + bv;
          x = fmaxf(x, 0.f);
          out[(size_t)r * HID + col] = x;
        }
      }
    }
  }
}

// ================= 4 attention-logit arrays (layer 0 only) =================
__global__ __launch_bounds__(256) void compute_al4(
    const float* __restrict__ ha, const float* __restrict__ hb,
    const float* __restrict__ v4,
    float* __restrict__ o0, float* __restrict__ o1,
    float* __restrict__ o2, float* __restrict__ o3, int na, int nb)
{
  __shared__ float vsh[4 * HID * HEADS];
  for (int i = threadIdx.x; i < 4 * HID * HEADS; i += 256) vsh[i] = v4[i];
  __syncthreads();
  int gid = blockIdx.x * 256 + threadIdx.x;
  int row = gid >> 3, h = gid & 7;
  const float* hr; float* o; int q, rl;
  if (row < na)                    { q = 0; rl = row;               hr = ha; o = o0; }
  else if (row < na + nb)          { q = 1; rl = row - na;          hr = hb; o = o1; }
  else if (row < na + 2 * nb)      { q = 2; rl = row - na - nb;     hr = hb; o = o2; }
  else if (row < 2 * na + 2 * nb)  { q = 3; rl = row - na - 2 * nb; hr = ha; o = o3; }
  else return;
  hr += (size_t)rl * HID;
  const float* vq = vsh + q * HID * HEADS;
  float s = 0.f;
  for (int k = 0; k < HID; k++) s = fmaf(hr[k], vq[k * HEADS + h], s);
  o[(size_t)rl * HEADS + h] = s;
}

// ================= wave-per-node segment softmax + aggregation; writes bf16-split z =========
struct GDir {
  const int* indptr; const int* srcs;
  const float* als; const float* ald;
  const float* h;
  unsigned short* zhi; unsigned short* zlo;
};

__global__ __launch_bounds__(256) void gat_edge2(GDir d0, GDir d1, int n0, int ntot)
{
  const int w = threadIdx.x >> 6;
  const int lane = threadIdx.x & 63;
  const int g = blockIdx.x * 4 + w;
  if (g >= ntot) return;
  const bool first = (g < n0);
  const int n = first ? g : g - n0;
  const int* indptr = first ? d0.indptr : d1.indptr;
  const int* srcs   = first ? d0.srcs   : d1.srcs;
  const float* als  = first ? d0.als    : d1.als;
  const float* ald  = first ? d0.ald    : d1.ald;
  const float* hsrc = first ? d0.h      : d1.h;
  unsigned short* zh = (first ? d0.zhi : d1.zhi) + (size_t)n * (HEADS * HID);
  unsigned short* zl = (first ? d0.zlo : d1.zlo) + (size_t)n * (HEADS * HID);

  const int base = indptr[n];
  const int deg = indptr[n + 1] - base;
  if (deg == 0) {
#pragma unroll
    for (int hh = 0; hh < HEADS; hh++) {
      *(unsigned*)(zh + hh * HID + 2 * lane) = 0u;
      *(unsigned*)(zl + hh * HID + 2 * lane) = 0u;
    }
    return;
  }
  const int eh = lane >> 3, h = lane & 7;
  const float aldn = ald[(size_t)n * HEADS + h];
  const int nch = (deg + 7) >> 3;
  const int ncc = nch < 4 ? nch : 4;

  int sc[4];
  float vc[4];
#pragma unroll
  for (int c = 0; c < 4; c++) {
    int e = c * 8 + eh;
    sc[c] = (c < ncc && e < deg) ? srcs[base + e] : -1;
  }
#pragma unroll
  for (int c = 0; c < 4; c++)
    vc[c] = (sc[c] >= 0) ? als[(size_t)sc[c] * HEADS + h] : 0.f;
  float den = 0.f;
#pragma unroll
  for (int c = 0; c < 4; c++) {
    float v = vc[c] + aldn;
    v = v > 0.f ? v : 0.2f * v;
    float ex = (sc[c] >= 0) ? expf(v) : 0.f;
    vc[c] = ex;
    den += ex;
  }
  for (int e0 = 32; e0 < deg; e0 += 8) {
    int e = e0 + eh;
    if (e < deg) {
      int s = srcs[base + e];
      float v = als[(size_t)s * HEADS + h] + aldn;
      v = v > 0.f ? v : 0.2f * v;
      den += expf(v);
    }
  }
  den += __shfl_xor(den, 8);
  den += __shfl_xor(den, 16);
  den += __shfl_xor(den, 32);

  float acc[16];
#pragma unroll
  for (int i = 0; i < 16; i++) acc[i] = 0.f;
#pragma unroll
  for (int c = 0; c < 4; c++) {
    if (c >= ncc) break;
    const int rem = deg - c * 8;
    const int elim = rem < 8 ? rem : 8;
#pragma unroll
    for (int half = 0; half < 2; half++) {
      if (half * 4 >= elim) break;
      int sj[4];
#pragma unroll
      for (int j = 0; j < 4; j++) {
        int s = __shfl(sc[c], (half * 4 + j) * 8);
        sj[j] = s < 0 ? 0 : s;
      }
      float2 hv[4];
#pragma unroll
      for (int j = 0; j < 4; j++)
        hv[j] = *(const float2*)(hsrc + (size_t)sj[j] * HID + 2 * lane);
#pragma unroll
      for (int j = 0; j < 4; j++) {
#pragma unroll
        for (int hh = 0; hh < 8; hh++) {
          float a = __shfl(vc[c], (half * 4 + j) * 8 + hh);
          acc[2 * hh]     = fmaf(a, hv[j].x, acc[2 * hh]);
          acc[2 * hh + 1] = fmaf(a, hv[j].y, acc[2 * hh + 1]);
        }
      }
    }
  }
  for (int e0 = 32; e0 < deg; e0 += 8) {
    int e = e0 + eh;
    int s = (e < deg) ? srcs[base + e] : -1;
    float ex = 0.f;
    if (s >= 0) {
      float v = als[(size_t)s * HEADS + h] + aldn;
      v = v > 0.f ? v : 0.2f * v;
      ex = expf(v);
    }
    int elim = deg - e0; if (elim > 8) elim = 8;
    for (int e8 = 0; e8 < elim; e8++) {
      int ss = __shfl(s, e8 * 8);
      const float2 hvt = *(const float2*)(hsrc + (size_t)ss * HID + 2 * lane);
#pragma unroll
      for (int hh = 0; hh < 8; hh++) {
        float a = __shfl(ex, e8 * 8 + hh);
        acc[2 * hh]     = fmaf(a, hvt.x, acc[2 * hh]);
        acc[2 * hh + 1] = fmaf(a, hvt.y, acc[2 * hh + 1]);
      }
    }
  }
#pragma unroll
  for (int hh = 0; hh < 8; hh++) {
    float dh = __shfl(den, hh);
    float inv = 1.f / (dh + 1e-16f);
    float x0 = acc[2 * hh] * inv;
    float x1 = acc[2 * hh + 1] * inv;
    unsigned short h0 = bf16_rne(x0), h1 = bf16_rne(x1);
    unsigned short l0 = bf16_rne(x0 - bf16f(h0)), l1 = bf16_rne(x1 - bf16f(h1));
    *(unsigned*)(zh + hh * HID + 2 * lane) = (unsigned)h0 | ((unsigned)h1 << 16);
    *(unsigned*)(zl + hh * HID + 2 * lane) = (unsigned)l0 | ((unsigned)l1 << 16);
  }
}

// ================= MFMA bf16x4-split GEMM, GRID SPLIT-K -> P (proven R10) =================
struct MSeg {
  const unsigned short* Ahi; const unsigned short* Alo;
  const unsigned short* Bhi; const unsigned short* Blo;
  int M; int yb;
};

__global__ __launch_bounds__(256, 2) void gemm_mfma_splitk(
    MSeg s0, MSeg s1, float* __restrict__ P, int Mtot, int KS)
{
  __shared__ __align__(16) unsigned short smem[12288];
  const int tid = threadIdx.x;
  const unsigned short *Ahi, *Alo, *Bhi, *Blo; int M, ytile, rowbase;
  if ((int)blockIdx.x < s0.yb) {
    Ahi = s0.Ahi; Alo = s0.Alo; Bhi = s0.Bhi; Blo = s0.Blo;
    M = s0.M; ytile = blockIdx.x; rowbase = 0;
  } else {
    Ahi = s1.Ahi; Alo = s1.Alo; Bhi = s1.Bhi; Blo = s1.Blo;
    M = s1.M; ytile = blockIdx.x - s0.yb; rowbase = s0.yb * 64;
  }
  const int bm = ytile * 64;
  const int kchunk = 1024 / KS;
  const int kbeg = blockIdx.y * kchunk;
  const int nks = kchunk / 32;

  const int sr = tid >> 2;
  const int sg = tid & 3;
  const int g1 = sg ^ ((sr >> 1) & 3);
  const int sr2 = sr + 64;
  const int g2 = sg ^ ((sr2 >> 1) & 3);
  const int aslot  = sr * 32 + g1 * 8;
  const int bslotA = sr * 32 + g1 * 8;
  const int bslotB = sr2 * 32 + g2 * 8;
  const unsigned short* gA  = Ahi + (size_t)(bm + sr) * 1024 + kbeg + sg * 8;
  const unsigned short* gAl = Alo + (size_t)(bm + sr) * 1024 + kbeg + sg * 8;
  const unsigned short* gB0 = Bhi + (size_t)sr  * 1024 + kbeg + sg * 8;
  const unsigned short* gB1 = Bhi + (size_t)sr2 * 1024 + kbeg + sg * 8;
  const unsigned short* gC0 = Blo + (size_t)sr  * 1024 + kbeg + sg * 8;
  const unsigned short* gC1 = Blo + (size_t)sr2 * 1024 + kbeg + sg * 8;

  const int l = tid & 63;
  const int w = tid >> 6;
  const int kg = l >> 4;
  int aoff[4], boff[2];
#pragma unroll
  for (int mi = 0; mi < 4; mi++) {
    int r = mi * 16 + (l & 15);
    aoff[mi] = r * 32 + (kg ^ ((r >> 1) & 3)) * 8;
  }
#pragma unroll
  for (int ni = 0; ni < 2; ni++) {
    int r = w * 32 + ni * 16 + (l & 15);
    boff[ni] = r * 32 + (kg ^ ((r >> 1) & 3)) * 8;
  }

  f32x4 acc[4][2];
  const f32x4 z4 = {0.f, 0.f, 0.f, 0.f};
#pragma unroll
  for (int mi = 0; mi < 4; mi++)
#pragma unroll
    for (int ni = 0; ni < 2; ni++) acc[mi][ni] = z4;

  uint4 rA  = *(const uint4*)gA;
  uint4 rAl = *(const uint4*)gAl;
  uint4 rB0 = *(const uint4*)gB0;
  uint4 rB1 = *(const uint4*)gB1;
  uint4 rC0 = *(const uint4*)gC0;
  uint4 rC1 = *(const uint4*)gC1;

  for (int ks = 0; ks < nks; ks++) {
    *(uint4*)&smem[aslot]         = rA;
    *(uint4*)&smem[2048 + aslot]  = rAl;
    *(uint4*)&smem[4096 + bslotA] = rB0;
    *(uint4*)&smem[4096 + bslotB] = rB1;
    *(uint4*)&smem[8192 + bslotA] = rC0;
    *(uint4*)&smem[8192 + bslotB] = rC1;
    __syncthreads();
    if (ks < nks - 1) {
      const int k0 = (ks + 1) * 32;
      rA  = *(const uint4*)(gA  + k0);
      rAl = *(const uint4*)(gAl + k0);
      rB0 = *(const uint4*)(gB0 + k0);
      rB1 = *(const uint4*)(gB1 + k0);
      rC0 = *(const uint4*)(gC0 + k0);
      rC1 = *(const uint4*)(gC1 + k0);
    }
    s16x8 bh0 = *(const s16x8*)&smem[4096 + boff[0]];
    s16x8 bh1 = *(const s16x8*)&smem[4096 + boff[1]];
    s16x8 bl0 = *(const s16x8*)&smem[8192 + boff[0]];
    s16x8 bl1 = *(const s16x8*)&smem[8192 + boff[1]];
#pragma unroll
    for (int mi = 0; mi < 4; mi++) {
      s16x8 ah = *(const s16x8*)&smem[aoff[mi]];
      s16x8 al = *(const s16x8*)&smem[2048 + aoff[mi]];
      acc[mi][0] = __builtin_amdgcn_mfma_f32_16x16x32_bf16(ah, bh0, acc[mi][0], 0, 0, 0);
      acc[mi][1] = __builtin_amdgcn_mfma_f32_16x16x32_bf16(ah, bh1, acc[mi][1], 0, 0, 0);
      acc[mi][0] = __builtin_amdgcn_mfma_f32_16x16x32_bf16(ah, bl0, acc[mi][0], 0, 0, 0);
      acc[mi][1] = __builtin_amdgcn_mfma_f32_16x16x32_bf16(ah, bl1, acc[mi][1], 0, 0, 0);
      acc[mi][0] = __builtin_amdgcn_mfma_f32_16x16x32_bf16(al, bh0, acc[mi][0], 0, 0, 0);
      acc[mi][1] = __builtin_amdgcn_mfma_f32_16x16x32_bf16(al, bh1, acc[mi][1], 0, 0, 0);
      acc[mi][0] = __builtin_amdgcn_mfma_f32_16x16x32_bf16(al, bl0, acc[mi][0], 0, 0, 0);
      acc[mi][1] = __builtin_amdgcn_mfma_f32_16x16x32_bf16(al, bl1, acc[mi][1], 0, 0, 0);
    }
    __syncthreads();
  }

  const int q = l >> 4, cl = l & 15;
  const size_t prow0 = (size_t)blockIdx.y * Mtot + rowbase + bm;
#pragma unroll
  for (int ni = 0; ni < 2; ni++) {
    const int col = w * 32 + ni * 16 + cl;
#pragma unroll
    for (int mi = 0; mi < 4; mi++) {
      const int r0 = mi * 16 + q * 4;
      const f32x4 v = acc[mi][ni];
#pragma unroll
      for (int j = 0; j < 4; j++) {
        const int r = r0 + j;
        if (bm + r < M) P[(prow0 + r) * HID + col] = v[j];
      }
    }
  }
}

// ======= reduce KS partials + scale/bias/relu + NEXT-LAYER attention logits (fused) ========
struct RSegA {
  float* out; const float* bias; int M; int rowbase;
  const float* va; const float* vb;
  float* ala; float* alb;
};

__global__ __launch_bounds__(256) void reduce_epi_al(
    const float* __restrict__ P, int Mtot, int KS, float scale, int do_relu,
    RSegA s0, RSegA s1)
{
  int idx = blockIdx.x * 256 + threadIdx.x;
  if (idx >= Mtot * 32) return;
  int r = idx >> 5;
  int c = (idx & 31) << 2;
  float* outp; const float* bias; int rl;
  const float* va; const float* vb; float* ala; float* alb;
  if (s1.M > 0 && r >= s1.rowbase) {
    rl = r - s1.rowbase; if (rl >= s1.M) return;
    outp = s1.out; bias = s1.bias; va = s1.va; vb = s1.vb; ala = s1.ala; alb = s1.alb;
  } else {
    rl = r; if (rl >= s0.M) return;
    outp = s0.out; bias = s0.bias; va = s0.va; vb = s0.vb; ala = s0.ala; alb = s0.alb;
  }
  float4 acc = make_float4(0.f, 0.f, 0.f, 0.f);
  for (int z = 0; z < KS; z++) {
    const float4 v = *(const float4*)(P + ((size_t)z * Mtot + r) * HID + c);
    acc.x += v.x; acc.y += v.y; acc.z += v.z; acc.w += v.w;
  }
  const float4 b = *(const float4*)(bias + c);
  acc.x = acc.x * scale + b.x;
  acc.y = acc.y * scale + b.y;
  acc.z = acc.z * scale + b.z;
  acc.w = acc.w * scale + b.w;
  if (do_relu) {
    acc.x = fmaxf(acc.x, 0.f); acc.y = fmaxf(acc.y, 0.f);
    acc.z = fmaxf(acc.z, 0.f); acc.w = fmaxf(acc.w, 0.f);
  }
  *(float4*)(outp + (size_t)rl * HID + c) = acc;

  const float av[4] = {acc.x, acc.y, acc.z, acc.w};
  float pA[8], pB[8];
#pragma unroll
  for (int i = 0; i < 8; i++) { pA[i] = 0.f; pB[i] = 0.f; }
#pragma unroll
  for (int j = 0; j < 4; j++) {
    const float4 a0 = *(const float4*)(va + (c + j) * 8);
    const float4 a1 = *(const float4*)(va + (c + j) * 8 + 4);
    const float4 b0 = *(const float4*)(vb + (c + j) * 8);
    const float4 b1 = *(const float4*)(vb + (c + j) * 8 + 4);
    pA[0] = fmaf(av[j], a0.x, pA[0]); pA[1] = fmaf(av[j], a0.y, pA[1]);
    pA[2] = fmaf(av[j], a0.z, pA[2]); pA[3] = fmaf(av[j], a0.w, pA[3]);
    pA[4] = fmaf(av[j], a1.x, pA[4]); pA[5] = fmaf(av[j], a1.y, pA[5]);
    pA[6] = fmaf(av[j], a1.z, pA[6]); pA[7] = fmaf(av[j], a1.w, pA[7]);
    pB[0] = fmaf(av[j], b0.x, pB[0]); pB[1] = fmaf(av[j], b0.y, pB[1]);
    pB[2] = fmaf(av[j], b0.z, pB[2]); pB[3] = fmaf(av[j], b0.w, pB[3]);
    pB[4] = fmaf(av[j], b1.x, pB[4]); pB[5] = fmaf(av[j], b1.y, pB[5]);
    pB[6] = fmaf(av[j], b1.z, pB[6]); pB[7] = fmaf(av[j], b1.w, pB[7]);
  }
#pragma unroll
  for (int off = 16; off >= 1; off >>= 1) {
#pragma unroll
    for (int i = 0; i < 8; i++) {
      pA[i] += __shfl_xor(pA[i], off);
      pB[i] += __shfl_xor(pB[i], off);
    }
  }
  if ((threadIdx.x & 31) == 0) {
    *(float4*)(ala + (size_t)rl * 8)     = make_float4(pA[0], pA[1], pA[2], pA[3]);
    *(float4*)(ala + (size_t)rl * 8 + 4) = make_float4(pA[4], pA[5], pA[6], pA[7]);
    *(float4*)(alb + (size_t)rl * 8)     = make_float4(pB[0], pB[1], pB[2], pB[3]);
    *(float4*)(alb + (size_t)rl * 8 + 4) = make_float4(pB[4], pB[5], pB[6], pB[7]);
  }
}

// ================= reduce KS partials + scale + bias (plain, writes h2) — R10 proven =======
struct RSeg { float* out; const float* bias; int M; int rowbase; };

__global__ __launch_bounds__(256) void reduce_epi(
    const float* __restrict__ P, int Mtot, int KS, float scale, int do_relu,
    RSeg s0, RSeg s1)
{
  int idx = blockIdx.x * 256 + threadIdx.x;
  if (idx >= Mtot * 32) return;
  int r = idx >> 5;
  int c = (idx & 31) << 2;
  float* outp; const float* bias; int rl;
  if (s1.M > 0 && r >= s1.rowbase) {
    rl = r - s1.rowbase; if (rl >= s1.M) return; outp = s1.out; bias = s1.bias;
  } else {
    rl = r; if (rl >= s0.M) return; outp = s0.out; bias = s0.bias;
  }
  float4 acc = make_float4(0.f, 0.f, 0.f, 0.f);
  for (int z = 0; z < KS; z++) {
    const float4 v = *(const float4*)(P + ((size_t)z * Mtot + r) * HID + c);
    acc.x += v.x; acc.y += v.y; acc.z += v.z; acc.w += v.w;
  }
  const float4 b = *(const float4*)(bias + c);
  acc.x = acc.x * scale + b.x;
  acc.y = acc.y * scale + b.y;
  acc.z = acc.z * scale + b.z;
  acc.w = acc.w * scale + b.w;
  if (do_relu) {
    acc.x = fmaxf(acc.x, 0.f); acc.y = fmaxf(acc.y, 0.f);
    acc.z = fmaxf(acc.z, 0.f); acc.w = fmaxf(acc.w, 0.f);
  }
  *(float4*)(outp + (size_t)rl * HID + c) = acc;
}

// ================= fused pool + FC (R8-R10 proven: 320 blocks, LDS pre-reduce) =============
__global__ __launch_bounds__(256) void pool_fin(
    const float* __restrict__ ha, const float* __restrict__ hb,
    const int* __restrict__ batch_a, const int* __restrict__ batch_b,
    const float* __restrict__ fc_w, const float* __restrict__ fc_b,
    float* __restrict__ gsum, int* __restrict__ ticket,
    float* __restrict__ out, int na, int nb, int ng)
{
  const bool isA = blockIdx.x < 160;
  const float* h = isA ? ha : hb;
  const int* batch = isA ? batch_a : batch_b;
  const float* wseg = isA ? fc_w : fc_w + HID;
  float* gs = isA ? gsum : gsum + 8;
  const int n = isA ? na : nb;
  const int b = isA ? blockIdx.x : blockIdx.x - 160;

  __shared__ float sg[8];
  __shared__ int lastf;
  if (threadIdx.x < 8) sg[threadIdx.x] = 0.f;
  __syncthreads();
  const int lane = threadIdx.x & 63;
  const int wv = threadIdx.x >> 6;
  const int gw = b * 4 + wv;
  const int tw = 160 * 4;
  const float2 w2 = *(const float2*)(wseg + lane * 2);
  for (int r = gw; r < n; r += tw) {
    float2 hv = *(const float2*)(h + (size_t)r * HID + lane * 2);
    float s = hv.x * w2.x + hv.y * w2.y;
#pragma unroll
    for (int off = 32; off > 0; off >>= 1) s += __shfl_down(s, off, 64);
    if (lane == 0) atomicAdd(&sg[batch[r]], s);
  }
  __syncthreads();
  if (threadIdx.x < 8) atomicAdd(&gs[threadIdx.x], sg[threadIdx.x]);
  if (threadIdx.x == 0) {
    __threadfence();
    int tk = atomicAdd(ticket, 1);
    lastf = (tk == (int)gridDim.x - 1);
  }
  __syncthreads();
  if (lastf) {
    int g = threadIdx.x;
    if (g < ng) {
      int l, r, lo;
      l = 0; r = na; while (l < r) { int m = (l + r) >> 1; if (batch_a[m] < g) l = m + 1; else r = m; } lo = l;
      r = na; while (l < r) { int m = (l + r) >> 1; if (batch_a[m] < g + 1) l = m + 1; else r = m; }
      int ca = l - lo; if (ca < 1) ca = 1;
      l = 0; r = nb; while (l < r) { int m = (l + r) >> 1; if (batch_b[m] < g) l = m + 1; else r = m; } lo = l;
      r = nb; while (l < r) { int m = (l + r) >> 1; if (batch_b[m] < g + 1) l = m + 1; else r = m; }
      int cb = l - lo; if (cb < 1) cb = 1;
      float va = atomicAdd(&gsum[g], 0.f);
      float vb = atomicAdd(&gsum[8 + g], 0.f);
      out[g] = va / (float)ca + vb / (float)cb + fc_b[0];
    }
  }
}

extern "C" void kernel_launch(void* const* d_in, const int* in_sizes, int n_in,
                              void* d_out, int out_size, void* d_ws, size_t ws_size,
                              hipStream_t stream)
{
  const float* x_a = (const float*)d_in[0];
  const float* x_b = (const float*)d_in[1];
  const int* edge_ab = (const int*)d_in[2];
  const int* edge_ba = (const int*)d_in[3];
  const int* batch_a = (const int*)d_in[4];
  const int* batch_b = (const int*)d_in[5];
  const float* lin_a_w = (const float*)d_in[6];
  const float* lin_a_b = (const float*)d_in[7];
  const float* lin_b_w = (const float*)d_in[8];
  const float* lin_b_b = (const float*)d_in[9];
  const float* fc_w = (const float*)d_in[10];
  const float* fc_b = (const float*)d_in[11];

  const int NA = in_sizes[4];
  const int NB = in_sizes[5];
  const int E  = in_sizes[2] / 2;
  const int FA = in_sizes[0] / NA;
  const int FB = in_sizes[1] / NB;
  const int NG = out_size;
  const int NMAX = NA > NB ? NA : NB;
  const int NAp = (NA + 127) & ~127, NBp = (NB + 127) & ~127;
  const int NMAXp = NAp > NBp ? NAp : NBp;
  const int Mtot = NAp + NBp;

  // ---- size model (mirrors carve order) ----
  auto al256 = [](size_t b) { return (b + 255) & ~(size_t)255; };
  size_t fixed = 0;
  fixed += 3 * al256((size_t)NAp * HID * 4) + 3 * al256((size_t)NBp * HID * 4);  // h0,h1,h2
  fixed += 2 * al256((size_t)NMAXp * 1024 * 2);
  fixed += al256((size_t)8 * 131072 * 2);
  fixed += 2 * al256((size_t)FA * HID * 2) + 2 * al256((size_t)FB * HID * 2);
  fixed += al256((size_t)8 * HID * HEADS * 4);
  fixed += 2 * al256((size_t)NAp * HEADS * 4) + 2 * al256((size_t)NBp * HEADS * 4);
  fixed += al256(((size_t)4 * NMAX + 24) * 4);
  fixed += al256((size_t)(NB + 1) * 4) + al256((size_t)(NA + 1) * 4);
  fixed += 2 * al256((size_t)E * 4);
  fixed += 8192;
  const size_t zba_sz = 2 * al256((size_t)NAp * 1024 * 2);
  const size_t pslice = al256((size_t)Mtot * HID * 4);

  int KS = 4; bool dual = true;
  if (fixed + zba_sz + 4 * pslice <= ws_size)      { dual = true;  KS = 4; }
  else if (fixed + zba_sz + 2 * pslice <= ws_size) { dual = true;  KS = 2; }
  else if (fixed + 4 * pslice <= ws_size)          { dual = false; KS = 4; }
  else if (fixed + 2 * pslice <= ws_size)          { dual = false; KS = 2; }
  else if (fixed + 1 * pslice <= ws_size)          { dual = false; KS = 1; }
  else return;  // loud failure (out stays poisoned)

  char* w = (char*)d_ws;
  auto carve = [&](size_t bytes) -> void* {
    void* p = (void*)w;
    w += (bytes + 255) & ~(size_t)255;
    return p;
  };
  float* ha0 = (float*)carve((size_t)NAp * HID * 4);
  float* hb0 = (float*)carve((size_t)NBp * HID * 4);
  float* ha1 = (float*)carve((size_t)NAp * HID * 4);
  float* hb1 = (float*)carve((size_t)NBp * HID * 4);
  float* ha2 = (float*)carve((size_t)NAp * HID * 4);
  float* hb2 = (float*)carve((size_t)NBp * HID * 4);
  unsigned short* zab_hi = (unsigned short*)carve((size_t)NMAXp * 1024 * 2);
  unsigned short* zab_lo = (unsigned short*)carve((size_t)NMAXp * 1024 * 2);
  unsigned short* zba_hi = dual ? (unsigned short*)carve((size_t)NAp * 1024 * 2) : zab_hi;
  unsigned short* zba_lo = dual ? (unsigned short*)carve((size_t)NAp * 1024 * 2) : zab_lo;
  float* P = (float*)carve((size_t)KS * Mtot * HID * 4);
  unsigned short* WT = (unsigned short*)carve((size_t)8 * 131072 * 2);
  unsigned short* wa_hi = (unsigned short*)carve((size_t)FA * HID * 2);
  unsigned short* wa_lo = (unsigned short*)carve((size_t)FA * HID * 2);
  unsigned short* wb_hi = (unsigned short*)carve((size_t)FB * HID * 2);
  unsigned short* wb_lo = (unsigned short*)carve((size_t)FB * HID * 2);
  float* vv  = (float*)carve((size_t)8 * HID * HEADS * 4);
  float* als_ab = (float*)carve((size_t)NAp * HEADS * 4);
  float* ald_ab = (float*)carve((size_t)NBp * HEADS * 4);
  float* als_ba = (float*)carve((size_t)NBp * HEADS * 4);
  float* ald_ba = (float*)carve((size_t)NAp * HEADS * 4);
  int* csrblk = (int*)carve(((size_t)4 * NMAX + 24) * 4);
  int* indptr_ab = (int*)carve((size_t)(NB + 1) * 4);
  int* indptr_ba = (int*)carve((size_t)(NA + 1) * 4);
  int* srcs_ab   = (int*)carve((size_t)E * 4);
  int* srcs_ba   = (int*)carve((size_t)E * 4);
  if ((size_t)(w - (char*)d_ws) > ws_size) return;

  int* cnt_ab = csrblk;
  int* cnt_ba = csrblk + NMAX;
  int* cur_ab = csrblk + 2 * NMAX;
  int* cur_ba = csrblk + 3 * NMAX;
  float* gsum = (float*)(csrblk + 4 * NMAX);
  int* ticket = csrblk + 4 * NMAX + 16;

  hipMemsetAsync(csrblk, 0, ((size_t)4 * NMAX + 24) * 4, stream);

  // ---- fused weight prep (tiled transposes) + histogram ----
  PrepArgs pa;
  const int wi_idx[8] = {12, 13, 17, 18, 22, 23, 27, 28};
  const int ai_idx[8] = {14, 15, 19, 20, 24, 25, 29, 30};
  for (int i = 0; i < 8; i++) {
    pa.W[i] = (const float*)d_in[wi_idx[i]];
    pa.a[i] = (const float*)d_in[ai_idx[i]];
    pa.v[i] = vv + (size_t)i * HID * HEADS;
  }
  for (int g = 0; g < 4; g++) {
    pa.WThi[g] = WT + (size_t)g * 131072;
    pa.WTlo[g] = WT + (size_t)(4 + g) * 131072;
  }
  PrepX px;
  px.lwa = lin_a_w; px.lwb = lin_b_w;
  px.wa_hi = wa_hi; px.wa_lo = wa_lo; px.wb_hi = wb_hi; px.wb_lo = wb_lo;
  px.KA = FA; px.KB = FB;
  px.nta = (FA / 64) * 2;
  px.ntb = (FB / 64) * 2;
  const int hist_b = (2 * E + 255) / 256;
  prep_hist<<<160 + px.nta + px.ntb + hist_b, 256, 0, stream>>>(
      pa, px, edge_ab + E, edge_ba + E, cnt_ab, cnt_ba, E);
  scan2<<<2, 1024, 0, stream>>>(cnt_ab, cnt_ba, indptr_ab, indptr_ba, NB, NA);
  scatter2<<<(2 * E + 255) / 256, 256, 0, stream>>>(
      edge_ab, edge_ba, indptr_ab, indptr_ba, cur_ab, cur_ba, srcs_ab, srcs_ba, E);

  // ---- input linears: MFMA split GEMM with fused bias+relu ----
  {
    ISeg sa = {x_a, wa_hi, wa_lo, ha0, lin_a_b, NA, FA, NAp / 64};
    ISeg sb = {x_b, wb_hi, wb_lo, hb0, lin_b_b, NB, FB, NBp / 64};
    gemm_mfma_in<<<NAp / 64 + NBp / 64, 256, 0, stream>>>(sa, sb);
  }

  const int red_grid = (Mtot * 32 + 255) / 256;

  // ---- layer-0 attention logits (only standalone al launch) ----
  compute_al4<<<((2 * (NA + NB)) * HEADS + 255) / 256, 256, 0, stream>>>(
      ha0, hb0, vv, als_ab, ald_ab, als_ba, ald_ba, NA, NB);

  GDir dab0 = {indptr_ab, srcs_ab, als_ab, ald_ab, ha0, zab_hi, zab_lo};
  GDir dba0 = {indptr_ba, srcs_ba, als_ba, ald_ba, hb0, zba_hi, zba_lo};
  MSeg mab0 = {zab_hi, zab_lo, WT + (size_t)0 * 131072, WT + (size_t)4 * 131072, NB, NBp / 64};
  MSeg mba0 = {zba_hi, zba_lo, WT + (size_t)1 * 131072, WT + (size_t)5 * 131072, NA, NAp / 64};
  const float* v1 = vv + (size_t)4 * HID * HEADS;

  GDir dab1 = {indptr_ab, srcs_ab, als_ab, ald_ab, ha1, zab_hi, zab_lo};
  GDir dba1 = {indptr_ba, srcs_ba, als_ba, ald_ba, hb1, zba_hi, zba_lo};
  MSeg mab1 = {zab_hi, zab_lo, WT + (size_t)2 * 131072, WT + (size_t)6 * 131072, NB, NBp / 64};
  MSeg mba1 = {zba_hi, zba_lo, WT + (size_t)3 * 131072, WT + (size_t)7 * 131072, NA, NAp / 64};

  if (dual) {
    // layer 0
    gat_edge2<<<(NB + NA + 3) / 4, 256, 0, stream>>>(dab0, dba0, NB, NB + NA);
    gemm_mfma_splitk<<<dim3(NBp / 64 + NAp / 64, KS), 256, 0, stream>>>(mab0, mba0, P, Mtot, KS);
    RSegA r0 = {hb1, (const float*)d_in[16], NB, 0,
                v1 + 1024, v1 + 2048, ald_ab, als_ba};
    RSegA r1 = {ha1, (const float*)d_in[21], NA, NBp,
                v1, v1 + 3072, als_ab, ald_ba};
    reduce_epi_al<<<red_grid, 256, 0, stream>>>(P, Mtot, KS, 1.f / HEADS, 1, r0, r1);
    // layer 1
    gat_edge2<<<(NB + NA + 3) / 4, 256, 0, stream>>>(dab1, dba1, NB, NB + NA);
    gemm_mfma_splitk<<<dim3(NBp / 64 + NAp / 64, KS), 256, 0, stream>>>(mab1, mba1, P, Mtot, KS);
    RSeg p0 = {hb2, (const float*)d_in[26], NB, 0};
    RSeg p1 = {ha2, (const float*)d_in[31], NA, NBp};
    reduce_epi<<<red_grid, 256, 0, stream>>>(P, Mtot, KS, 1.f / HEADS, 0, p0, p1);
  } else {
    const RSegA ranull = {nullptr, nullptr, 0, 0, nullptr, nullptr, nullptr, nullptr};
    const RSeg rnull = {nullptr, nullptr, 0, 0};
    gat_edge2<<<(NB + 3) / 4, 256, 0, stream>>>(dab0, dab0, NB, NB);
    {
      MSeg mz = {nullptr, nullptr, nullptr, nullptr, 0, 0};
      gemm_mfma_splitk<<<dim3(NBp / 64, KS), 256, 0, stream>>>(mab0, mz, P, NBp, KS);
      RSegA r0 = {hb1, (const float*)d_in[16], NB, 0, v1 + 1024, v1 + 2048, ald_ab, als_ba};
      reduce_epi_al<<<(NBp * 32 + 255) / 256, 256, 0, stream>>>(P, NBp, KS, 1.f / HEADS, 1, r0, ranull);
    }
    gat_edge2<<<(NA + 3) / 4, 256, 0, stream>>>(dba0, dba0, NA, NA);
    {
      MSeg mz = {nullptr, nullptr, nullptr, nullptr, 0, 0};
      gemm_mfma_splitk<<<dim3(NAp / 64, KS), 256, 0, stream>>>(mba0, mz, P, NAp, KS);
      RSegA r1 = {ha1, (const float*)d_in[21], NA, 0, v1, v1 + 3072, als_ab, ald_ba};
      reduce_epi_al<<<(NAp * 32 + 255) / 256, 256, 0, stream>>>(P, NAp, KS, 1.f / HEADS, 1, r1, ranull);
    }
    gat_edge2<<<(NB + 3) / 4, 256, 0, stream>>>(dab1, dab1, NB, NB);
    {
      MSeg mz = {nullptr, nullptr, nullptr, nullptr, 0, 0};
      gemm_mfma_splitk<<<dim3(NBp / 64, KS), 256, 0, stream>>>(mab1, mz, P, NBp, KS);
      RSeg p0 = {hb2, (const float*)d_in[26], NB, 0};
      reduce_epi<<<(NBp * 32 + 255) / 256, 256, 0, stream>>>(P, NBp, KS, 1.f / HEADS, 0, p0, rnull);
    }
    gat_edge2<<<(NA + 3) / 4, 256, 0, stream>>>(dba1, dba1, NA, NA);
    {
      MSeg mz = {nullptr, nullptr, nullptr, nullptr, 0, 0};
      gemm_mfma_splitk<<<dim3(NAp / 64, KS), 256, 0, stream>>>(mba1, mz, P, NAp, KS);
      RSeg p1 = {ha2, (const float*)d_in[31], NA, 0};
      reduce_epi<<<(NAp * 32 + 255) / 256, 256, 0, stream>>>(P, NAp, KS, 1.f / HEADS, 0, p1, rnull);
    }
  }

  // ---- pooled mean + FC (proven 320-block path) ----
  pool_fin<<<320, 256, 0, stream>>>(ha2, hb2, batch_a, batch_b, fc_w, fc_b,
                                    gsum, ticket, (float*)d_out, NA, NB, NG);
}

// Round 14
// 381.933 us; speedup vs baseline: 1.6360x; 1.0012x over previous
//
#include <hip/hip_runtime.h>
#include <math.h>

#define HID 128
#define HEADS 8

typedef __attribute__((ext_vector_type(8))) short s16x8;
typedef __attribute__((ext_vector_type(4))) float f32x4;

__device__ __forceinline__ unsigned short bf16_rne(float x) {
  unsigned u = __float_as_uint(x);
  unsigned r = u + 0x7FFFu + ((u >> 16) & 1u);
  return (unsigned short)(r >> 16);
}
__device__ __forceinline__ float bf16f(unsigned short h) {
  return __uint_as_float(((unsigned)h) << 16);
}

// ====== fused prep: TILED transposes (layer W + input W) + make_v + histogram ==============
struct PrepArgs {
  const float* W[8];
  const float* a[8];
  unsigned short* WThi[4];
  unsigned short* WTlo[4];
  float* v[8];
};
struct PrepX {
  const float* lwa; const float* lwb;
  unsigned short *wa_hi, *wa_lo, *wb_hi, *wb_lo;
  int KA, KB, nta, ntb;
};

__global__ __launch_bounds__(256) void prep_hist(
    PrepArgs p, PrepX px,
    const int* __restrict__ dst_ab, const int* __restrict__ dst_ba,
    int* __restrict__ cnt_ab, int* __restrict__ cnt_ba, int E)
{
  __shared__ float tile[64][65];
  const int bid = blockIdx.x;
  const int tid = threadIdx.x;
  const int a = tid >> 2;          // tile row 0..63
  const int cg = (tid & 3) << 4;   // tile col group: 16 cols

  if (bid < 128) {  // layer W: per (mat g, head h, 64x64 tile) transpose (k,c)->(c,k) + split
    const int g = bid >> 5;
    const int rem = bid & 31;
    const int h = rem >> 2;
    const int t = rem & 3;
    const int k0 = (t >> 1) << 6, c0 = (t & 1) << 6;
    const float* src = p.W[2 * g] + (size_t)(k0 + a) * 1024 + h * 128 + c0 + cg;
#pragma unroll
    for (int i = 0; i < 16; i += 4) {
      const float4 v4 = *(const float4*)(src + i);
      tile[a][cg + i + 0] = v4.x; tile[a][cg + i + 1] = v4.y;
      tile[a][cg + i + 2] = v4.z; tile[a][cg + i + 3] = v4.w;
    }
    __syncthreads();
    const size_t ob = (size_t)(c0 + a) * 1024 + h * 128 + k0 + cg;
    unsigned hw[8], lw_[8];
#pragma unroll
    for (int i = 0; i < 8; i++) {
      float x0 = tile[cg + 2 * i][a];
      float x1 = tile[cg + 2 * i + 1][a];
      unsigned short h0 = bf16_rne(x0), h1 = bf16_rne(x1);
      unsigned short l0 = bf16_rne(x0 - bf16f(h0)), l1 = bf16_rne(x1 - bf16f(h1));
      hw[i]  = (unsigned)h0 | ((unsigned)h1 << 16);
      lw_[i] = (unsigned)l0 | ((unsigned)l1 << 16);
    }
    *(uint4*)(p.WThi[g] + ob)     = make_uint4(hw[0], hw[1], hw[2], hw[3]);
    *(uint4*)(p.WThi[g] + ob + 8) = make_uint4(hw[4], hw[5], hw[6], hw[7]);
    *(uint4*)(p.WTlo[g] + ob)     = make_uint4(lw_[0], lw_[1], lw_[2], lw_[3]);
    *(uint4*)(p.WTlo[g] + ob + 8) = make_uint4(lw_[4], lw_[5], lw_[6], lw_[7]);
  } else if (bid < 160) {  // make_v
    const int u = bid - 128;
    const int wi = u >> 2;
    const int gid = ((u & 3) << 8) + tid;
    const int k = gid >> 3, h = gid & 7;
    const float* wr = p.W[wi] + (size_t)k * (HEADS * HID) + h * HID;
    const float* ar = p.a[wi] + (size_t)h * HID;
    float s = 0.f;
    for (int c = 0; c < HID; c++) s = fmaf(wr[c], ar[c], s);
    p.v[wi][gid] = s;
  } else if (bid < 160 + px.nta + px.ntb) {  // input W transpose+split: [K][128] -> [128][K]
    const bool isa = (bid - 160) < px.nta;
    const int b = isa ? (bid - 160) : (bid - 160 - px.nta);
    const int K = isa ? px.KA : px.KB;
    const float* lw = isa ? px.lwa : px.lwb;
    unsigned short* ohi = isa ? px.wa_hi : px.wb_hi;
    unsigned short* olo = isa ? px.wa_lo : px.wb_lo;
    const int k0 = (b >> 1) << 6, c0 = (b & 1) << 6;
    const float* src = lw + (size_t)(k0 + a) * 128 + c0 + cg;
#pragma unroll
    for (int i = 0; i < 16; i += 4) {
      const float4 v4 = *(const float4*)(src + i);
      tile[a][cg + i + 0] = v4.x; tile[a][cg + i + 1] = v4.y;
      tile[a][cg + i + 2] = v4.z; tile[a][cg + i + 3] = v4.w;
    }
    __syncthreads();
    const size_t ob = (size_t)(c0 + a) * K + k0 + cg;
    unsigned hw[8], lw_[8];
#pragma unroll
    for (int i = 0; i < 8; i++) {
      float x0 = tile[cg + 2 * i][a];
      float x1 = tile[cg + 2 * i + 1][a];
      unsigned short h0 = bf16_rne(x0), h1 = bf16_rne(x1);
      unsigned short l0 = bf16_rne(x0 - bf16f(h0)), l1 = bf16_rne(x1 - bf16f(h1));
      hw[i]  = (unsigned)h0 | ((unsigned)h1 << 16);
      lw_[i] = (unsigned)l0 | ((unsigned)l1 << 16);
    }
    *(uint4*)(ohi + ob)     = make_uint4(hw[0], hw[1], hw[2], hw[3]);
    *(uint4*)(ohi + ob + 8) = make_uint4(hw[4], hw[5], hw[6], hw[7]);
    *(uint4*)(olo + ob)     = make_uint4(lw_[0], lw_[1], lw_[2], lw_[3]);
    *(uint4*)(olo + ob + 8) = make_uint4(lw_[4], lw_[5], lw_[6], lw_[7]);
  } else {  // degree histogram, both directions
    int gid = (bid - 160 - px.nta - px.ntb) * 256 + tid;
    if (gid < E) atomicAdd(&cnt_ab[dst_ab[gid]], 1);
    else if (gid < 2 * E) atomicAdd(&cnt_ba[dst_ba[gid - E]], 1);
  }
}

__global__ __launch_bounds__(1024) void scan2(
    const int* __restrict__ cnt_ab, const int* __restrict__ cnt_ba,
    int* __restrict__ ip_ab, int* __restrict__ ip_ba, int n_ab, int n_ba)
{
  const int* cnt = (blockIdx.x == 0) ? cnt_ab : cnt_ba;
  int* indptr = (blockIdx.x == 0) ? ip_ab : ip_ba;
  int n = (blockIdx.x == 0) ? n_ab : n_ba;
  __shared__ int parts[1024];
  const int tid = threadIdx.x;
  const int base = tid * 10;
  int local[10];
  int s = 0;
#pragma unroll
  for (int j = 0; j < 10; j++) {
    int v = (base + j < n) ? cnt[base + j] : 0;
    local[j] = v; s += v;
  }
  parts[tid] = s;
  __syncthreads();
  for (int off = 1; off < 1024; off <<= 1) {
    int v = (tid >= off) ? parts[tid - off] : 0;
    __syncthreads();
    parts[tid] += v;
    __syncthreads();
  }
  int ex = parts[tid] - s;
#pragma unroll
  for (int j = 0; j < 10; j++) {
    if (base + j < n) indptr[base + j] = ex;
    ex += local[j];
  }
  if (tid == 1023) indptr[n] = parts[1023];
}

// ===== fused: CSR scatter + input-linear MFMA GEMM (bias+relu) + layer-0 logits ============
// blocks [0, scat_b): scatter. blocks [scat_b, ...): 64-row GEMM tile; epilogue stores h0,
// mirrors it into bank-padded LDS [64][133], then threads 0..63 compute per-row logits with
// the SAME col-ascending accumulation order as the old compute_al4 (bit-identical).
struct ISeg {
  const float* A;
  const unsigned short* Bhi; const unsigned short* Blo;
  float* out; const float* bias; int M; int K; int yb;
  const float* va; const float* vb;   // [128][8] each
  float* ala; float* alb;             // [M][8] each
};

__global__ __launch_bounds__(256) void gemm_in_fused(
    const int* __restrict__ edge_ab, const int* __restrict__ edge_ba,
    const int* __restrict__ ip_ab, const int* __restrict__ ip_ba,
    int* __restrict__ cur_ab, int* __restrict__ cur_ba,
    int* __restrict__ srcs_ab, int* __restrict__ srcs_ba, int E, int scat_b,
    ISeg s0, ISeg s1)
{
  __shared__ __align__(16) unsigned short smem[12288];
  __shared__ float fl[64][133];
  const int tid = threadIdx.x;
  const int bid0 = blockIdx.x;
  if (bid0 < scat_b) {  // scatter part (independent of GEMM part)
    int gid = bid0 * 256 + tid;
    if (gid < E) {
      int d = edge_ab[E + gid];
      int pos = ip_ab[d] + atomicAdd(&cur_ab[d], 1);
      srcs_ab[pos] = edge_ab[gid];
    } else if (gid < 2 * E) {
      int g = gid - E;
      int d = edge_ba[E + g];
      int pos = ip_ba[d] + atomicAdd(&cur_ba[d], 1);
      srcs_ba[pos] = edge_ba[g];
    }
    return;
  }
  const int gemm_bid = bid0 - scat_b;
  const float* A; const unsigned short *Bhi, *Blo; const float* bias; float* out;
  const float* va; const float* vb; float* ala; float* alb;
  int M, K, ytile;
  if (gemm_bid < s0.yb) {
    A = s0.A; Bhi = s0.Bhi; Blo = s0.Blo; out = s0.out; bias = s0.bias;
    M = s0.M; K = s0.K; ytile = gemm_bid;
    va = s0.va; vb = s0.vb; ala = s0.ala; alb = s0.alb;
  } else {
    A = s1.A; Bhi = s1.Bhi; Blo = s1.Blo; out = s1.out; bias = s1.bias;
    M = s1.M; K = s1.K; ytile = gemm_bid - s0.yb;
    va = s1.va; vb = s1.vb; ala = s1.ala; alb = s1.alb;
  }
  const int bm = ytile * 64;
  const int nks = K >> 5;

  const int sr = tid >> 2;
  const int sg = tid & 3;
  const int g1 = sg ^ ((sr >> 1) & 3);
  const int sr2 = sr + 64;
  const int g2 = sg ^ ((sr2 >> 1) & 3);
  const int aslot  = sr * 32 + g1 * 8;
  const int bslotA = sr * 32 + g1 * 8;
  const int bslotB = sr2 * 32 + g2 * 8;
  const int gr = bm + sr;
  const bool arow_ok = (gr < M);
  const float* gA = A + (size_t)gr * K + sg * 8;
  const unsigned short* gB0 = Bhi + (size_t)sr  * K + sg * 8;
  const unsigned short* gB1 = Bhi + (size_t)sr2 * K + sg * 8;
  const unsigned short* gC0 = Blo + (size_t)sr  * K + sg * 8;
  const unsigned short* gC1 = Blo + (size_t)sr2 * K + sg * 8;

  const int l = tid & 63;
  const int w = tid >> 6;
  const int kg = l >> 4;
  int aoff[4], boff[2];
#pragma unroll
  for (int mi = 0; mi < 4; mi++) {
    int r = mi * 16 + (l & 15);
    aoff[mi] = r * 32 + (kg ^ ((r >> 1) & 3)) * 8;
  }
#pragma unroll
  for (int ni = 0; ni < 2; ni++) {
    int r = w * 32 + ni * 16 + (l & 15);
    boff[ni] = r * 32 + (kg ^ ((r >> 1) & 3)) * 8;
  }

  f32x4 acc[4][2];
  const f32x4 z4 = {0.f, 0.f, 0.f, 0.f};
#pragma unroll
  for (int mi = 0; mi < 4; mi++)
#pragma unroll
    for (int ni = 0; ni < 2; ni++) acc[mi][ni] = z4;

  float4 fa0 = make_float4(0.f, 0.f, 0.f, 0.f), fa1 = fa0;
  if (arow_ok) { fa0 = *(const float4*)gA; fa1 = *(const float4*)(gA + 4); }
  uint4 rB0 = *(const uint4*)gB0;
  uint4 rB1 = *(const uint4*)gB1;
  uint4 rC0 = *(const uint4*)gC0;
  uint4 rC1 = *(const uint4*)gC1;

  for (int ks = 0; ks < nks; ks++) {
    {
      const float f[8] = {fa0.x, fa0.y, fa0.z, fa0.w, fa1.x, fa1.y, fa1.z, fa1.w};
      unsigned au[4], lu[4];
#pragma unroll
      for (int i = 0; i < 4; i++) {
        unsigned short h0 = bf16_rne(f[2 * i]);
        unsigned short l0 = bf16_rne(f[2 * i] - bf16f(h0));
        unsigned short h1 = bf16_rne(f[2 * i + 1]);
        unsigned short l1 = bf16_rne(f[2 * i + 1] - bf16f(h1));
        au[i] = (unsigned)h0 | ((unsigned)h1 << 16);
        lu[i] = (unsigned)l0 | ((unsigned)l1 << 16);
      }
      *(uint4*)&smem[aslot]        = make_uint4(au[0], au[1], au[2], au[3]);
      *(uint4*)&smem[2048 + aslot] = make_uint4(lu[0], lu[1], lu[2], lu[3]);
    }
    *(uint4*)&smem[4096 + bslotA] = rB0;
    *(uint4*)&smem[4096 + bslotB] = rB1;
    *(uint4*)&smem[8192 + bslotA] = rC0;
    *(uint4*)&smem[8192 + bslotB] = rC1;
    __syncthreads();
    if (ks < nks - 1) {
      const int k0 = (ks + 1) * 32;
      if (arow_ok) {
        fa0 = *(const float4*)(gA + k0);
        fa1 = *(const float4*)(gA + k0 + 4);
      }
      rB0 = *(const uint4*)(gB0 + k0);
      rB1 = *(const uint4*)(gB1 + k0);
      rC0 = *(const uint4*)(gC0 + k0);
      rC1 = *(const uint4*)(gC1 + k0);
    }
    s16x8 bh0 = *(const s16x8*)&smem[4096 + boff[0]];
    s16x8 bh1 = *(const s16x8*)&smem[4096 + boff[1]];
    s16x8 bl0 = *(const s16x8*)&smem[8192 + boff[0]];
    s16x8 bl1 = *(const s16x8*)&smem[8192 + boff[1]];
#pragma unroll
    for (int mi = 0; mi < 4; mi++) {
      s16x8 ah = *(const s16x8*)&smem[aoff[mi]];
      s16x8 al = *(const s16x8*)&smem[2048 + aoff[mi]];
      acc[mi][0] = __builtin_amdgcn_mfma_f32_16x16x32_bf16(ah, bh0, acc[mi][0], 0, 0, 0);
      acc[mi][1] = __builtin_amdgcn_mfma_f32_16x16x32_bf16(ah, bh1, acc[mi][1], 0, 0, 0);
      acc[mi][0] = __builtin_amdgcn_mfma_f32_16x16x32_bf16(ah, bl0, acc[mi][0], 0, 0, 0);
      acc[mi][1] = __builtin_amdgcn_mfma_f32_16x16x32_bf16(ah, bl1, acc[mi][1], 0, 0, 0);
      acc[mi][0] = __builtin_amdgcn_mfma_f32_16x16x32_bf16(al, bh0, acc[mi][0], 0, 0, 0);
      acc[mi][1] = __builtin_amdgcn_mfma_f32_16x16x32_bf16(al, bh1, acc[mi][1], 0, 0, 0);
      acc[mi][0] = __builtin_amdgcn_mfma_f32_16x16x32_bf16(al, bl0, acc[mi][0], 0, 0, 0);
      acc[mi][1] = __builtin_amdgcn_mfma_f32_16x16x32_bf16(al, bl1, acc[mi][1], 0, 0, 0);
    }
    __syncthreads();
  }

  // epilogue: bias + relu, store h0, and mirror into padded LDS tile
  const int q = l >> 4, cl = l & 15;
#pragma unroll
  for (int ni = 0; ni < 2; ni++) {
    const int col = w * 32 + ni * 16 + cl;
    const float bv = bias[col];
#pragma unroll
    for (int mi = 0; mi < 4; mi++) {
      const int rt = mi * 16 + q * 4;
      const f32x4 v = acc[mi][ni];
#pragma unroll
      for (int j = 0; j < 4; j++) {
        const int r = bm + rt + j;
        if (r < M) {
          float x = v[j] + bv;
          x = fmaxf(x, 0.f);
          out[(size_t)r * HID + col] = x;
          fl[rt + j][col] = x;
        }
      }
    }
  }
  __syncthreads();
  // layer-0 logits: thread t owns row bm+t; col-ascending accumulation == old compute_al4
  if (tid < 64) {
    const int r = bm + tid;
    if (r < M) {
      float pA[8], pB[8];
#pragma unroll
      for (int i = 0; i < 8; i++) { pA[i] = 0.f; pB[i] = 0.f; }
      for (int col = 0; col < HID; col++) {
        const float hv = fl[tid][col];
        const float4 a0 = *(const float4*)(va + col * 8);
        const float4 a1 = *(const float4*)(va + col * 8 + 4);
        const float4 b0 = *(const float4*)(vb + col * 8);
        const float4 b1 = *(const float4*)(vb + col * 8 + 4);
        pA[0] = fmaf(hv, a0.x, pA[0]); pA[1] = fmaf(hv, a0.y, pA[1]);
        pA[2] = fmaf(hv, a0.z, pA[2]); pA[3] = fmaf(hv, a0.w, pA[3]);
        pA[4] = fmaf(hv, a1.x, pA[4]); pA[5] = fmaf(hv, a1.y, pA[5]);
        pA[6] = fmaf(hv, a1.z, pA[6]); pA[7] = fmaf(hv, a1.w, pA[7]);
        pB[0] = fmaf(hv, b0.x, pB[0]); pB[1] = fmaf(hv, b0.y, pB[1]);
        pB[2] = fmaf(hv, b0.z, pB[2]); pB[3] = fmaf(hv, b0.w, pB[3]);
        pB[4] = fmaf(hv, b1.x, pB[4]); pB[5] = fmaf(hv, b1.y, pB[5]);
        pB[6] = fmaf(hv, b1.z, pB[6]); pB[7] = fmaf(hv, b1.w, pB[7]);
      }
      *(float4*)(ala + (size_t)r * 8)     = make_float4(pA[0], pA[1], pA[2], pA[3]);
      *(float4*)(ala + (size_t)r * 8 + 4) = make_float4(pA[4], pA[5], pA[6], pA[7]);
      *(float4*)(alb + (size_t)r * 8)     = make_float4(pB[0], pB[1], pB[2], pB[3]);
      *(float4*)(alb + (size_t)r * 8 + 4) = make_float4(pB[4], pB[5], pB[6], pB[7]);
    }
  }
}

// ================= wave-per-node segment softmax + aggregation; writes bf16-split z =========
struct GDir {
  const int* indptr; const int* srcs;
  const float* als; const float* ald;
  const float* h;
  unsigned short* zhi; unsigned short* zlo;
};

__global__ __launch_bounds__(256) void gat_edge2(GDir d0, GDir d1, int n0, int ntot)
{
  const int w = threadIdx.x >> 6;
  const int lane = threadIdx.x & 63;
  const int g = blockIdx.x * 4 + w;
  if (g >= ntot) return;
  const bool first = (g < n0);
  const int n = first ? g : g - n0;
  const int* indptr = first ? d0.indptr : d1.indptr;
  const int* srcs   = first ? d0.srcs   : d1.srcs;
  const float* als  = first ? d0.als    : d1.als;
  const float* ald  = first ? d0.ald    : d1.ald;
  const float* hsrc = first ? d0.h      : d1.h;
  unsigned short* zh = (first ? d0.zhi : d1.zhi) + (size_t)n * (HEADS * HID);
  unsigned short* zl = (first ? d0.zlo : d1.zlo) + (size_t)n * (HEADS * HID);

  const int base = indptr[n];
  const int deg = indptr[n + 1] - base;
  if (deg == 0) {
#pragma unroll
    for (int hh = 0; hh < HEADS; hh++) {
      *(unsigned*)(zh + hh * HID + 2 * lane) = 0u;
      *(unsigned*)(zl + hh * HID + 2 * lane) = 0u;
    }
    return;
  }
  const int eh = lane >> 3, h = lane & 7;
  const float aldn = ald[(size_t)n * HEADS + h];
  const int nch = (deg + 7) >> 3;
  const int ncc = nch < 4 ? nch : 4;

  int sc[4];
  float vc[4];
#pragma unroll
  for (int c = 0; c < 4; c++) {
    int e = c * 8 + eh;
    sc[c] = (c < ncc && e < deg) ? srcs[base + e] : -1;
  }
#pragma unroll
  for (int c = 0; c < 4; c++)
    vc[c] = (sc[c] >= 0) ? als[(size_t)sc[c] * HEADS + h] : 0.f;
  float den = 0.f;
#pragma unroll
  for (int c = 0; c < 4; c++) {
    float v = vc[c] + aldn;
    v = v > 0.f ? v : 0.2f * v;
    float ex = (sc[c] >= 0) ? expf(v) : 0.f;
    vc[c] = ex;
    den += ex;
  }
  for (int e0 = 32; e0 < deg; e0 += 8) {
    int e = e0 + eh;
    if (e < deg) {
      int s = srcs[base + e];
      float v = als[(size_t)s * HEADS + h] + aldn;
      v = v > 0.f ? v : 0.2f * v;
      den += expf(v);
    }
  }
  den += __shfl_xor(den, 8);
  den += __shfl_xor(den, 16);
  den += __shfl_xor(den, 32);

  float acc[16];
#pragma unroll
  for (int i = 0; i < 16; i++) acc[i] = 0.f;
#pragma unroll
  for (int c = 0; c < 4; c++) {
    if (c >= ncc) break;
    const int rem = deg - c * 8;
    const int elim = rem < 8 ? rem : 8;
#pragma unroll
    for (int half = 0; half < 2; half++) {
      if (half * 4 >= elim) break;
      int sj[4];
#pragma unroll
      for (int j = 0; j < 4; j++) {
        int s = __shfl(sc[c], (half * 4 + j) * 8);
        sj[j] = s < 0 ? 0 : s;
      }
      float2 hv[4];
#pragma unroll
      for (int j = 0; j < 4; j++)
        hv[j] = *(const float2*)(hsrc + (size_t)sj[j] * HID + 2 * lane);
#pragma unroll
      for (int j = 0; j < 4; j++) {
#pragma unroll
        for (int hh = 0; hh < 8; hh++) {
          float a = __shfl(vc[c], (half * 4 + j) * 8 + hh);
          acc[2 * hh]     = fmaf(a, hv[j].x, acc[2 * hh]);
          acc[2 * hh + 1] = fmaf(a, hv[j].y, acc[2 * hh + 1]);
        }
      }
    }
  }
  for (int e0 = 32; e0 < deg; e0 += 8) {
    int e = e0 + eh;
    int s = (e < deg) ? srcs[base + e] : -1;
    float ex = 0.f;
    if (s >= 0) {
      float v = als[(size_t)s * HEADS + h] + aldn;
      v = v > 0.f ? v : 0.2f * v;
      ex = expf(v);
    }
    int elim = deg - e0; if (elim > 8) elim = 8;
    for (int e8 = 0; e8 < elim; e8++) {
      int ss = __shfl(s, e8 * 8);
      const float2 hvt = *(const float2*)(hsrc + (size_t)ss * HID + 2 * lane);
#pragma unroll
      for (int hh = 0; hh < 8; hh++) {
        float a = __shfl(ex, e8 * 8 + hh);
        acc[2 * hh]     = fmaf(a, hvt.x, acc[2 * hh]);
        acc[2 * hh + 1] = fmaf(a, hvt.y, acc[2 * hh + 1]);
      }
    }
  }
#pragma unroll
  for (int hh = 0; hh < 8; hh++) {
    float dh = __shfl(den, hh);
    float inv = 1.f / (dh + 1e-16f);
    float x0 = acc[2 * hh] * inv;
    float x1 = acc[2 * hh + 1] * inv;
    unsigned short h0 = bf16_rne(x0), h1 = bf16_rne(x1);
    unsigned short l0 = bf16_rne(x0 - bf16f(h0)), l1 = bf16_rne(x1 - bf16f(h1));
    *(unsigned*)(zh + hh * HID + 2 * lane) = (unsigned)h0 | ((unsigned)h1 << 16);
    *(unsigned*)(zl + hh * HID + 2 * lane) = (unsigned)l0 | ((unsigned)l1 << 16);
  }
}

// ================= MFMA bf16x4-split GEMM, GRID SPLIT-K -> P (proven R10) =================
struct MSeg {
  const unsigned short* Ahi; const unsigned short* Alo;
  const unsigned short* Bhi; const unsigned short* Blo;
  int M; int yb;
};

__global__ __launch_bounds__(256, 2) void gemm_mfma_splitk(
    MSeg s0, MSeg s1, float* __restrict__ P, int Mtot, int KS)
{
  __shared__ __align__(16) unsigned short smem[12288];
  const int tid = threadIdx.x;
  const unsigned short *Ahi, *Alo, *Bhi, *Blo; int M, ytile, rowbase;
  if ((int)blockIdx.x < s0.yb) {
    Ahi = s0.Ahi; Alo = s0.Alo; Bhi = s0.Bhi; Blo = s0.Blo;
    M = s0.M; ytile = blockIdx.x; rowbase = 0;
  } else {
    Ahi = s1.Ahi; Alo = s1.Alo; Bhi = s1.Bhi; Blo = s1.Blo;
    M = s1.M; ytile = blockIdx.x - s0.yb; rowbase = s0.yb * 64;
  }
  const int bm = ytile * 64;
  const int kchunk = 1024 / KS;
  const int kbeg = blockIdx.y * kchunk;
  const int nks = kchunk / 32;

  const int sr = tid >> 2;
  const int sg = tid & 3;
  const int g1 = sg ^ ((sr >> 1) & 3);
  const int sr2 = sr + 64;
  const int g2 = sg ^ ((sr2 >> 1) & 3);
  const int aslot  = sr * 32 + g1 * 8;
  const int bslotA = sr * 32 + g1 * 8;
  const int bslotB = sr2 * 32 + g2 * 8;
  const unsigned short* gA  = Ahi + (size_t)(bm + sr) * 1024 + kbeg + sg * 8;
  const unsigned short* gAl = Alo + (size_t)(bm + sr) * 1024 + kbeg + sg * 8;
  const unsigned short* gB0 = Bhi + (size_t)sr  * 1024 + kbeg + sg * 8;
  const unsigned short* gB1 = Bhi + (size_t)sr2 * 1024 + kbeg + sg * 8;
  const unsigned short* gC0 = Blo + (size_t)sr  * 1024 + kbeg + sg * 8;
  const unsigned short* gC1 = Blo + (size_t)sr2 * 1024 + kbeg + sg * 8;

  const int l = tid & 63;
  const int w = tid >> 6;
  const int kg = l >> 4;
  int aoff[4], boff[2];
#pragma unroll
  for (int mi = 0; mi < 4; mi++) {
    int r = mi * 16 + (l & 15);
    aoff[mi] = r * 32 + (kg ^ ((r >> 1) & 3)) * 8;
  }
#pragma unroll
  for (int ni = 0; ni < 2; ni++) {
    int r = w * 32 + ni * 16 + (l & 15);
    boff[ni] = r * 32 + (kg ^ ((r >> 1) & 3)) * 8;
  }

  f32x4 acc[4][2];
  const f32x4 z4 = {0.f, 0.f, 0.f, 0.f};
#pragma unroll
  for (int mi = 0; mi < 4; mi++)
#pragma unroll
    for (int ni = 0; ni < 2; ni++) acc[mi][ni] = z4;

  uint4 rA  = *(const uint4*)gA;
  uint4 rAl = *(const uint4*)gAl;
  uint4 rB0 = *(const uint4*)gB0;
  uint4 rB1 = *(const uint4*)gB1;
  uint4 rC0 = *(const uint4*)gC0;
  uint4 rC1 = *(const uint4*)gC1;

  for (int ks = 0; ks < nks; ks++) {
    *(uint4*)&smem[aslot]         = rA;
    *(uint4*)&smem[2048 + aslot]  = rAl;
    *(uint4*)&smem[4096 + bslotA] = rB0;
    *(uint4*)&smem[4096 + bslotB] = rB1;
    *(uint4*)&smem[8192 + bslotA] = rC0;
    *(uint4*)&smem[8192 + bslotB] = rC1;
    __syncthreads();
    if (ks < nks - 1) {
      const int k0 = (ks + 1) * 32;
      rA  = *(const uint4*)(gA  + k0);
      rAl = *(const uint4*)(gAl + k0);
      rB0 = *(const uint4*)(gB0 + k0);
      rB1 = *(const uint4*)(gB1 + k0);
      rC0 = *(const uint4*)(gC0 + k0);
      rC1 = *(const uint4*)(gC1 + k0);
    }
    s16x8 bh0 = *(const s16x8*)&smem[4096 + boff[0]];
    s16x8 bh1 = *(const s16x8*)&smem[4096 + boff[1]];
    s16x8 bl0 = *(const s16x8*)&smem[8192 + boff[0]];
    s16x8 bl1 = *(const s16x8*)&smem[8192 + boff[1]];
#pragma unroll
    for (int mi = 0; mi < 4; mi++) {
      s16x8 ah = *(const s16x8*)&smem[aoff[mi]];
      s16x8 al = *(const s16x8*)&smem[2048 + aoff[mi]];
      acc[mi][0] = __builtin_amdgcn_mfma_f32_16x16x32_bf16(ah, bh0, acc[mi][0], 0, 0, 0);
      acc[mi][1] = __builtin_amdgcn_mfma_f32_16x16x32_bf16(ah, bh1, acc[mi][1], 0, 0, 0);
      acc[mi][0] = __builtin_amdgcn_mfma_f32_16x16x32_bf16(ah, bl0, acc[mi][0], 0, 0, 0);
      acc[mi][1] = __builtin_amdgcn_mfma_f32_16x16x32_bf16(ah, bl1, acc[mi][1], 0, 0, 0);
      acc[mi][0] = __builtin_amdgcn_mfma_f32_16x16x32_bf16(al, bh0, acc[mi][0], 0, 0, 0);
      acc[mi][1] = __builtin_amdgcn_mfma_f32_16x16x32_bf16(al, bh1, acc[mi][1], 0, 0, 0);
      acc[mi][0] = __builtin_amdgcn_mfma_f32_16x16x32_bf16(al, bl0, acc[mi][0], 0, 0, 0);
      acc[mi][1] = __builtin_amdgcn_mfma_f32_16x16x32_bf16(al, bl1, acc[mi][1], 0, 0, 0);
    }
    __syncthreads();
  }

  const int q = l >> 4, cl = l & 15;
  const size_t prow0 = (size_t)blockIdx.y * Mtot + rowbase + bm;
#pragma unroll
  for (int ni = 0; ni < 2; ni++) {
    const int col = w * 32 + ni * 16 + cl;
#pragma unroll
    for (int mi = 0; mi < 4; mi++) {
      const int r0 = mi * 16 + q * 4;
      const f32x4 v = acc[mi][ni];
#pragma unroll
      for (int j = 0; j < 4; j++) {
        const int r = r0 + j;
        if (bm + r < M) P[(prow0 + r) * HID + col] = v[j];
      }
    }
  }
}

// ======= reduce KS partials + scale/bias/relu + NEXT-LAYER attention logits (fused) ========
struct RSegA {
  float* out; const float* bias; int M; int rowbase;
  const float* va; const float* vb;
  float* ala; float* alb;
};

__global__ __launch_bounds__(256) void reduce_epi_al(
    const float* __restrict__ P, int Mtot, int KS, float scale, int do_relu,
    RSegA s0, RSegA s1)
{
  int idx = blockIdx.x * 256 + threadIdx.x;
  if (idx >= Mtot * 32) return;
  int r = idx >> 5;
  int c = (idx & 31) << 2;
  float* outp; const float* bias; int rl;
  const float* va; const float* vb; float* ala; float* alb;
  if (s1.M > 0 && r >= s1.rowbase) {
    rl = r - s1.rowbase; if (rl >= s1.M) return;
    outp = s1.out; bias = s1.bias; va = s1.va; vb = s1.vb; ala = s1.ala; alb = s1.alb;
  } else {
    rl = r; if (rl >= s0.M) return;
    outp = s0.out; bias = s0.bias; va = s0.va; vb = s0.vb; ala = s0.ala; alb = s0.alb;
  }
  float4 acc = make_float4(0.f, 0.f, 0.f, 0.f);
  for (int z = 0; z < KS; z++) {
    const float4 v = *(const float4*)(P + ((size_t)z * Mtot + r) * HID + c);
    acc.x += v.x; acc.y += v.y; acc.z += v.z; acc.w += v.w;
  }
  const float4 b = *(const float4*)(bias + c);
  acc.x = acc.x * scale + b.x;
  acc.y = acc.y * scale + b.y;
  acc.z = acc.z * scale + b.z;
  acc.w = acc.w * scale + b.w;
  if (do_relu) {
    acc.x = fmaxf(acc.x, 0.f); acc.y = fmaxf(acc.y, 0.f);
    acc.z = fmaxf(acc.z, 0.f); acc.w = fmaxf(acc.w, 0.f);
  }
  *(float4*)(outp + (size_t)rl * HID + c) = acc;

  const float av[4] = {acc.x, acc.y, acc.z, acc.w};
  float pA[8], pB[8];
#pragma unroll
  for (int i = 0; i < 8; i++) { pA[i] = 0.f; pB[i] = 0.f; }
#pragma unroll
  for (int j = 0; j < 4; j++) {
    const float4 a0 = *(const float4*)(va + (c + j) * 8);
    const float4 a1 = *(const float4*)(va + (c + j) * 8 + 4);
    const float4 b0 = *(const float4*)(vb + (c + j) * 8);
    const float4 b1 = *(const float4*)(vb + (c + j) * 8 + 4);
    pA[0] = fmaf(av[j], a0.x, pA[0]); pA[1] = fmaf(av[j], a0.y, pA[1]);
    pA[2] = fmaf(av[j], a0.z, pA[2]); pA[3] = fmaf(av[j], a0.w, pA[3]);
    pA[4] = fmaf(av[j], a1.x, pA[4]); pA[5] = fmaf(av[j], a1.y, pA[5]);
    pA[6] = fmaf(av[j], a1.z, pA[6]); pA[7] = fmaf(av[j], a1.w, pA[7]);
    pB[0] = fmaf(av[j], b0.x, pB[0]); pB[1] = fmaf(av[j], b0.y, pB[1]);
    pB[2] = fmaf(av[j], b0.z, pB[2]); pB[3] = fmaf(av[j], b0.w, pB[3]);
    pB[4] = fmaf(av[j], b1.x, pB[4]); pB[5] = fmaf(av[j], b1.y, pB[5]);
    pB[6] = fmaf(av[j], b1.z, pB[6]); pB[7] = fmaf(av[j], b1.w, pB[7]);
  }
#pragma unroll
  for (int off = 16; off >= 1; off >>= 1) {
#pragma unroll
    for (int i = 0; i < 8; i++) {
      pA[i] += __shfl_xor(pA[i], off);
      pB[i] += __shfl_xor(pB[i], off);
    }
  }
  if ((threadIdx.x & 31) == 0) {
    *(float4*)(ala + (size_t)rl * 8)     = make_float4(pA[0], pA[1], pA[2], pA[3]);
    *(float4*)(ala + (size_t)rl * 8 + 4) = make_float4(pA[4], pA[5], pA[6], pA[7]);
    *(float4*)(alb + (size_t)rl * 8)     = make_float4(pB[0], pB[1], pB[2], pB[3]);
    *(float4*)(alb + (size_t)rl * 8 + 4) = make_float4(pB[4], pB[5], pB[6], pB[7]);
  }
}

// ================= reduce KS partials + scale + bias (plain, writes h2) =================
struct RSeg { float* out; const float* bias; int M; int rowbase; };

__global__ __launch_bounds__(256) void reduce_epi(
    const float* __restrict__ P, int Mtot, int KS, float scale, int do_relu,
    RSeg s0, RSeg s1)
{
  int idx = blockIdx.x * 256 + threadIdx.x;
  if (idx >= Mtot * 32) return;
  int r = idx >> 5;
  int c = (idx & 31) << 2;
  float* outp; const float* bias; int rl;
  if (s1.M > 0 && r >= s1.rowbase) {
    rl = r - s1.rowbase; if (rl >= s1.M) return; outp = s1.out; bias = s1.bias;
  } else {
    rl = r; if (rl >= s0.M) return; outp = s0.out; bias = s0.bias;
  }
  float4 acc = make_float4(0.f, 0.f, 0.f, 0.f);
  for (int z = 0; z < KS; z++) {
    const float4 v = *(const float4*)(P + ((size_t)z * Mtot + r) * HID + c);
    acc.x += v.x; acc.y += v.y; acc.z += v.z; acc.w += v.w;
  }
  const float4 b = *(const float4*)(bias + c);
  acc.x = acc.x * scale + b.x;
  acc.y = acc.y * scale + b.y;
  acc.z = acc.z * scale + b.z;
  acc.w = acc.w * scale + b.w;
  if (do_relu) {
    acc.x = fmaxf(acc.x, 0.f); acc.y = fmaxf(acc.y, 0.f);
    acc.z = fmaxf(acc.z, 0.f); acc.w = fmaxf(acc.w, 0.f);
  }
  *(float4*)(outp + (size_t)rl * HID + c) = acc;
}

// ================= fused pool + FC (R8-R10 proven: 320 blocks, LDS pre-reduce) =============
__global__ __launch_bounds__(256) void pool_fin(
    const float* __restrict__ ha, const float* __restrict__ hb,
    const int* __restrict__ batch_a, const int* __restrict__ batch_b,
    const float* __restrict__ fc_w, const float* __restrict__ fc_b,
    float* __restrict__ gsum, int* __restrict__ ticket,
    float* __restrict__ out, int na, int nb, int ng)
{
  const bool isA = blockIdx.x < 160;
  const float* h = isA ? ha : hb;
  const int* batch = isA ? batch_a : batch_b;
  const float* wseg = isA ? fc_w : fc_w + HID;
  float* gs = isA ? gsum : gsum + 8;
  const int n = isA ? na : nb;
  const int b = isA ? blockIdx.x : blockIdx.x - 160;

  __shared__ float sg[8];
  __shared__ int lastf;
  if (threadIdx.x < 8) sg[threadIdx.x] = 0.f;
  __syncthreads();
  const int lane = threadIdx.x & 63;
  const int wv = threadIdx.x >> 6;
  const int gw = b * 4 + wv;
  const int tw = 160 * 4;
  const float2 w2 = *(const float2*)(wseg + lane * 2);
  for (int r = gw; r < n; r += tw) {
    float2 hv = *(const float2*)(h + (size_t)r * HID + lane * 2);
    float s = hv.x * w2.x + hv.y * w2.y;
#pragma unroll
    for (int off = 32; off > 0; off >>= 1) s += __shfl_down(s, off, 64);
    if (lane == 0) atomicAdd(&sg[batch[r]], s);
  }
  __syncthreads();
  if (threadIdx.x < 8) atomicAdd(&gs[threadIdx.x], sg[threadIdx.x]);
  if (threadIdx.x == 0) {
    __threadfence();
    int tk = atomicAdd(ticket, 1);
    lastf = (tk == (int)gridDim.x - 1);
  }
  __syncthreads();
  if (lastf) {
    int g = threadIdx.x;
    if (g < ng) {
      int l, r, lo;
      l = 0; r = na; while (l < r) { int m = (l + r) >> 1; if (batch_a[m] < g) l = m + 1; else r = m; } lo = l;
      r = na; while (l < r) { int m = (l + r) >> 1; if (batch_a[m] < g + 1) l = m + 1; else r = m; }
      int ca = l - lo; if (ca < 1) ca = 1;
      l = 0; r = nb; while (l < r) { int m = (l + r) >> 1; if (batch_b[m] < g) l = m + 1; else r = m; } lo = l;
      r = nb; while (l < r) { int m = (l + r) >> 1; if (batch_b[m] < g + 1) l = m + 1; else r = m; }
      int cb = l - lo; if (cb < 1) cb = 1;
      float va = atomicAdd(&gsum[g], 0.f);
      float vb = atomicAdd(&gsum[8 + g], 0.f);
      out[g] = va / (float)ca + vb / (float)cb + fc_b[0];
    }
  }
}

extern "C" void kernel_launch(void* const* d_in, const int* in_sizes, int n_in,
                              void* d_out, int out_size, void* d_ws, size_t ws_size,
                              hipStream_t stream)
{
  const float* x_a = (const float*)d_in[0];
  const float* x_b = (const float*)d_in[1];
  const int* edge_ab = (const int*)d_in[2];
  const int* edge_ba = (const int*)d_in[3];
  const int* batch_a = (const int*)d_in[4];
  const int* batch_b = (const int*)d_in[5];
  const float* lin_a_w = (const float*)d_in[6];
  const float* lin_a_b = (const float*)d_in[7];
  const float* lin_b_w = (const float*)d_in[8];
  const float* lin_b_b = (const float*)d_in[9];
  const float* fc_w = (const float*)d_in[10];
  const float* fc_b = (const float*)d_in[11];

  const int NA = in_sizes[4];
  const int NB = in_sizes[5];
  const int E  = in_sizes[2] / 2;
  const int FA = in_sizes[0] / NA;
  const int FB = in_sizes[1] / NB;
  const int NG = out_size;
  const int NMAX = NA > NB ? NA : NB;
  const int NAp = (NA + 127) & ~127, NBp = (NB + 127) & ~127;
  const int NMAXp = NAp > NBp ? NAp : NBp;
  const int Mtot = NAp + NBp;

  // ---- size model (mirrors carve order) ----
  auto al256 = [](size_t b) { return (b + 255) & ~(size_t)255; };
  size_t fixed = 0;
  fixed += 3 * al256((size_t)NAp * HID * 4) + 3 * al256((size_t)NBp * HID * 4);  // h0,h1,h2
  fixed += 2 * al256((size_t)NMAXp * 1024 * 2);
  fixed += al256((size_t)8 * 131072 * 2);
  fixed += 2 * al256((size_t)FA * HID * 2) + 2 * al256((size_t)FB * HID * 2);
  fixed += al256((size_t)8 * HID * HEADS * 4);
  fixed += 2 * al256((size_t)NAp * HEADS * 4) + 2 * al256((size_t)NBp * HEADS * 4);
  fixed += al256(((size_t)4 * NMAX + 24) * 4);
  fixed += al256((size_t)(NB + 1) * 4) + al256((size_t)(NA + 1) * 4);
  fixed += 2 * al256((size_t)E * 4);
  fixed += 8192;
  const size_t zba_sz = 2 * al256((size_t)NAp * 1024 * 2);
  const size_t pslice = al256((size_t)Mtot * HID * 4);

  int KS = 4; bool dual = true;
  if (fixed + zba_sz + 4 * pslice <= ws_size)      { dual = true;  KS = 4; }
  else if (fixed + zba_sz + 2 * pslice <= ws_size) { dual = true;  KS = 2; }
  else if (fixed + 4 * pslice <= ws_size)          { dual = false; KS = 4; }
  else if (fixed + 2 * pslice <= ws_size)          { dual = false; KS = 2; }
  else if (fixed + 1 * pslice <= ws_size)          { dual = false; KS = 1; }
  else return;  // loud failure (out stays poisoned)

  char* w = (char*)d_ws;
  auto carve = [&](size_t bytes) -> void* {
    void* p = (void*)w;
    w += (bytes + 255) & ~(size_t)255;
    return p;
  };
  float* ha0 = (float*)carve((size_t)NAp * HID * 4);
  float* hb0 = (float*)carve((size_t)NBp * HID * 4);
  float* ha1 = (float*)carve((size_t)NAp * HID * 4);
  float* hb1 = (float*)carve((size_t)NBp * HID * 4);
  float* ha2 = (float*)carve((size_t)NAp * HID * 4);
  float* hb2 = (float*)carve((size_t)NBp * HID * 4);
  unsigned short* zab_hi = (unsigned short*)carve((size_t)NMAXp * 1024 * 2);
  unsigned short* zab_lo = (unsigned short*)carve((size_t)NMAXp * 1024 * 2);
  unsigned short* zba_hi = dual ? (unsigned short*)carve((size_t)NAp * 1024 * 2) : zab_hi;
  unsigned short* zba_lo = dual ? (unsigned short*)carve((size_t)NAp * 1024 * 2) : zab_lo;
  float* P = (float*)carve((size_t)KS * Mtot * HID * 4);
  unsigned short* WT = (unsigned short*)carve((size_t)8 * 131072 * 2);
  unsigned short* wa_hi = (unsigned short*)carve((size_t)FA * HID * 2);
  unsigned short* wa_lo = (unsigned short*)carve((size_t)FA * HID * 2);
  unsigned short* wb_hi = (unsigned short*)carve((size_t)FB * HID * 2);
  unsigned short* wb_lo = (unsigned short*)carve((size_t)FB * HID * 2);
  float* vv  = (float*)carve((size_t)8 * HID * HEADS * 4);
  float* als_ab = (float*)carve((size_t)NAp * HEADS * 4);
  float* ald_ab = (float*)carve((size_t)NBp * HEADS * 4);
  float* als_ba = (float*)carve((size_t)NBp * HEADS * 4);
  float* ald_ba = (float*)carve((size_t)NAp * HEADS * 4);
  int* csrblk = (int*)carve(((size_t)4 * NMAX + 24) * 4);
  int* indptr_ab = (int*)carve((size_t)(NB + 1) * 4);
  int* indptr_ba = (int*)carve((size_t)(NA + 1) * 4);
  int* srcs_ab   = (int*)carve((size_t)E * 4);
  int* srcs_ba   = (int*)carve((size_t)E * 4);
  if ((size_t)(w - (char*)d_ws) > ws_size) return;

  int* cnt_ab = csrblk;
  int* cnt_ba = csrblk + NMAX;
  int* cur_ab = csrblk + 2 * NMAX;
  int* cur_ba = csrblk + 3 * NMAX;
  float* gsum = (float*)(csrblk + 4 * NMAX);
  int* ticket = csrblk + 4 * NMAX + 16;

  hipMemsetAsync(csrblk, 0, ((size_t)4 * NMAX + 24) * 4, stream);

  // ---- fused weight prep (tiled transposes) + histogram ----
  PrepArgs pa;
  const int wi_idx[8] = {12, 13, 17, 18, 22, 23, 27, 28};
  const int ai_idx[8] = {14, 15, 19, 20, 24, 25, 29, 30};
  for (int i = 0; i < 8; i++) {
    pa.W[i] = (const float*)d_in[wi_idx[i]];
    pa.a[i] = (const float*)d_in[ai_idx[i]];
    pa.v[i] = vv + (size_t)i * HID * HEADS;
  }
  for (int g = 0; g < 4; g++) {
    pa.WThi[g] = WT + (size_t)g * 131072;
    pa.WTlo[g] = WT + (size_t)(4 + g) * 131072;
  }
  PrepX px;
  px.lwa = lin_a_w; px.lwb = lin_b_w;
  px.wa_hi = wa_hi; px.wa_lo = wa_lo; px.wb_hi = wb_hi; px.wb_lo = wb_lo;
  px.KA = FA; px.KB = FB;
  px.nta = (FA / 64) * 2;
  px.ntb = (FB / 64) * 2;
  const int hist_b = (2 * E + 255) / 256;
  prep_hist<<<160 + px.nta + px.ntb + hist_b, 256, 0, stream>>>(
      pa, px, edge_ab + E, edge_ba + E, cnt_ab, cnt_ba, E);
  scan2<<<2, 1024, 0, stream>>>(cnt_ab, cnt_ba, indptr_ab, indptr_ba, NB, NA);

  // ---- fused: scatter + input MFMA GEMM + layer-0 logits ----
  {
    // layer-0 logit v's: A rows use v0 (als_ab) & v3 (ald_ba); B rows use v1 (ald_ab) & v2 (als_ba)
    ISeg sa = {x_a, wa_hi, wa_lo, ha0, lin_a_b, NA, FA, NAp / 64,
               vv + 0 * 1024, vv + 3 * 1024, als_ab, ald_ba};
    ISeg sb = {x_b, wb_hi, wb_lo, hb0, lin_b_b, NB, FB, NBp / 64,
               vv + 1 * 1024, vv + 2 * 1024, ald_ab, als_ba};
    const int scat_b = (2 * E + 255) / 256;
    gemm_in_fused<<<scat_b + NAp / 64 + NBp / 64, 256, 0, stream>>>(
        edge_ab, edge_ba, indptr_ab, indptr_ba, cur_ab, cur_ba,
        srcs_ab, srcs_ba, E, scat_b, sa, sb);
  }

  const int red_grid = (Mtot * 32 + 255) / 256;

  GDir dab0 = {indptr_ab, srcs_ab, als_ab, ald_ab, ha0, zab_hi, zab_lo};
  GDir dba0 = {indptr_ba, srcs_ba, als_ba, ald_ba, hb0, zba_hi, zba_lo};
  MSeg mab0 = {zab_hi, zab_lo, WT + (size_t)0 * 131072, WT + (size_t)4 * 131072, NB, NBp / 64};
  MSeg mba0 = {zba_hi, zba_lo, WT + (size_t)1 * 131072, WT + (size_t)5 * 131072, NA, NAp / 64};
  const float* v1 = vv + (size_t)4 * HID * HEADS;

  GDir dab1 = {indptr_ab, srcs_ab, als_ab, ald_ab, ha1, zab_hi, zab_lo};
  GDir dba1 = {indptr_ba, srcs_ba, als_ba, ald_ba, hb1, zba_hi, zba_lo};
  MSeg mab1 = {zab_hi, zab_lo, WT + (size_t)2 * 131072, WT + (size_t)6 * 131072, NB, NBp / 64};
  MSeg mba1 = {zba_hi, zba_lo, WT + (size_t)3 * 131072, WT + (size_t)7 * 131072, NA, NAp / 64};

  if (dual) {
    // layer 0
    gat_edge2<<<(NB + NA + 3) / 4, 256, 0, stream>>>(dab0, dba0, NB, NB + NA);
    gemm_mfma_splitk<<<dim3(NBp / 64 + NAp / 64, KS), 256, 0, stream>>>(mab0, mba0, P, Mtot, KS);
    RSegA r0 = {hb1, (const float*)d_in[16], NB, 0,
                v1 + 1024, v1 + 2048, ald_ab, als_ba};
    RSegA r1 = {ha1, (const float*)d_in[21], NA, NBp,
                v1, v1 + 3072, als_ab, ald_ba};
    reduce_epi_al<<<red_grid, 256, 0, stream>>>(P, Mtot, KS, 1.f / HEADS, 1, r0, r1);
    // layer 1
    gat_edge2<<<(NB + NA + 3) / 4, 256, 0, stream>>>(dab1, dba1, NB, NB + NA);
    gemm_mfma_splitk<<<dim3(NBp / 64 + NAp / 64, KS), 256, 0, stream>>>(mab1, mba1, P, Mtot, KS);
    RSeg p0 = {hb2, (const float*)d_in[26], NB, 0};
    RSeg p1 = {ha2, (const float*)d_in[31], NA, NBp};
    reduce_epi<<<red_grid, 256, 0, stream>>>(P, Mtot, KS, 1.f / HEADS, 0, p0, p1);
  } else {
    const RSegA ranull = {nullptr, nullptr, 0, 0, nullptr, nullptr, nullptr, nullptr};
    const RSeg rnull = {nullptr, nullptr, 0, 0};
    gat_edge2<<<(NB + 3) / 4, 256, 0, stream>>>(dab0, dab0, NB, NB);
    {
      MSeg mz = {nullptr, nullptr, nullptr, nullptr, 0, 0};
      gemm_mfma_splitk<<<dim3(NBp / 64, KS), 256, 0, stream>>>(mab0, mz, P, NBp, KS);
      RSegA r0 = {hb1, (const float*)d_in[16], NB, 0, v1 + 1024, v1 + 2048, ald_ab, als_ba};
      reduce_epi_al<<<(NBp * 32 + 255) / 256, 256, 0, stream>>>(P, NBp, KS, 1.f / HEADS, 1, r0, ranull);
    }
    gat_edge2<<<(NA + 3) / 4, 256, 0, stream>>>(dba0, dba0, NA, NA);
    {
      MSeg mz = {nullptr, nullptr, nullptr, nullptr, 0, 0};
      gemm_mfma_splitk<<<dim3(NAp / 64, KS), 256, 0, stream>>>(mba0, mz, P, NAp, KS);
      RSegA r1 = {ha1, (const float*)d_in[21], NA, 0, v1, v1 + 3072, als_ab, ald_ba};
      reduce_epi_al<<<(NAp * 32 + 255) / 256, 256, 0, stream>>>(P, NAp, KS, 1.f / HEADS, 1, r1, ranull);
    }
    gat_edge2<<<(NB + 3) / 4, 256, 0, stream>>>(dab1, dab1, NB, NB);
    {
      MSeg mz = {nullptr, nullptr, nullptr, nullptr, 0, 0};
      gemm_mfma_splitk<<<dim3(NBp / 64, KS), 256, 0, stream>>>(mab1, mz, P, NBp, KS);
      RSeg p0 = {hb2, (const float*)d_in[26], NB, 0};
      reduce_epi<<<(NBp * 32 + 255) / 256, 256, 0, stream>>>(P, NBp, KS, 1.f / HEADS, 0, p0, rnull);
    }
    gat_edge2<<<(NA + 3) / 4, 256, 0, stream>>>(dba1, dba1, NA, NA);
    {
      MSeg mz = {nullptr, nullptr, nullptr, nullptr, 0, 0};
      gemm_mfma_splitk<<<dim3(NAp / 64, KS), 256, 0, stream>>>(mba1, mz, P, NAp, KS);
      RSeg p1 = {ha2, (const float*)d_in[31], NA, 0};
      reduce_epi<<<(NAp * 32 + 255) / 256, 256, 0, stream>>>(P, NAp, KS, 1.f / HEADS, 0, p1, rnull);
    }
  }

  // ---- pooled mean + FC (proven 320-block path) ----
  pool_fin<<<320, 256, 0, stream>>>(ha2, hb2, batch_a, batch_b, fc_w, fc_b,
                                    gsum, ticket, (float*)d_out, NA, NB, NG);
}